// Round 1
// baseline (1016.473 us; speedup 1.0000x reference)
//
#include <hip/hip_runtime.h>
#include <hip/hip_bf16.h>

// Problem constants
#define S_    2048
#define DIM_  1024
#define H_    16
#define DH_   64
#define BOT_  256
#define NIMG_ 4
#define LI_   512
#define K_    256
#define IH_   4
#define ID_   16
#define MAXREL_ 64
#define NBUCK_ 129
#define GH_   8
#define IDH2_ 128   // 2*IH*ID

// ---------------------------------------------------------------------------
// Generic fp32 GEMM: C[M,N] = A[M,Kd] @ B[N,Kd]^T (+bias[N]) (*scale)
// 64x64 tile, BK=16, 256 threads, 4x4 per thread, transposed LDS for float4.
// M,N multiples of 64; Kd multiple of 16 (true for all call sites).
// ---------------------------------------------------------------------------
__global__ __launch_bounds__(256) void gemm_nt(
    const float* __restrict__ A, const float* __restrict__ B,
    const float* __restrict__ bias, const float* __restrict__ scale_ptr,
    float* __restrict__ C, int M, int N, int Kd)
{
    __shared__ float As[16][68];
    __shared__ float Bs[16][68];
    int tid = threadIdx.x;
    int tx = tid & 15, ty = tid >> 4;
    int row0 = blockIdx.y * 64, col0 = blockIdx.x * 64;
    float acc[4][4] = {};
    for (int k0 = 0; k0 < Kd; k0 += 16) {
        int r  = tid >> 2;          // 0..63
        int c4 = (tid & 3) * 4;     // 0,4,8,12
        float4 av = *(const float4*)(A + (size_t)(row0 + r) * Kd + k0 + c4);
        float4 bv = *(const float4*)(B + (size_t)(col0 + r) * Kd + k0 + c4);
        As[c4 + 0][r] = av.x; As[c4 + 1][r] = av.y;
        As[c4 + 2][r] = av.z; As[c4 + 3][r] = av.w;
        Bs[c4 + 0][r] = bv.x; Bs[c4 + 1][r] = bv.y;
        Bs[c4 + 2][r] = bv.z; Bs[c4 + 3][r] = bv.w;
        __syncthreads();
#pragma unroll
        for (int kk = 0; kk < 16; kk++) {
            float4 a4 = *(const float4*)&As[kk][ty * 4];
            float4 b4 = *(const float4*)&Bs[kk][tx * 4];
            float a[4] = {a4.x, a4.y, a4.z, a4.w};
            float b[4] = {b4.x, b4.y, b4.z, b4.w};
#pragma unroll
            for (int i = 0; i < 4; i++)
#pragma unroll
                for (int j = 0; j < 4; j++)
                    acc[i][j] += a[i] * b[j];
        }
        __syncthreads();
    }
    float scl = scale_ptr ? *scale_ptr : 1.0f;
#pragma unroll
    for (int i = 0; i < 4; i++) {
        int rr = row0 + ty * 4 + i;
#pragma unroll
        for (int j = 0; j < 4; j++) {
            int cc = col0 + tx * 4 + j;
            float v = acc[i][j];
            if (bias) v += bias[cc];
            C[(size_t)rr * N + cc] = v * scl;
        }
    }
}

// ---------------------------------------------------------------------------
// RoPE applied in-place to q and k slices of qkv[S,3072].
// Thread handles one (s,h,d) pair with d<32: updates d and d+32.
// ---------------------------------------------------------------------------
__global__ __launch_bounds__(256) void rope_kernel(
    float* __restrict__ qkv, const float* __restrict__ rope)
{
    int idx = blockIdx.x * blockDim.x + threadIdx.x;  // S*H*32 total
    if (idx >= S_ * H_ * 32) return;
    int d = idx & 31;
    int h = (idx >> 5) & (H_ - 1);
    int s = idx >> 9;
    float r = rope[s * 32 + d];
    float c = cosf(r), sn = sinf(r);
    size_t base = (size_t)s * 3072 + h * 64 + d;
    float q1 = qkv[base], q2 = qkv[base + 32];
    qkv[base]      = q1 * c - q2 * sn;
    qkv[base + 32] = q2 * c + q1 * sn;
    float k1 = qkv[base + 1024], k2 = qkv[base + 1024 + 32];
    qkv[base + 1024]      = k1 * c - k2 * sn;
    qkv[base + 1024 + 32] = k2 * c + k1 * sn;
}

// ---------------------------------------------------------------------------
// Index scores: one block per global query row (n*L+q); 256 threads cover 512 keys.
// score[row][k] = sum_j relu(data_j + rpe_j) * sigmoid(MLP(gate+rpe))_j
// ---------------------------------------------------------------------------
__global__ __launch_bounds__(256) void score_kernel(
    const float* __restrict__ qI, const float* __restrict__ kI,
    const int* __restrict__ coords, const float* __restrict__ rpe_table,
    const float* __restrict__ W1g, const float* __restrict__ b1g,
    const float* __restrict__ W2g, const float* __restrict__ b2g,
    float* __restrict__ scores)
{
    int row = blockIdx.x;          // 0..2047
    int n = row >> 9;              // image index (L=512)
    int tid = threadIdx.x;
    __shared__ float sqI[IDH2_];
    __shared__ float srpe[NBUCK_ * IH_];
    __shared__ float sW1[GH_ * IH_], sb1[GH_], sW2[IH_ * GH_], sb2[IH_];
    if (tid < IDH2_) sqI[tid] = qI[(size_t)row * IDH2_ + tid];
    for (int i = tid; i < NBUCK_ * IH_; i += 256) srpe[i] = rpe_table[i];
    if (tid < 32) sW1[tid] = W1g[tid];
    else if (tid < 64) sW2[tid - 32] = W2g[tid - 32];
    else if (tid < 72) sb1[tid - 64] = b1g[tid - 64];
    else if (tid < 76) sb2[tid - 72] = b2g[tid - 72];
    int pq = coords[row * 2 + 1];
    __syncthreads();
    for (int kk = tid; kk < LI_; kk += 256) {
        int krow = n * LI_ + kk;
        const float* kp = kI + (size_t)krow * IDH2_;
        float dh[8];
#pragma unroll
        for (int hh = 0; hh < 8; hh++) {
            float acc = 0.0f;
#pragma unroll
            for (int d = 0; d < 16; d += 4) {
                float4 kv = *(const float4*)(kp + hh * 16 + d);
                acc += sqI[hh * 16 + d + 0] * kv.x + sqI[hh * 16 + d + 1] * kv.y +
                       sqI[hh * 16 + d + 2] * kv.z + sqI[hh * 16 + d + 3] * kv.w;
            }
            dh[hh] = acc;
        }
        int pk = coords[krow * 2 + 1];
        int rel = pq - pk;
        rel = rel < -MAXREL_ ? -MAXREL_ : (rel > MAXREL_ ? MAXREL_ : rel);
        const float* rp = srpe + (rel + MAXREL_) * IH_;
        float t1[GH_];
#pragma unroll
        for (int g = 0; g < GH_; g++) t1[g] = sb1[g];
#pragma unroll
        for (int j = 0; j < IH_; j++) {
            float gate = dh[IH_ + j] + rp[j];
#pragma unroll
            for (int g = 0; g < GH_; g++) t1[g] += gate * sW1[g * IH_ + j];
        }
#pragma unroll
        for (int g = 0; g < GH_; g++) t1[g] = fmaxf(t1[g], 0.0f);
        float score = 0.0f;
#pragma unroll
        for (int j = 0; j < IH_; j++) {
            float t2 = sb2[j];
#pragma unroll
            for (int g = 0; g < GH_; g++) t2 += t1[g] * sW2[j * GH_ + g];
            float sg = 1.0f / (1.0f + expf(-t2));
            float rs = fmaxf(dh[j] + rp[j], 0.0f);
            score += rs * sg;
        }
        scores[(size_t)row * LI_ + kk] = score;
    }
}

// ---------------------------------------------------------------------------
// Top-K (K=256 of 512) per row. Bitonic sort (ascending) to get threshold
// T = 256th largest, then stable selection matching jax.lax.top_k tie-break
// (scores > T, plus lowest-index ties == T). Emits ascending key indices.
// ---------------------------------------------------------------------------
__global__ __launch_bounds__(256) void topk_kernel(
    const float* __restrict__ scores, int* __restrict__ selidx)
{
    int row = blockIdx.x;
    int tid = threadIdx.x;
    __shared__ float sv[LI_];
    __shared__ float so[LI_];
    const float* src = scores + (size_t)row * LI_;
    for (int i = tid; i < LI_; i += 256) { float v = src[i]; sv[i] = v; so[i] = v; }
    for (int size = 2; size <= LI_; size <<= 1) {
        for (int stride = size >> 1; stride > 0; stride >>= 1) {
            __syncthreads();
            int pos = 2 * tid - (tid & (stride - 1));
            bool asc = ((pos & size) == 0);
            float a = sv[pos], b = sv[pos + stride];
            if ((a > b) == asc) { sv[pos] = b; sv[pos + stride] = a; }
        }
    }
    __syncthreads();
    if (tid == 0) {
        float T = sv[LI_ - K_];   // 256th largest
        int cgt = 0;
        for (int i = 0; i < LI_; i++) cgt += (so[i] > T) ? 1 : 0;
        int ne = K_ - cgt;        // ties to take, lowest index first
        int cnt = 0;
        int* dst = selidx + (size_t)row * K_;
        for (int i = 0; i < LI_ && cnt < K_; i++) {
            float v = so[i];
            bool sel = false;
            if (v > T) sel = true;
            else if (v == T && ne > 0) { sel = true; ne--; }
            if (sel) dst[cnt++] = i;
        }
    }
}

// ---------------------------------------------------------------------------
// Sparse attention: one wave (64 lanes) per (n,h,q). Each lane scores 4 of the
// 256 selected keys, wave-shuffle softmax, then lane d accumulates out[d].
// Block order (n,h,q) keeps the same K/V head-slice hot in L2 for 512 blocks.
// ---------------------------------------------------------------------------
__global__ __launch_bounds__(64) void attn_kernel(
    const float* __restrict__ qkv, const int* __restrict__ selidx,
    float* __restrict__ out)
{
    int bid = blockIdx.x;               // ((n*H + h) * L + q)
    int q  = bid & (LI_ - 1);
    int nh = bid >> 9;
    int h  = nh & (H_ - 1);
    int n  = nh >> 4;
    int lane = threadIdx.x;
    int s = n * LI_ + q;
    __shared__ float sq[DH_];
    __shared__ float sp[K_];
    __shared__ int   skr[K_];
    sq[lane] = qkv[(size_t)s * 3072 + h * 64 + lane] * 0.125f;  // 1/sqrt(64)
    __syncthreads();
    float sc[4];
    int kr[4];
    const int* sel = selidx + (size_t)s * K_;
#pragma unroll
    for (int t = 0; t < 4; t++) {
        int j = t * 64 + lane;
        int krow = n * LI_ + sel[j];
        kr[t] = krow;
        const float* kp = qkv + (size_t)krow * 3072 + 1024 + h * 64;
        float acc = 0.0f;
#pragma unroll
        for (int d = 0; d < 64; d += 4) {
            float4 kv = *(const float4*)(kp + d);
            acc += sq[d] * kv.x + sq[d + 1] * kv.y + sq[d + 2] * kv.z + sq[d + 3] * kv.w;
        }
        sc[t] = acc;
    }
    float m = fmaxf(fmaxf(sc[0], sc[1]), fmaxf(sc[2], sc[3]));
#pragma unroll
    for (int o = 32; o > 0; o >>= 1) m = fmaxf(m, __shfl_xor(m, o, 64));
    float p[4], l = 0.0f;
#pragma unroll
    for (int t = 0; t < 4; t++) { p[t] = __expf(sc[t] - m); l += p[t]; }
#pragma unroll
    for (int o = 32; o > 0; o >>= 1) l += __shfl_xor(l, o, 64);
    float inv = 1.0f / l;
#pragma unroll
    for (int t = 0; t < 4; t++) { sp[t * 64 + lane] = p[t] * inv; skr[t * 64 + lane] = kr[t]; }
    __syncthreads();
    int voff = 2048 + h * 64 + lane;
    float o0 = 0, o1 = 0, o2 = 0, o3 = 0;
#pragma unroll 4
    for (int j = 0; j < K_; j += 4) {
        o0 += sp[j + 0] * qkv[(size_t)skr[j + 0] * 3072 + voff];
        o1 += sp[j + 1] * qkv[(size_t)skr[j + 1] * 3072 + voff];
        o2 += sp[j + 2] * qkv[(size_t)skr[j + 2] * 3072 + voff];
        o3 += sp[j + 3] * qkv[(size_t)skr[j + 3] * 3072 + voff];
    }
    out[(size_t)s * 1024 + h * 64 + lane] = (o0 + o1) + (o2 + o3);
}

// ---------------------------------------------------------------------------
extern "C" void kernel_launch(void* const* d_in, const int* in_sizes, int n_in,
                              void* d_out, int out_size, void* d_ws, size_t ws_size,
                              hipStream_t stream)
{
    const float* hidden  = (const float*)d_in[0];
    const int*   coords  = (const int*)d_in[1];
    // d_in[2] cu_seqlens: structure is fixed (n=4, L=512) per setup_inputs
    const float* rope    = (const float*)d_in[3];
    const float* Wq_idx  = (const float*)d_in[4];
    const float* Wk_idx  = (const float*)d_in[5];
    const float* W1g     = (const float*)d_in[6];
    const float* b1g     = (const float*)d_in[7];
    const float* W2g     = (const float*)d_in[8];
    const float* b2g     = (const float*)d_in[9];
    const float* rpe     = (const float*)d_in[10];
    const float* Wqkv_d  = (const float*)d_in[11];
    const float* bqkv_d  = (const float*)d_in[12];
    const float* Wqkv_u  = (const float*)d_in[13];
    const float* bqkv_u  = (const float*)d_in[14];
    const float* Wp_d    = (const float*)d_in[15];
    const float* bp_d    = (const float*)d_in[16];
    const float* Wp_u    = (const float*)d_in[17];
    const float* bp_u    = (const float*)d_in[18];
    const float* scaler  = (const float*)d_in[19];
    float* out = (float*)d_out;

    // Workspace layout (floats). Total ~11.0M floats = ~44 MB.
    float* ws      = (float*)d_ws;
    float* mid1    = ws;                                  // S*BOT   (reused for mid2)
    float* qkv     = mid1 + (size_t)S_ * BOT_;            // S*3072
    float* qIb     = qkv  + (size_t)S_ * 3 * DIM_;        // S*128
    float* kIb     = qIb  + (size_t)S_ * IDH2_;           // S*128
    float* scoresb = kIb  + (size_t)S_ * IDH2_;           // NIMG*L*L
    int*   selidx  = (int*)(scoresb + (size_t)NIMG_ * LI_ * LI_);  // S*K ints
    float* attout  = (float*)(selidx + (size_t)S_ * K_);  // S*H*DH

    // 1) qkv = (hidden @ Wqkv_d^T + b) @ Wqkv_u^T + b
    gemm_nt<<<dim3(BOT_ / 64, S_ / 64), 256, 0, stream>>>(
        hidden, Wqkv_d, bqkv_d, nullptr, mid1, S_, BOT_, DIM_);
    gemm_nt<<<dim3(3 * DIM_ / 64, S_ / 64), 256, 0, stream>>>(
        mid1, Wqkv_u, bqkv_u, nullptr, qkv, S_, 3 * DIM_, BOT_);

    // 2) RoPE on q,k in place
    rope_kernel<<<(S_ * H_ * 32) / 256, 256, 0, stream>>>(qkv, rope);

    // 3) index projections
    gemm_nt<<<dim3(IDH2_ / 64, S_ / 64), 256, 0, stream>>>(
        hidden, Wq_idx, nullptr, nullptr, qIb, S_, IDH2_, DIM_);
    gemm_nt<<<dim3(IDH2_ / 64, S_ / 64), 256, 0, stream>>>(
        hidden, Wk_idx, nullptr, nullptr, kIb, S_, IDH2_, DIM_);

    // 4) index scores + top-k selection
    score_kernel<<<S_, 256, 0, stream>>>(
        qIb, kIb, coords, rpe, W1g, b1g, W2g, b2g, scoresb);
    topk_kernel<<<S_, 256, 0, stream>>>(scoresb, selidx);

    // 5) sparse attention
    attn_kernel<<<NIMG_ * H_ * LI_, 64, 0, stream>>>(qkv, selidx, attout);

    // 6) output projection (+ scaler fused into final GEMM epilogue)
    gemm_nt<<<dim3(BOT_ / 64, S_ / 64), 256, 0, stream>>>(
        attout, Wp_d, bp_d, nullptr, mid1, S_, BOT_, DIM_);
    gemm_nt<<<dim3(DIM_ / 64, S_ / 64), 256, 0, stream>>>(
        mid1, Wp_u, bp_u, scaler, out, S_, DIM_, BOT_);
}

// Round 4
// 618.240 us; speedup vs baseline: 1.6441x; 1.6441x over previous
//
#include <hip/hip_runtime.h>
#include <hip/hip_bf16.h>

// Problem constants
#define S_    2048
#define DIM_  1024
#define H_    16
#define DH_   64
#define BOT_  256
#define NIMG_ 4
#define LI_   512
#define K_    256
#define IH_   4
#define ID_   16
#define MAXREL_ 64
#define NBUCK_ 129
#define GH_   8
#define IDH2_ 128   // 2*IH*ID

// ---------------------------------------------------------------------------
// Generic fp32 GEMM: C[M,N] = A[M,Kd] @ B[N,Kd]^T (+bias[N]) (*scale)
// 64x64 tile, BK=16, 256 threads, 4x4 per thread, transposed LDS for float4.
// ---------------------------------------------------------------------------
__global__ __launch_bounds__(256) void gemm_nt(
    const float* __restrict__ A, const float* __restrict__ B,
    const float* __restrict__ bias, const float* __restrict__ scale_ptr,
    float* __restrict__ C, int M, int N, int Kd)
{
    __shared__ float As[16][68];
    __shared__ float Bs[16][68];
    int tid = threadIdx.x;
    int tx = tid & 15, ty = tid >> 4;
    int row0 = blockIdx.y * 64, col0 = blockIdx.x * 64;
    float acc[4][4] = {};
    for (int k0 = 0; k0 < Kd; k0 += 16) {
        int r  = tid >> 2;          // 0..63
        int c4 = (tid & 3) * 4;     // 0,4,8,12
        float4 av = *(const float4*)(A + (size_t)(row0 + r) * Kd + k0 + c4);
        float4 bv = *(const float4*)(B + (size_t)(col0 + r) * Kd + k0 + c4);
        As[c4 + 0][r] = av.x; As[c4 + 1][r] = av.y;
        As[c4 + 2][r] = av.z; As[c4 + 3][r] = av.w;
        Bs[c4 + 0][r] = bv.x; Bs[c4 + 1][r] = bv.y;
        Bs[c4 + 2][r] = bv.z; Bs[c4 + 3][r] = bv.w;
        __syncthreads();
#pragma unroll
        for (int kk = 0; kk < 16; kk++) {
            float4 a4 = *(const float4*)&As[kk][ty * 4];
            float4 b4 = *(const float4*)&Bs[kk][tx * 4];
            float a[4] = {a4.x, a4.y, a4.z, a4.w};
            float b[4] = {b4.x, b4.y, b4.z, b4.w};
#pragma unroll
            for (int i = 0; i < 4; i++)
#pragma unroll
                for (int j = 0; j < 4; j++)
                    acc[i][j] += a[i] * b[j];
        }
        __syncthreads();
    }
    float scl = scale_ptr ? *scale_ptr : 1.0f;
#pragma unroll
    for (int i = 0; i < 4; i++) {
        int rr = row0 + ty * 4 + i;
#pragma unroll
        for (int j = 0; j < 4; j++) {
            int cc = col0 + tx * 4 + j;
            float v = acc[i][j];
            if (bias) v += bias[cc];
            C[(size_t)rr * N + cc] = v * scl;
        }
    }
}

// ---------------------------------------------------------------------------
// RoPE applied in-place to q and k slices of qkv[S,3072].
// ---------------------------------------------------------------------------
__global__ __launch_bounds__(256) void rope_kernel(
    float* __restrict__ qkv, const float* __restrict__ rope)
{
    int idx = blockIdx.x * blockDim.x + threadIdx.x;  // S*H*32 total
    if (idx >= S_ * H_ * 32) return;
    int d = idx & 31;
    int h = (idx >> 5) & (H_ - 1);
    int s = idx >> 9;
    float r = rope[s * 32 + d];
    float c = cosf(r), sn = sinf(r);
    size_t base = (size_t)s * 3072 + h * 64 + d;
    float q1 = qkv[base], q2 = qkv[base + 32];
    qkv[base]      = q1 * c - q2 * sn;
    qkv[base + 32] = q2 * c + q1 * sn;
    float k1 = qkv[base + 1024], k2 = qkv[base + 1024 + 32];
    qkv[base + 1024]      = k1 * c - k2 * sn;
    qkv[base + 1024 + 32] = k2 * c + k1 * sn;
}

// ---------------------------------------------------------------------------
// Index scores: one block per global query row; 256 threads cover 512 keys.
// ---------------------------------------------------------------------------
__global__ __launch_bounds__(256) void score_kernel(
    const float* __restrict__ qI, const float* __restrict__ kI,
    const int* __restrict__ coords, const float* __restrict__ rpe_table,
    const float* __restrict__ W1g, const float* __restrict__ b1g,
    const float* __restrict__ W2g, const float* __restrict__ b2g,
    float* __restrict__ scores)
{
    int row = blockIdx.x;          // 0..2047
    int n = row >> 9;              // image index (L=512)
    int tid = threadIdx.x;
    __shared__ float sqI[IDH2_];
    __shared__ float srpe[NBUCK_ * IH_];
    __shared__ float sW1[GH_ * IH_], sb1[GH_], sW2[IH_ * GH_], sb2[IH_];
    if (tid < IDH2_) sqI[tid] = qI[(size_t)row * IDH2_ + tid];
    for (int i = tid; i < NBUCK_ * IH_; i += 256) srpe[i] = rpe_table[i];
    if (tid < 32) sW1[tid] = W1g[tid];
    else if (tid < 64) sW2[tid - 32] = W2g[tid - 32];
    else if (tid < 72) sb1[tid - 64] = b1g[tid - 64];
    else if (tid < 76) sb2[tid - 72] = b2g[tid - 72];
    int pq = coords[row * 2 + 1];
    __syncthreads();
    for (int kk = tid; kk < LI_; kk += 256) {
        int krow = n * LI_ + kk;
        const float* kp = kI + (size_t)krow * IDH2_;
        float dh[8];
#pragma unroll
        for (int hh = 0; hh < 8; hh++) {
            float acc = 0.0f;
#pragma unroll
            for (int d = 0; d < 16; d += 4) {
                float4 kv = *(const float4*)(kp + hh * 16 + d);
                acc += sqI[hh * 16 + d + 0] * kv.x + sqI[hh * 16 + d + 1] * kv.y +
                       sqI[hh * 16 + d + 2] * kv.z + sqI[hh * 16 + d + 3] * kv.w;
            }
            dh[hh] = acc;
        }
        int pk = coords[krow * 2 + 1];
        int rel = pq - pk;
        rel = rel < -MAXREL_ ? -MAXREL_ : (rel > MAXREL_ ? MAXREL_ : rel);
        const float* rp = srpe + (rel + MAXREL_) * IH_;
        float t1[GH_];
#pragma unroll
        for (int g = 0; g < GH_; g++) t1[g] = sb1[g];
#pragma unroll
        for (int j = 0; j < IH_; j++) {
            float gate = dh[IH_ + j] + rp[j];
#pragma unroll
            for (int g = 0; g < GH_; g++) t1[g] += gate * sW1[g * IH_ + j];
        }
#pragma unroll
        for (int g = 0; g < GH_; g++) t1[g] = fmaxf(t1[g], 0.0f);
        float score = 0.0f;
#pragma unroll
        for (int j = 0; j < IH_; j++) {
            float t2 = sb2[j];
#pragma unroll
            for (int g = 0; g < GH_; g++) t2 += t1[g] * sW2[j * GH_ + g];
            float sg = 1.0f / (1.0f + expf(-t2));
            float rs = fmaxf(dh[j] + rp[j], 0.0f);
            score += rs * sg;
        }
        scores[(size_t)row * LI_ + kk] = score;
    }
}

// ---------------------------------------------------------------------------
// Top-K (K=256 of 512) per row. Bitonic sort for threshold, then stable
// selection matching jax.lax.top_k tie-break. Emits a 512-bit membership
// bitmask per row (16 uint32 words).
// ---------------------------------------------------------------------------
__global__ __launch_bounds__(256) void topk_kernel(
    const float* __restrict__ scores, unsigned* __restrict__ selmask)
{
    int row = blockIdx.x;
    int tid = threadIdx.x;
    __shared__ float sv[LI_];
    __shared__ float so[LI_];
    const float* src = scores + (size_t)row * LI_;
    for (int i = tid; i < LI_; i += 256) { float v = src[i]; sv[i] = v; so[i] = v; }
    for (int size = 2; size <= LI_; size <<= 1) {
        for (int stride = size >> 1; stride > 0; stride >>= 1) {
            __syncthreads();
            int pos = 2 * tid - (tid & (stride - 1));
            bool asc = ((pos & size) == 0);
            float a = sv[pos], b = sv[pos + stride];
            if ((a > b) == asc) { sv[pos] = b; sv[pos + stride] = a; }
        }
    }
    __syncthreads();
    if (tid == 0) {
        float T = sv[LI_ - K_];   // 256th largest
        int cgt = 0;
        for (int i = 0; i < LI_; i++) cgt += (so[i] > T) ? 1 : 0;
        int ne = K_ - cgt;        // ties to take, lowest index first
        unsigned um[16];
#pragma unroll
        for (int w = 0; w < 16; w++) um[w] = 0u;
        int cnt = 0;
        for (int i = 0; i < LI_ && cnt < K_; i++) {
            float v = so[i];
            bool sel = false;
            if (v > T) sel = true;
            else if (v == T && ne > 0) { sel = true; ne--; }
            if (sel) { um[i >> 5] |= (1u << (i & 31)); cnt++; }
        }
        unsigned* dst = selmask + (size_t)row * 16;
#pragma unroll
        for (int w = 0; w < 16; w++) dst[w] = um[w];
    }
}

// ---------------------------------------------------------------------------
// Dense-masked tiled attention (fp32). One block per (n, h, 64-query tile):
// grid = 4*16*8 = 512 blocks, 256 threads. Iterates 8 key-tiles of 64:
// stage K^T and V in LDS, GEMM 64x64 scores (4x4/thread), mask via per-query
// 512-bit bitmap, exp (no max-sub: scores are O(1), softmax shift-invariant),
// accumulate PV and per-row sums, normalize at the end.
// LDS: 3x 64x68 f32 buffers + mask = 55 KiB (<64 KiB per-WG limit).
// KPs holds K^T during QK, then is overwritten with P^T for PV; the extra
// barrier between QK and the P write makes the aliasing safe.
// ---------------------------------------------------------------------------
__global__ __launch_bounds__(256) void attn_kernel(
    const float* __restrict__ qkv, const unsigned* __restrict__ selmask,
    float* __restrict__ out)
{
    __shared__ float Qs[64][68];      // [d][q]  (Q scaled by 1/8)
    __shared__ float KPs[64][68];     // QK phase: K^T [d][k]; PV phase: P^T [k][q]
    __shared__ float Vs[64][68];      // [k][d]
    __shared__ unsigned Ms[64][16];   // per-query membership bits

    int b  = blockIdx.x;
    int qt = b & 7;
    int h  = (b >> 3) & 15;
    int n  = b >> 7;
    int tid = threadIdx.x;
    int tx = tid & 15, ty = tid >> 4;
    int q0 = n * LI_ + qt * 64;       // first global query row

    // mask words: 64 q x 16 words
    for (int i = tid; i < 64 * 16; i += 256)
        Ms[i >> 4][i & 15] = selmask[(size_t)(q0 + (i >> 4)) * 16 + (i & 15)];

    // stage Q transposed, pre-scaled by 1/sqrt(64)
#pragma unroll
    for (int m = 0; m < 4; m++) {
        int r = (tid >> 4) + m * 16;
        int c = tid & 15;
        float4 v = *(const float4*)(qkv + (size_t)(q0 + r) * 3072 + h * 64 + c * 4);
        Qs[c * 4 + 0][r] = v.x * 0.125f;
        Qs[c * 4 + 1][r] = v.y * 0.125f;
        Qs[c * 4 + 2][r] = v.z * 0.125f;
        Qs[c * 4 + 3][r] = v.w * 0.125f;
    }

    float o[4][4] = {};
    float rs[4] = {};

    for (int kt = 0; kt < 8; kt++) {
        __syncthreads();   // prev PV reads (KPs,Vs) done before restaging
        // stage K tile (transposed, into KPs) and V tile
#pragma unroll
        for (int m = 0; m < 4; m++) {
            int r = (tid >> 4) + m * 16;
            int c = tid & 15;
            size_t krow = (size_t)(n * LI_ + kt * 64 + r) * 3072 + h * 64;
            float4 kv = *(const float4*)(qkv + krow + 1024 + c * 4);
            KPs[c * 4 + 0][r] = kv.x;
            KPs[c * 4 + 1][r] = kv.y;
            KPs[c * 4 + 2][r] = kv.z;
            KPs[c * 4 + 3][r] = kv.w;
            float4 vv = *(const float4*)(qkv + krow + 2048 + c * 4);
            *(float4*)&Vs[r][c * 4] = vv;
        }
        __syncthreads();

        // QK: s[4q][4k]
        float s[4][4] = {};
#pragma unroll 8
        for (int d = 0; d < 64; d++) {
            float4 a4 = *(const float4*)&Qs[d][ty * 4];
            float4 b4 = *(const float4*)&KPs[d][tx * 4];
            float a[4] = {a4.x, a4.y, a4.z, a4.w};
            float bb[4] = {b4.x, b4.y, b4.z, b4.w};
#pragma unroll
            for (int i = 0; i < 4; i++)
#pragma unroll
                for (int j = 0; j < 4; j++)
                    s[i][j] += a[i] * bb[j];
        }
        __syncthreads();   // all QK reads of KPs complete before P overwrite

        // mask + exp + row-sum partials + write P^T into KPs
        int kbase = kt * 64 + tx * 4;
        int wi = kbase >> 5;
        int bit0 = kbase & 31;
#pragma unroll
        for (int i = 0; i < 4; i++) {
            unsigned mw = Ms[ty * 4 + i][wi];
#pragma unroll
            for (int j = 0; j < 4; j++) {
                float p = ((mw >> (bit0 + j)) & 1u) ? __expf(s[i][j]) : 0.0f;
                rs[i] += p;
                KPs[tx * 4 + j][ty * 4 + i] = p;
            }
        }
        __syncthreads();

        // PV: o[4q][4d] += P^T dot V over this key tile
#pragma unroll 8
        for (int kk = 0; kk < 64; kk++) {
            float4 a4 = *(const float4*)&KPs[kk][ty * 4];
            float4 b4 = *(const float4*)&Vs[kk][tx * 4];
            float a[4] = {a4.x, a4.y, a4.z, a4.w};
            float bb[4] = {b4.x, b4.y, b4.z, b4.w};
#pragma unroll
            for (int i = 0; i < 4; i++)
#pragma unroll
                for (int j = 0; j < 4; j++)
                    o[i][j] += a[i] * bb[j];
        }
    }

    // reduce row sums across the 16 threads (same wave) sharing each q-row
#pragma unroll
    for (int i = 0; i < 4; i++) {
#pragma unroll
        for (int off = 1; off < 16; off <<= 1)
            rs[i] += __shfl_xor(rs[i], off, 64);
    }

    // normalize + store
#pragma unroll
    for (int i = 0; i < 4; i++) {
        float inv = 1.0f / rs[i];
        float4 o4 = make_float4(o[i][0] * inv, o[i][1] * inv, o[i][2] * inv, o[i][3] * inv);
        *(float4*)(out + (size_t)(q0 + ty * 4 + i) * 1024 + h * 64 + tx * 4) = o4;
    }
}

// ---------------------------------------------------------------------------
extern "C" void kernel_launch(void* const* d_in, const int* in_sizes, int n_in,
                              void* d_out, int out_size, void* d_ws, size_t ws_size,
                              hipStream_t stream)
{
    const float* hidden  = (const float*)d_in[0];
    const int*   coords  = (const int*)d_in[1];
    const float* rope    = (const float*)d_in[3];
    const float* Wq_idx  = (const float*)d_in[4];
    const float* Wk_idx  = (const float*)d_in[5];
    const float* W1g     = (const float*)d_in[6];
    const float* b1g     = (const float*)d_in[7];
    const float* W2g     = (const float*)d_in[8];
    const float* b2g     = (const float*)d_in[9];
    const float* rpe     = (const float*)d_in[10];
    const float* Wqkv_d  = (const float*)d_in[11];
    const float* bqkv_d  = (const float*)d_in[12];
    const float* Wqkv_u  = (const float*)d_in[13];
    const float* bqkv_u  = (const float*)d_in[14];
    const float* Wp_d    = (const float*)d_in[15];
    const float* bp_d    = (const float*)d_in[16];
    const float* Wp_u    = (const float*)d_in[17];
    const float* bp_u    = (const float*)d_in[18];
    const float* scaler  = (const float*)d_in[19];
    float* out = (float*)d_out;

    // Workspace layout (floats).
    float* ws      = (float*)d_ws;
    float* mid1    = ws;                                  // S*BOT
    float* qkv     = mid1 + (size_t)S_ * BOT_;            // S*3072
    float* qIb     = qkv  + (size_t)S_ * 3 * DIM_;        // S*128
    float* kIb     = qIb  + (size_t)S_ * IDH2_;           // S*128
    float* scoresb = kIb  + (size_t)S_ * IDH2_;           // NIMG*L*L
    unsigned* selmask = (unsigned*)(scoresb + (size_t)NIMG_ * LI_ * LI_);  // S*16
    float* attout  = (float*)(selmask + (size_t)S_ * 16); // S*H*DH

    // 1) qkv = (hidden @ Wqkv_d^T + b) @ Wqkv_u^T + b
    gemm_nt<<<dim3(BOT_ / 64, S_ / 64), 256, 0, stream>>>(
        hidden, Wqkv_d, bqkv_d, nullptr, mid1, S_, BOT_, DIM_);
    gemm_nt<<<dim3(3 * DIM_ / 64, S_ / 64), 256, 0, stream>>>(
        mid1, Wqkv_u, bqkv_u, nullptr, qkv, S_, 3 * DIM_, BOT_);

    // 2) RoPE on q,k in place
    rope_kernel<<<(S_ * H_ * 32) / 256, 256, 0, stream>>>(qkv, rope);

    // 3) index projections
    gemm_nt<<<dim3(IDH2_ / 64, S_ / 64), 256, 0, stream>>>(
        hidden, Wq_idx, nullptr, nullptr, qIb, S_, IDH2_, DIM_);
    gemm_nt<<<dim3(IDH2_ / 64, S_ / 64), 256, 0, stream>>>(
        hidden, Wk_idx, nullptr, nullptr, kIb, S_, IDH2_, DIM_);

    // 4) index scores + top-k membership bitmask
    score_kernel<<<S_, 256, 0, stream>>>(
        qIb, kIb, coords, rpe, W1g, b1g, W2g, b2g, scoresb);
    topk_kernel<<<S_, 256, 0, stream>>>(scoresb, selmask);

    // 5) dense-masked attention
    attn_kernel<<<NIMG_ * H_ * 8, 256, 0, stream>>>(qkv, selmask, attout);

    // 6) output projection (+ scaler fused into final GEMM epilogue)
    gemm_nt<<<dim3(BOT_ / 64, S_ / 64), 256, 0, stream>>>(
        attout, Wp_d, bp_d, nullptr, mid1, S_, BOT_, DIM_);
    gemm_nt<<<dim3(DIM_ / 64, S_ / 64), 256, 0, stream>>>(
        mid1, Wp_u, bp_u, scaler, out, S_, DIM_, BOT_);
}

// Round 6
// 558.074 us; speedup vs baseline: 1.8214x; 1.1078x over previous
//
#include <hip/hip_runtime.h>
#include <hip/hip_bf16.h>

// Problem constants
#define S_    2048
#define DIM_  1024
#define H_    16
#define DH_   64
#define BOT_  256
#define NIMG_ 4
#define LI_   512
#define K_    256
#define IH_   4
#define ID_   16
#define MAXREL_ 64
#define NBUCK_ 129
#define GH_   8
#define IDH2_ 128   // 2*IH*ID

// ---------------------------------------------------------------------------
// Generic fp32 GEMM: C[M,N] = A[M,Kd] @ B[N,Kd]^T (+bias[N]) (*scale)
// 64x64 tile, BK=16, 256 threads, 4x4 per thread, transposed LDS for float4.
// ---------------------------------------------------------------------------
__global__ __launch_bounds__(256) void gemm_nt(
    const float* __restrict__ A, const float* __restrict__ B,
    const float* __restrict__ bias, const float* __restrict__ scale_ptr,
    float* __restrict__ C, int M, int N, int Kd)
{
    __shared__ float As[16][68];
    __shared__ float Bs[16][68];
    int tid = threadIdx.x;
    int tx = tid & 15, ty = tid >> 4;
    int row0 = blockIdx.y * 64, col0 = blockIdx.x * 64;
    float acc[4][4] = {};
    for (int k0 = 0; k0 < Kd; k0 += 16) {
        int r  = tid >> 2;          // 0..63
        int c4 = (tid & 3) * 4;     // 0,4,8,12
        float4 av = *(const float4*)(A + (size_t)(row0 + r) * Kd + k0 + c4);
        float4 bv = *(const float4*)(B + (size_t)(col0 + r) * Kd + k0 + c4);
        As[c4 + 0][r] = av.x; As[c4 + 1][r] = av.y;
        As[c4 + 2][r] = av.z; As[c4 + 3][r] = av.w;
        Bs[c4 + 0][r] = bv.x; Bs[c4 + 1][r] = bv.y;
        Bs[c4 + 2][r] = bv.z; Bs[c4 + 3][r] = bv.w;
        __syncthreads();
#pragma unroll
        for (int kk = 0; kk < 16; kk++) {
            float4 a4 = *(const float4*)&As[kk][ty * 4];
            float4 b4 = *(const float4*)&Bs[kk][tx * 4];
            float a[4] = {a4.x, a4.y, a4.z, a4.w};
            float b[4] = {b4.x, b4.y, b4.z, b4.w};
#pragma unroll
            for (int i = 0; i < 4; i++)
#pragma unroll
                for (int j = 0; j < 4; j++)
                    acc[i][j] += a[i] * b[j];
        }
        __syncthreads();
    }
    float scl = scale_ptr ? *scale_ptr : 1.0f;
#pragma unroll
    for (int i = 0; i < 4; i++) {
        int rr = row0 + ty * 4 + i;
#pragma unroll
        for (int j = 0; j < 4; j++) {
            int cc = col0 + tx * 4 + j;
            float v = acc[i][j];
            if (bias) v += bias[cc];
            C[(size_t)rr * N + cc] = v * scl;
        }
    }
}

// ---------------------------------------------------------------------------
// RoPE applied in-place to q and k slices of qkv[S,3072].
// ---------------------------------------------------------------------------
__global__ __launch_bounds__(256) void rope_kernel(
    float* __restrict__ qkv, const float* __restrict__ rope)
{
    int idx = blockIdx.x * blockDim.x + threadIdx.x;  // S*H*32 total
    if (idx >= S_ * H_ * 32) return;
    int d = idx & 31;
    int h = (idx >> 5) & (H_ - 1);
    int s = idx >> 9;
    float r = rope[s * 32 + d];
    float c = cosf(r), sn = sinf(r);
    size_t base = (size_t)s * 3072 + h * 64 + d;
    float q1 = qkv[base], q2 = qkv[base + 32];
    qkv[base]      = q1 * c - q2 * sn;
    qkv[base + 32] = q2 * c + q1 * sn;
    float k1 = qkv[base + 1024], k2 = qkv[base + 1024 + 32];
    qkv[base + 1024]      = k1 * c - k2 * sn;
    qkv[base + 1024 + 32] = k2 * c + k1 * sn;
}

// ---------------------------------------------------------------------------
// Fused index scores + top-K membership. One block per query row (2048 blocks,
// 256 threads). Scores stay in LDS as order-preserving uint keys (all scores
// are >= +0.0: relu*sigmoid sums — no -0.0/NaN, so key order == float order
// including ties). Radix select (4x 8-bit histogram passes) finds the exact
// 256th-largest key; selection is parallel via 64-lane ballots with
// jax.lax.top_k tie-break (lowest index first) done by popcount prefix.
// Emits a 512-bit membership bitmask per row (16 uint32 words).
// ---------------------------------------------------------------------------
__global__ __launch_bounds__(256) void score_topk_kernel(
    const float* __restrict__ qI, const float* __restrict__ kI,
    const int* __restrict__ coords, const float* __restrict__ rpe_table,
    const float* __restrict__ W1g, const float* __restrict__ b1g,
    const float* __restrict__ W2g, const float* __restrict__ b2g,
    unsigned* __restrict__ selmask)
{
    int row = blockIdx.x;          // 0..2047
    int n = row >> 9;              // image index (L=512)
    int tid = threadIdx.x;
    __shared__ float sqI[IDH2_];
    __shared__ float srpe[NBUCK_ * IH_];
    __shared__ float sW1[GH_ * IH_], sb1[GH_], sW2[IH_ * GH_], sb2[IH_];
    __shared__ unsigned keys[LI_];
    __shared__ int hist[256];
    __shared__ unsigned gtw[16], eqw[16];
    __shared__ unsigned sprefix;
    __shared__ int skk;

    if (tid < IDH2_) sqI[tid] = qI[(size_t)row * IDH2_ + tid];
    for (int i = tid; i < NBUCK_ * IH_; i += 256) srpe[i] = rpe_table[i];
    if (tid < 32) sW1[tid] = W1g[tid];
    else if (tid < 64) sW2[tid - 32] = W2g[tid - 32];
    else if (tid < 72) sb1[tid - 64] = b1g[tid - 64];
    else if (tid < 76) sb2[tid - 72] = b2g[tid - 72];
    if (tid == 0) { sprefix = 0u; skk = K_; }
    int pq = coords[row * 2 + 1];
    __syncthreads();

    // ---- score computation (identical math to reference) ----
    for (int kk2 = tid; kk2 < LI_; kk2 += 256) {
        int krow = n * LI_ + kk2;
        const float* kp = kI + (size_t)krow * IDH2_;
        float dh[8];
#pragma unroll
        for (int hh = 0; hh < 8; hh++) {
            float acc = 0.0f;
#pragma unroll
            for (int d = 0; d < 16; d += 4) {
                float4 kv = *(const float4*)(kp + hh * 16 + d);
                acc += sqI[hh * 16 + d + 0] * kv.x + sqI[hh * 16 + d + 1] * kv.y +
                       sqI[hh * 16 + d + 2] * kv.z + sqI[hh * 16 + d + 3] * kv.w;
            }
            dh[hh] = acc;
        }
        int pk = coords[krow * 2 + 1];
        int rel = pq - pk;
        rel = rel < -MAXREL_ ? -MAXREL_ : (rel > MAXREL_ ? MAXREL_ : rel);
        const float* rp = srpe + (rel + MAXREL_) * IH_;
        float t1[GH_];
#pragma unroll
        for (int g = 0; g < GH_; g++) t1[g] = sb1[g];
#pragma unroll
        for (int j = 0; j < IH_; j++) {
            float gate = dh[IH_ + j] + rp[j];
#pragma unroll
            for (int g = 0; g < GH_; g++) t1[g] += gate * sW1[g * IH_ + j];
        }
#pragma unroll
        for (int g = 0; g < GH_; g++) t1[g] = fmaxf(t1[g], 0.0f);
        float score = 0.0f;
#pragma unroll
        for (int j = 0; j < IH_; j++) {
            float t2 = sb2[j];
#pragma unroll
            for (int g = 0; g < GH_; g++) t2 += t1[g] * sW2[j * GH_ + g];
            float sg = 1.0f / (1.0f + expf(-t2));
            float rs = fmaxf(dh[j] + rp[j], 0.0f);
            score += rs * sg;
        }
        unsigned bits = __float_as_uint(score);
        keys[kk2] = (bits & 0x80000000u) ? ~bits : (bits | 0x80000000u);
    }
    __syncthreads();

    // ---- radix select: exact key of the K-th largest ----
    const unsigned himask[4] = {0u, 0xFF000000u, 0xFFFF0000u, 0xFFFFFF00u};
#pragma unroll
    for (int pass = 0; pass < 4; pass++) {
        int shift = 24 - pass * 8;
        unsigned hm = himask[pass];
        unsigned pref = sprefix;   // stable since end-of-previous-pass barrier
        int kcur = skk;
        hist[tid] = 0;
        __syncthreads();
        for (int e = tid; e < LI_; e += 256) {
            unsigned key = keys[e];
            if ((key & hm) == pref) atomicAdd(&hist[(key >> shift) & 255], 1);
        }
        __syncthreads();
        // suffix-inclusive scan: hist[b] = #active elements with digit >= b
        for (int off = 1; off < 256; off <<= 1) {
            int add = (tid + off < 256) ? hist[tid + off] : 0;
            __syncthreads();
            hist[tid] += add;
            __syncthreads();
        }
        int above = (tid == 255) ? 0 : hist[tid + 1];
        if (hist[tid] >= kcur && above < kcur) {   // unique winner bin
            sprefix = pref | ((unsigned)tid << shift);
            skk = kcur - above;
        }
        __syncthreads();
    }
    unsigned Tu = sprefix;

    // ---- parallel selection with stable tie-break via ballots ----
    int lane = tid & 63, w = tid >> 6;
    for (int c = w; c < 8; c += 4) {               // wave-uniform loop
        unsigned key = keys[c * 64 + lane];
        unsigned long long bg = __ballot(key > Tu);
        unsigned long long be = __ballot(key == Tu);
        if (lane == 0) {
            gtw[2 * c]     = (unsigned)bg;
            gtw[2 * c + 1] = (unsigned)(bg >> 32);
            eqw[2 * c]     = (unsigned)be;
            eqw[2 * c + 1] = (unsigned)(be >> 32);
        }
    }
    __syncthreads();
    if (tid < 16) {
        int total_gt = 0, base = 0;
#pragma unroll
        for (int i2 = 0; i2 < 16; i2++) {
            total_gt += __popc(gtw[i2]);
            if (i2 < tid) base += __popc(eqw[i2]);
        }
        int ne = K_ - total_gt - base;             // ties this word may take
        unsigned x = eqw[tid];
        int pc = __popc(x);
        int m = ne < 0 ? 0 : (ne > pc ? pc : ne);
        while (pc > m) { x ^= (1u << (31 - __clz(x))); pc--; }  // keep lowest m
        selmask[(size_t)row * 16 + tid] = gtw[tid] | x;
    }
}

// ---------------------------------------------------------------------------
// Dense-masked tiled attention (fp32). One block per (n, h, 64-query tile):
// grid = 4*16*8 = 512 blocks, 256 threads. Iterates 8 key-tiles of 64:
// stage K^T and V in LDS, GEMM 64x64 scores (4x4/thread), mask via per-query
// 512-bit bitmap, exp (no max-sub: scores are O(1), softmax shift-invariant),
// accumulate PV and per-row sums, normalize at the end.
// LDS: 3x 64x68 f32 buffers + mask = 55 KiB (<64 KiB per-WG limit).
// ---------------------------------------------------------------------------
__global__ __launch_bounds__(256) void attn_kernel(
    const float* __restrict__ qkv, const unsigned* __restrict__ selmask,
    float* __restrict__ out)
{
    __shared__ float Qs[64][68];      // [d][q]  (Q scaled by 1/8)
    __shared__ float KPs[64][68];     // QK phase: K^T [d][k]; PV phase: P^T [k][q]
    __shared__ float Vs[64][68];      // [k][d]
    __shared__ unsigned Ms[64][16];   // per-query membership bits

    int b  = blockIdx.x;
    int qt = b & 7;
    int h  = (b >> 3) & 15;
    int n  = b >> 7;
    int tid = threadIdx.x;
    int tx = tid & 15, ty = tid >> 4;
    int q0 = n * LI_ + qt * 64;       // first global query row

    for (int i = tid; i < 64 * 16; i += 256)
        Ms[i >> 4][i & 15] = selmask[(size_t)(q0 + (i >> 4)) * 16 + (i & 15)];

#pragma unroll
    for (int m = 0; m < 4; m++) {
        int r = (tid >> 4) + m * 16;
        int c = tid & 15;
        float4 v = *(const float4*)(qkv + (size_t)(q0 + r) * 3072 + h * 64 + c * 4);
        Qs[c * 4 + 0][r] = v.x * 0.125f;
        Qs[c * 4 + 1][r] = v.y * 0.125f;
        Qs[c * 4 + 2][r] = v.z * 0.125f;
        Qs[c * 4 + 3][r] = v.w * 0.125f;
    }

    float o[4][4] = {};
    float rs[4] = {};

    for (int kt = 0; kt < 8; kt++) {
        __syncthreads();   // prev PV reads (KPs,Vs) done before restaging
#pragma unroll
        for (int m = 0; m < 4; m++) {
            int r = (tid >> 4) + m * 16;
            int c = tid & 15;
            size_t krow = (size_t)(n * LI_ + kt * 64 + r) * 3072 + h * 64;
            float4 kv = *(const float4*)(qkv + krow + 1024 + c * 4);
            KPs[c * 4 + 0][r] = kv.x;
            KPs[c * 4 + 1][r] = kv.y;
            KPs[c * 4 + 2][r] = kv.z;
            KPs[c * 4 + 3][r] = kv.w;
            float4 vv = *(const float4*)(qkv + krow + 2048 + c * 4);
            *(float4*)&Vs[r][c * 4] = vv;
        }
        __syncthreads();

        float s[4][4] = {};
#pragma unroll 8
        for (int d = 0; d < 64; d++) {
            float4 a4 = *(const float4*)&Qs[d][ty * 4];
            float4 b4 = *(const float4*)&KPs[d][tx * 4];
            float a[4] = {a4.x, a4.y, a4.z, a4.w};
            float bb[4] = {b4.x, b4.y, b4.z, b4.w};
#pragma unroll
            for (int i = 0; i < 4; i++)
#pragma unroll
                for (int j = 0; j < 4; j++)
                    s[i][j] += a[i] * bb[j];
        }
        __syncthreads();   // all QK reads of KPs complete before P overwrite

        int kbase = kt * 64 + tx * 4;
        int wi = kbase >> 5;
        int bit0 = kbase & 31;
#pragma unroll
        for (int i = 0; i < 4; i++) {
            unsigned mw = Ms[ty * 4 + i][wi];
#pragma unroll
            for (int j = 0; j < 4; j++) {
                float p = ((mw >> (bit0 + j)) & 1u) ? __expf(s[i][j]) : 0.0f;
                rs[i] += p;
                KPs[tx * 4 + j][ty * 4 + i] = p;
            }
        }
        __syncthreads();

#pragma unroll 8
        for (int kk = 0; kk < 64; kk++) {
            float4 a4 = *(const float4*)&KPs[kk][ty * 4];
            float4 b4 = *(const float4*)&Vs[kk][tx * 4];
            float a[4] = {a4.x, a4.y, a4.z, a4.w};
            float bb[4] = {b4.x, b4.y, b4.z, b4.w};
#pragma unroll
            for (int i = 0; i < 4; i++)
#pragma unroll
                for (int j = 0; j < 4; j++)
                    o[i][j] += a[i] * bb[j];
        }
    }

#pragma unroll
    for (int i = 0; i < 4; i++) {
#pragma unroll
        for (int off = 1; off < 16; off <<= 1)
            rs[i] += __shfl_xor(rs[i], off, 64);
    }

#pragma unroll
    for (int i = 0; i < 4; i++) {
        float inv = 1.0f / rs[i];
        float4 o4 = make_float4(o[i][0] * inv, o[i][1] * inv, o[i][2] * inv, o[i][3] * inv);
        *(float4*)(out + (size_t)(q0 + ty * 4 + i) * 1024 + h * 64 + tx * 4) = o4;
    }
}

// ---------------------------------------------------------------------------
extern "C" void kernel_launch(void* const* d_in, const int* in_sizes, int n_in,
                              void* d_out, int out_size, void* d_ws, size_t ws_size,
                              hipStream_t stream)
{
    const float* hidden  = (const float*)d_in[0];
    const int*   coords  = (const int*)d_in[1];
    const float* rope    = (const float*)d_in[3];
    const float* Wq_idx  = (const float*)d_in[4];
    const float* Wk_idx  = (const float*)d_in[5];
    const float* W1g     = (const float*)d_in[6];
    const float* b1g     = (const float*)d_in[7];
    const float* W2g     = (const float*)d_in[8];
    const float* b2g     = (const float*)d_in[9];
    const float* rpe     = (const float*)d_in[10];
    const float* Wqkv_d  = (const float*)d_in[11];
    const float* bqkv_d  = (const float*)d_in[12];
    const float* Wqkv_u  = (const float*)d_in[13];
    const float* bqkv_u  = (const float*)d_in[14];
    const float* Wp_d    = (const float*)d_in[15];
    const float* bp_d    = (const float*)d_in[16];
    const float* Wp_u    = (const float*)d_in[17];
    const float* bp_u    = (const float*)d_in[18];
    const float* scaler  = (const float*)d_in[19];
    float* out = (float*)d_out;

    // Workspace layout (floats).
    float* ws      = (float*)d_ws;
    float* mid1    = ws;                                  // S*BOT
    float* qkv     = mid1 + (size_t)S_ * BOT_;            // S*3072
    float* qIb     = qkv  + (size_t)S_ * 3 * DIM_;        // S*128
    float* kIb     = qIb  + (size_t)S_ * IDH2_;           // S*128
    unsigned* selmask = (unsigned*)(kIb + (size_t)S_ * IDH2_);  // S*16
    float* attout  = (float*)(selmask + (size_t)S_ * 16); // S*H*DH

    // 1) qkv = (hidden @ Wqkv_d^T + b) @ Wqkv_u^T + b
    gemm_nt<<<dim3(BOT_ / 64, S_ / 64), 256, 0, stream>>>(
        hidden, Wqkv_d, bqkv_d, nullptr, mid1, S_, BOT_, DIM_);
    gemm_nt<<<dim3(3 * DIM_ / 64, S_ / 64), 256, 0, stream>>>(
        mid1, Wqkv_u, bqkv_u, nullptr, qkv, S_, 3 * DIM_, BOT_);

    // 2) RoPE on q,k in place
    rope_kernel<<<(S_ * H_ * 32) / 256, 256, 0, stream>>>(qkv, rope);

    // 3) index projections
    gemm_nt<<<dim3(IDH2_ / 64, S_ / 64), 256, 0, stream>>>(
        hidden, Wq_idx, nullptr, nullptr, qIb, S_, IDH2_, DIM_);
    gemm_nt<<<dim3(IDH2_ / 64, S_ / 64), 256, 0, stream>>>(
        hidden, Wk_idx, nullptr, nullptr, kIb, S_, IDH2_, DIM_);

    // 4) fused index scores + top-k membership bitmask
    score_topk_kernel<<<S_, 256, 0, stream>>>(
        qIb, kIb, coords, rpe, W1g, b1g, W2g, b2g, selmask);

    // 5) dense-masked attention
    attn_kernel<<<NIMG_ * H_ * 8, 256, 0, stream>>>(qkv, selmask, attout);

    // 6) output projection (+ scaler fused into final GEMM epilogue)
    gemm_nt<<<dim3(BOT_ / 64, S_ / 64), 256, 0, stream>>>(
        attout, Wp_d, bp_d, nullptr, mid1, S_, BOT_, DIM_);
    gemm_nt<<<dim3(DIM_ / 64, S_ / 64), 256, 0, stream>>>(
        mid1, Wp_u, bp_u, scaler, out, S_, DIM_, BOT_);
}

// Round 8
// 476.042 us; speedup vs baseline: 2.1353x; 1.1723x over previous
//
#include <hip/hip_runtime.h>
#include <hip/hip_bf16.h>

// Problem constants
#define S_    2048
#define DIM_  1024
#define H_    16
#define DH_   64
#define BOT_  256
#define NIMG_ 4
#define LI_   512
#define K_    256
#define IH_   4
#define ID_   16
#define MAXREL_ 64
#define NBUCK_ 129
#define GH_   8
#define IDH2_ 128   // 2*IH*ID

// ---------------------------------------------------------------------------
// Generic fp32 GEMM: C[M,N] = A[M,Kd] @ B[N,Kd]^T (+bias[N]) (*scale)
// 64x64 tile, BK=16, 256 threads, 4x4 per thread, transposed LDS for float4.
// ---------------------------------------------------------------------------
__global__ __launch_bounds__(256) void gemm_nt(
    const float* __restrict__ A, const float* __restrict__ B,
    const float* __restrict__ bias, const float* __restrict__ scale_ptr,
    float* __restrict__ C, int M, int N, int Kd)
{
    __shared__ float As[16][68];
    __shared__ float Bs[16][68];
    int tid = threadIdx.x;
    int tx = tid & 15, ty = tid >> 4;
    int row0 = blockIdx.y * 64, col0 = blockIdx.x * 64;
    float acc[4][4] = {};
    for (int k0 = 0; k0 < Kd; k0 += 16) {
        int r  = tid >> 2;          // 0..63
        int c4 = (tid & 3) * 4;     // 0,4,8,12
        float4 av = *(const float4*)(A + (size_t)(row0 + r) * Kd + k0 + c4);
        float4 bv = *(const float4*)(B + (size_t)(col0 + r) * Kd + k0 + c4);
        As[c4 + 0][r] = av.x; As[c4 + 1][r] = av.y;
        As[c4 + 2][r] = av.z; As[c4 + 3][r] = av.w;
        Bs[c4 + 0][r] = bv.x; Bs[c4 + 1][r] = bv.y;
        Bs[c4 + 2][r] = bv.z; Bs[c4 + 3][r] = bv.w;
        __syncthreads();
#pragma unroll
        for (int kk = 0; kk < 16; kk++) {
            float4 a4 = *(const float4*)&As[kk][ty * 4];
            float4 b4 = *(const float4*)&Bs[kk][tx * 4];
            float a[4] = {a4.x, a4.y, a4.z, a4.w};
            float b[4] = {b4.x, b4.y, b4.z, b4.w};
#pragma unroll
            for (int i = 0; i < 4; i++)
#pragma unroll
                for (int j = 0; j < 4; j++)
                    acc[i][j] += a[i] * b[j];
        }
        __syncthreads();
    }
    float scl = scale_ptr ? *scale_ptr : 1.0f;
#pragma unroll
    for (int i = 0; i < 4; i++) {
        int rr = row0 + ty * 4 + i;
#pragma unroll
        for (int j = 0; j < 4; j++) {
            int cc = col0 + tx * 4 + j;
            float v = acc[i][j];
            if (bias) v += bias[cc];
            C[(size_t)rr * N + cc] = v * scl;
        }
    }
}

// ---------------------------------------------------------------------------
// RoPE applied in-place to q and k slices of qkv[S,3072].
// ---------------------------------------------------------------------------
__global__ __launch_bounds__(256) void rope_kernel(
    float* __restrict__ qkv, const float* __restrict__ rope)
{
    int idx = blockIdx.x * blockDim.x + threadIdx.x;  // S*H*32 total
    if (idx >= S_ * H_ * 32) return;
    int d = idx & 31;
    int h = (idx >> 5) & (H_ - 1);
    int s = idx >> 9;
    float r = rope[s * 32 + d];
    float c = cosf(r), sn = sinf(r);
    size_t base = (size_t)s * 3072 + h * 64 + d;
    float q1 = qkv[base], q2 = qkv[base + 32];
    qkv[base]      = q1 * c - q2 * sn;
    qkv[base + 32] = q2 * c + q1 * sn;
    float k1 = qkv[base + 1024], k2 = qkv[base + 1024 + 32];
    qkv[base + 1024]      = k1 * c - k2 * sn;
    qkv[base + 1024 + 32] = k2 * c + k1 * sn;
}

// ---------------------------------------------------------------------------
// Fused index scores + top-K membership, v2 (fixed qI staging).
// 4 query rows per block (512 blocks, 256 threads = 4 waves). kI is staged
// through LDS in 64-key tiles and reused by all 4 rows; one (q,k) pair per
// thread per tile. Keys (order-preserving uints; scores >= +0.0) land in
// LDS. Selection: one row per wave — per-wave radix select (4x 8-bit
// passes) with wave-shuffle suffix scan (no block barriers inside a pass),
// then in-register ballot masks with jax.lax.top_k lowest-index tie-break.
// ---------------------------------------------------------------------------
__global__ __launch_bounds__(256) void score_topk_kernel(
    const float* __restrict__ qI, const float* __restrict__ kI,
    const int* __restrict__ coords, const float* __restrict__ rpe_table,
    const float* __restrict__ W1g, const float* __restrict__ b1g,
    const float* __restrict__ W2g, const float* __restrict__ b2g,
    unsigned* __restrict__ selmask)
{
    __shared__ float skI[64][132];          // kI tile, padded (132%32=4)
    __shared__ float sqI2[4][IDH2_];        // 4 query rows of qI
    __shared__ unsigned skeys[4][LI_];      // per-row score keys
    __shared__ int shist[4][256];           // per-wave radix histogram
    __shared__ float srpe[NBUCK_ * IH_];
    __shared__ float sW1[GH_ * IH_], sb1[GH_], sW2[IH_ * GH_], sb2[IH_];

    int tid  = threadIdx.x;
    int lane = tid & 63;
    int wv   = tid >> 6;                    // wave index = local query row
    int row  = blockIdx.x * 4 + wv;         // this wave's global query row
    int n    = (blockIdx.x * 4) >> 9;       // image (4 rows never cross)

    // ---- stage tables + qI rows ----
    for (int i = tid; i < NBUCK_ * IH_; i += 256) srpe[i] = rpe_table[i];
    if (tid < 32) sW1[tid] = W1g[tid];
    else if (tid < 64) sW2[tid - 32] = W2g[tid - 32];
    else if (tid < 72) sb1[tid - 64] = b1g[tid - 64];
    else if (tid < 76) sb2[tid - 72] = b2g[tid - 72];
    for (int i = tid; i < 4 * IDH2_; i += 256)   // FIX: was `if (tid < 512)` with 256 threads
        sqI2[i >> 7][i & 127] =
            qI[(size_t)(blockIdx.x * 4 + (i >> 7)) * IDH2_ + (i & 127)];
    int pq = coords[row * 2 + 1];

    // ---- score phase: 8 tiles of 64 keys ----
    for (int kt = 0; kt < 8; kt++) {
        __syncthreads();                    // previous tile fully consumed
        {   // stage kI tile: thread covers row tid>>2, 32 floats
            int r  = tid >> 2;
            int d0 = (tid & 3) * 32;
            const float* src = kI + (size_t)(n * LI_ + kt * 64 + r) * IDH2_ + d0;
#pragma unroll
            for (int j = 0; j < 8; j++)
                *(float4*)&skI[r][d0 + j * 4] = *(const float4*)(src + j * 4);
        }
        __syncthreads();

        int kloc = lane;                    // key within tile
        int kg   = kt * 64 + kloc;          // key within image row
        const float* sq = &sqI2[wv][0];
        float dh[8];
#pragma unroll
        for (int hh = 0; hh < 8; hh++) {
            float acc = 0.0f;
#pragma unroll
            for (int d = 0; d < 16; d += 4) {
                float4 kv = *(const float4*)&skI[kloc][hh * 16 + d];
                acc += sq[hh * 16 + d + 0] * kv.x + sq[hh * 16 + d + 1] * kv.y +
                       sq[hh * 16 + d + 2] * kv.z + sq[hh * 16 + d + 3] * kv.w;
            }
            dh[hh] = acc;
        }
        int pk = coords[(n * LI_ + kg) * 2 + 1];
        int rel = pq - pk;
        rel = rel < -MAXREL_ ? -MAXREL_ : (rel > MAXREL_ ? MAXREL_ : rel);
        const float* rp = srpe + (rel + MAXREL_) * IH_;
        float t1[GH_];
#pragma unroll
        for (int g = 0; g < GH_; g++) t1[g] = sb1[g];
#pragma unroll
        for (int j = 0; j < IH_; j++) {
            float gate = dh[IH_ + j] + rp[j];
#pragma unroll
            for (int g = 0; g < GH_; g++) t1[g] += gate * sW1[g * IH_ + j];
        }
#pragma unroll
        for (int g = 0; g < GH_; g++) t1[g] = fmaxf(t1[g], 0.0f);
        float score = 0.0f;
#pragma unroll
        for (int j = 0; j < IH_; j++) {
            float t2 = sb2[j];
#pragma unroll
            for (int g = 0; g < GH_; g++) t2 += t1[g] * sW2[j * GH_ + g];
            float sg = 1.0f / (1.0f + expf(-t2));
            float rs = fmaxf(dh[j] + rp[j], 0.0f);
            score += rs * sg;
        }
        unsigned bits = __float_as_uint(score);
        skeys[wv][kg] = (bits & 0x80000000u) ? ~bits : (bits | 0x80000000u);
    }
    __syncthreads();

    // ---- per-wave radix select: exact key of the K-th largest ----
    unsigned pref = 0u;
    int kcur = K_;
    const unsigned himask[4] = {0u, 0xFF000000u, 0xFFFF0000u, 0xFFFFFF00u};
#pragma unroll
    for (int pass = 0; pass < 4; pass++) {
        int shift = 24 - pass * 8;
        unsigned hm = himask[pass];
        *(int4*)&shist[wv][4 * lane] = make_int4(0, 0, 0, 0);
        __syncthreads();
#pragma unroll
        for (int c = 0; c < 8; c++) {
            unsigned key = skeys[wv][c * 64 + lane];
            if ((key & hm) == pref) atomicAdd(&shist[wv][(key >> shift) & 255], 1);
        }
        __syncthreads();
        int4 b4 = *(const int4*)&shist[wv][4 * lane];
        int b[4] = {b4.x, b4.y, b4.z, b4.w};
        int t = b[0] + b[1] + b[2] + b[3];
        int Ssum = t;
#pragma unroll
        for (int off = 1; off < 64; off <<= 1) {
            int u = __shfl_down(Ssum, off, 64);
            if (lane + off < 64) Ssum += u;
        }
        int E = Ssum - t;                    // suffix of lanes > this one
        int cs[5];
        cs[4] = E;
        cs[3] = b[3] + E;
        cs[2] = b[2] + cs[3];
        cs[1] = b[1] + cs[2];
        cs[0] = b[0] + cs[1];
        bool found = false;
        unsigned cpref = 0u; int ck = 0;
#pragma unroll
        for (int j = 0; j < 4; j++) {
            if (!found && cs[j] >= kcur && cs[j + 1] < kcur) {
                found = true;
                cpref = pref | ((unsigned)(4 * lane + j) << shift);
                ck = kcur - cs[j + 1];
            }
        }
        unsigned long long bm = __ballot(found);
        int src = __ffsll((long long)bm) - 1;   // exactly one winner lane
        pref = (unsigned)__shfl((int)cpref, src, 64);
        kcur = __shfl(ck, src, 64);
        __syncthreads();
    }
    unsigned Tu = pref;

    // ---- membership masks, all in registers (ballots are wave-uniform) ----
    unsigned long long bg[8], be[8];
#pragma unroll
    for (int c = 0; c < 8; c++) {
        unsigned key = skeys[wv][c * 64 + lane];
        bg[c] = __ballot(key > Tu);
        be[c] = __ballot(key == Tu);
    }
    if (lane < 16) {
        int total_gt = 0;
#pragma unroll
        for (int c = 0; c < 8; c++) total_gt += __popcll(bg[c]);
        int base = 0;
#pragma unroll
        for (int c = 0; c < 8; c++) {
            if (2 * c < lane)     base += __popc((unsigned)be[c]);
            if (2 * c + 1 < lane) base += __popc((unsigned)(be[c] >> 32));
        }
        unsigned gw = (unsigned)(bg[lane >> 1] >> (32 * (lane & 1)));
        unsigned ew = (unsigned)(be[lane >> 1] >> (32 * (lane & 1)));
        int ne = K_ - total_gt - base;       // ties this word may take
        int pc = __popc(ew);
        int m = ne < 0 ? 0 : (ne > pc ? pc : ne);
        while (pc > m) { ew ^= (1u << (31 - __clz(ew))); pc--; }  // keep lowest
        selmask[(size_t)row * 16 + lane] = gw | ew;
    }
}

// ---------------------------------------------------------------------------
// Dense-masked tiled attention (fp32). One block per (n, h, 64-query tile):
// grid = 4*16*8 = 512 blocks, 256 threads. Iterates 8 key-tiles of 64:
// stage K^T and V in LDS, GEMM 64x64 scores (4x4/thread), mask via per-query
// 512-bit bitmap, exp (no max-sub: scores are O(1), softmax shift-invariant),
// accumulate PV and per-row sums, normalize at the end.
// LDS: 3x 64x68 f32 buffers + mask = 55 KiB (<64 KiB per-WG limit).
// ---------------------------------------------------------------------------
__global__ __launch_bounds__(256) void attn_kernel(
    const float* __restrict__ qkv, const unsigned* __restrict__ selmask,
    float* __restrict__ out)
{
    __shared__ float Qs[64][68];      // [d][q]  (Q scaled by 1/8)
    __shared__ float KPs[64][68];     // QK phase: K^T [d][k]; PV phase: P^T [k][q]
    __shared__ float Vs[64][68];      // [k][d]
    __shared__ unsigned Ms[64][16];   // per-query membership bits

    int b  = blockIdx.x;
    int qt = b & 7;
    int h  = (b >> 3) & 15;
    int n  = b >> 7;
    int tid = threadIdx.x;
    int tx = tid & 15, ty = tid >> 4;
    int q0 = n * LI_ + qt * 64;       // first global query row

    for (int i = tid; i < 64 * 16; i += 256)
        Ms[i >> 4][i & 15] = selmask[(size_t)(q0 + (i >> 4)) * 16 + (i & 15)];

#pragma unroll
    for (int m = 0; m < 4; m++) {
        int r = (tid >> 4) + m * 16;
        int c = tid & 15;
        float4 v = *(const float4*)(qkv + (size_t)(q0 + r) * 3072 + h * 64 + c * 4);
        Qs[c * 4 + 0][r] = v.x * 0.125f;
        Qs[c * 4 + 1][r] = v.y * 0.125f;
        Qs[c * 4 + 2][r] = v.z * 0.125f;
        Qs[c * 4 + 3][r] = v.w * 0.125f;
    }

    float o[4][4] = {};
    float rs[4] = {};

    for (int kt = 0; kt < 8; kt++) {
        __syncthreads();   // prev PV reads (KPs,Vs) done before restaging
#pragma unroll
        for (int m = 0; m < 4; m++) {
            int r = (tid >> 4) + m * 16;
            int c = tid & 15;
            size_t krow = (size_t)(n * LI_ + kt * 64 + r) * 3072 + h * 64;
            float4 kv = *(const float4*)(qkv + krow + 1024 + c * 4);
            KPs[c * 4 + 0][r] = kv.x;
            KPs[c * 4 + 1][r] = kv.y;
            KPs[c * 4 + 2][r] = kv.z;
            KPs[c * 4 + 3][r] = kv.w;
            float4 vv = *(const float4*)(qkv + krow + 2048 + c * 4);
            *(float4*)&Vs[r][c * 4] = vv;
        }
        __syncthreads();

        float s[4][4] = {};
#pragma unroll 8
        for (int d = 0; d < 64; d++) {
            float4 a4 = *(const float4*)&Qs[d][ty * 4];
            float4 b4 = *(const float4*)&KPs[d][tx * 4];
            float a[4] = {a4.x, a4.y, a4.z, a4.w};
            float bb[4] = {b4.x, b4.y, b4.z, b4.w};
#pragma unroll
            for (int i = 0; i < 4; i++)
#pragma unroll
                for (int j = 0; j < 4; j++)
                    s[i][j] += a[i] * bb[j];
        }
        __syncthreads();   // all QK reads of KPs complete before P overwrite

        int kbase = kt * 64 + tx * 4;
        int wi = kbase >> 5;
        int bit0 = kbase & 31;
#pragma unroll
        for (int i = 0; i < 4; i++) {
            unsigned mw = Ms[ty * 4 + i][wi];
#pragma unroll
            for (int j = 0; j < 4; j++) {
                float p = ((mw >> (bit0 + j)) & 1u) ? __expf(s[i][j]) : 0.0f;
                rs[i] += p;
                KPs[tx * 4 + j][ty * 4 + i] = p;
            }
        }
        __syncthreads();

#pragma unroll 8
        for (int kk = 0; kk < 64; kk++) {
            float4 a4 = *(const float4*)&KPs[kk][ty * 4];
            float4 b4 = *(const float4*)&Vs[kk][tx * 4];
            float a[4] = {a4.x, a4.y, a4.z, a4.w};
            float bb[4] = {b4.x, b4.y, b4.z, b4.w};
#pragma unroll
            for (int i = 0; i < 4; i++)
#pragma unroll
                for (int j = 0; j < 4; j++)
                    o[i][j] += a[i] * bb[j];
        }
    }

#pragma unroll
    for (int i = 0; i < 4; i++) {
#pragma unroll
        for (int off = 1; off < 16; off <<= 1)
            rs[i] += __shfl_xor(rs[i], off, 64);
    }

#pragma unroll
    for (int i = 0; i < 4; i++) {
        float inv = 1.0f / rs[i];
        float4 o4 = make_float4(o[i][0] * inv, o[i][1] * inv, o[i][2] * inv, o[i][3] * inv);
        *(float4*)(out + (size_t)(q0 + ty * 4 + i) * 1024 + h * 64 + tx * 4) = o4;
    }
}

// ---------------------------------------------------------------------------
extern "C" void kernel_launch(void* const* d_in, const int* in_sizes, int n_in,
                              void* d_out, int out_size, void* d_ws, size_t ws_size,
                              hipStream_t stream)
{
    const float* hidden  = (const float*)d_in[0];
    const int*   coords  = (const int*)d_in[1];
    const float* rope    = (const float*)d_in[3];
    const float* Wq_idx  = (const float*)d_in[4];
    const float* Wk_idx  = (const float*)d_in[5];
    const float* W1g     = (const float*)d_in[6];
    const float* b1g     = (const float*)d_in[7];
    const float* W2g     = (const float*)d_in[8];
    const float* b2g     = (const float*)d_in[9];
    const float* rpe     = (const float*)d_in[10];
    const float* Wqkv_d  = (const float*)d_in[11];
    const float* bqkv_d  = (const float*)d_in[12];
    const float* Wqkv_u  = (const float*)d_in[13];
    const float* bqkv_u  = (const float*)d_in[14];
    const float* Wp_d    = (const float*)d_in[15];
    const float* bp_d    = (const float*)d_in[16];
    const float* Wp_u    = (const float*)d_in[17];
    const float* bp_u    = (const float*)d_in[18];
    const float* scaler  = (const float*)d_in[19];
    float* out = (float*)d_out;

    // Workspace layout (floats).
    float* ws      = (float*)d_ws;
    float* mid1    = ws;                                  // S*BOT
    float* qkv     = mid1 + (size_t)S_ * BOT_;            // S*3072
    float* qIb     = qkv  + (size_t)S_ * 3 * DIM_;        // S*128
    float* kIb     = qIb  + (size_t)S_ * IDH2_;           // S*128
    unsigned* selmask = (unsigned*)(kIb + (size_t)S_ * IDH2_);  // S*16
    float* attout  = (float*)(selmask + (size_t)S_ * 16); // S*H*DH

    // 1) qkv = (hidden @ Wqkv_d^T + b) @ Wqkv_u^T + b
    gemm_nt<<<dim3(BOT_ / 64, S_ / 64), 256, 0, stream>>>(
        hidden, Wqkv_d, bqkv_d, nullptr, mid1, S_, BOT_, DIM_);
    gemm_nt<<<dim3(3 * DIM_ / 64, S_ / 64), 256, 0, stream>>>(
        mid1, Wqkv_u, bqkv_u, nullptr, qkv, S_, 3 * DIM_, BOT_);

    // 2) RoPE on q,k in place
    rope_kernel<<<(S_ * H_ * 32) / 256, 256, 0, stream>>>(qkv, rope);

    // 3) index projections
    gemm_nt<<<dim3(IDH2_ / 64, S_ / 64), 256, 0, stream>>>(
        hidden, Wq_idx, nullptr, nullptr, qIb, S_, IDH2_, DIM_);
    gemm_nt<<<dim3(IDH2_ / 64, S_ / 64), 256, 0, stream>>>(
        hidden, Wk_idx, nullptr, nullptr, kIb, S_, IDH2_, DIM_);

    // 4) fused index scores + top-k membership bitmask (4 rows/block)
    score_topk_kernel<<<S_ / 4, 256, 0, stream>>>(
        qIb, kIb, coords, rpe, W1g, b1g, W2g, b2g, selmask);

    // 5) dense-masked attention
    attn_kernel<<<NIMG_ * H_ * 8, 256, 0, stream>>>(qkv, selmask, attout);

    // 6) output projection (+ scaler fused into final GEMM epilogue)
    gemm_nt<<<dim3(BOT_ / 64, S_ / 64), 256, 0, stream>>>(
        attout, Wp_d, bp_d, nullptr, mid1, S_, BOT_, DIM_);
    gemm_nt<<<dim3(DIM_ / 64, S_ / 64), 256, 0, stream>>>(
        mid1, Wp_u, bp_u, scaler, out, S_, DIM_, BOT_);
}

// Round 9
// 366.776 us; speedup vs baseline: 2.7714x; 1.2979x over previous
//
#include <hip/hip_runtime.h>
#include <hip/hip_bf16.h>

// Problem constants
#define S_    2048
#define DIM_  1024
#define H_    16
#define DH_   64
#define BOT_  256
#define NIMG_ 4
#define LI_   512
#define K_    256
#define IH_   4
#define ID_   16
#define MAXREL_ 64
#define NBUCK_ 129
#define GH_   8
#define IDH2_ 128   // 2*IH*ID

typedef short bf16x8 __attribute__((ext_vector_type(8)));
typedef float f32x4  __attribute__((ext_vector_type(4)));

__device__ __forceinline__ unsigned short f2bf(float x) {   // RNE float->bf16
    unsigned u = __float_as_uint(x);
    return (unsigned short)((u + 0x7fffu + ((u >> 16) & 1u)) >> 16);
}
__device__ __forceinline__ float bf2f(unsigned short h) {
    return __uint_as_float(((unsigned)h) << 16);
}

// Split-region element offsets (ushort units), compile-time:
#define NHID_   2097152                      // hidden 2048x1024
#define OFF_WQKVD_ 2097152                   // 256x1024
#define OFF_WQKVU_ 2359296                   // 3072x256
#define OFF_WQ_    3145728                   // 128x1024
#define OFF_WK_    3276800                   // 128x1024
#define OFF_WPD_   3407872                   // 256x1024
#define OFF_WPU_   3670016                   // 1024x256
#define NSPLIT_    3932160

// ---------------------------------------------------------------------------
// Fused hi/lo bf16 split of hidden + all 6 weight matrices (one launch).
// x = bf2f(hi) + bf2f(lo) to ~2^-17 relative.
// ---------------------------------------------------------------------------
__global__ __launch_bounds__(256) void split_all_kernel(
    const float* __restrict__ hid, const float* __restrict__ wqd,
    const float* __restrict__ wqu, const float* __restrict__ wq,
    const float* __restrict__ wk,  const float* __restrict__ wpd,
    const float* __restrict__ wpu,
    unsigned short* __restrict__ hi, unsigned short* __restrict__ lo)
{
    long e = ((long)blockIdx.x * 256 + threadIdx.x) * 4;
    if (e >= NSPLIT_) return;
    const float* src; long off;
    if (e < OFF_WQKVD_)      { src = hid; off = 0; }
    else if (e < OFF_WQKVU_) { src = wqd; off = OFF_WQKVD_; }
    else if (e < OFF_WQ_)    { src = wqu; off = OFF_WQKVU_; }
    else if (e < OFF_WK_)    { src = wq;  off = OFF_WQ_; }
    else if (e < OFF_WPD_)   { src = wk;  off = OFF_WK_; }
    else if (e < OFF_WPU_)   { src = wpd; off = OFF_WPD_; }
    else                     { src = wpu; off = OFF_WPU_; }
    float4 v = *(const float4*)(src + (e - off));
    ushort4 h, l;
    h.x = f2bf(v.x); l.x = f2bf(v.x - bf2f(h.x));
    h.y = f2bf(v.y); l.y = f2bf(v.y - bf2f(h.y));
    h.z = f2bf(v.z); l.z = f2bf(v.z - bf2f(h.z));
    h.w = f2bf(v.w); l.w = f2bf(v.w - bf2f(h.w));
    *(ushort4*)&hi[e] = h;
    *(ushort4*)&lo[e] = l;
}

// ---------------------------------------------------------------------------
// bf16x3 split-precision MFMA GEMM: C[M,N] = A[M,K] @ B[N,K]^T (+bias)(*scale)
// A,B given as hi/lo bf16 pairs; C = Ah*Bh + Ah*Bl + Al*Bh (fp32 MFMA acc),
// rel err ~2^-17. Block tile 128x64, BK=32, 256 thr = 4 waves in 2x2, each
// wave 64x32 = 4x2 mfma_f32_16x16x32_bf16 tiles x3. LDS stride 40 bf16
// (80 B): 2-way bank aliasing (free), 16B-aligned b128 frag reads.
// Layouts per m89-verified mapping: A m=lane&15,k=quad*8+j; C col=lane&15,
// row=quad*4+reg. Output: fp32 (Cf) and/or hi/lo bf16 split (Chi/Clo).
// ---------------------------------------------------------------------------
__global__ __launch_bounds__(256) void gemm_bf16x3(
    const unsigned short* __restrict__ Ah, const unsigned short* __restrict__ Al,
    const unsigned short* __restrict__ Bh, const unsigned short* __restrict__ Bl,
    const float* __restrict__ bias, const float* __restrict__ scale_ptr,
    float* __restrict__ Cf, unsigned short* __restrict__ Chi,
    unsigned short* __restrict__ Clo, int M, int N, int Kd)
{
    __shared__ unsigned short sAh[128 * 40], sAl[128 * 40];
    __shared__ unsigned short sBh[64 * 40],  sBl[64 * 40];
    int tid = threadIdx.x;
    int lane = tid & 63, wv = tid >> 6;
    int wr = wv >> 1, wc = wv & 1;          // wave grid 2x2: 64 rows x 32 cols
    int row0 = blockIdx.y * 128, col0 = blockIdx.x * 64;

    f32x4 acc[4][2];
#pragma unroll
    for (int i = 0; i < 4; i++)
#pragma unroll
        for (int j = 0; j < 2; j++) acc[i][j] = (f32x4){0.f, 0.f, 0.f, 0.f};

    int ar = tid >> 1, ac = (tid & 1) * 16;  // A staging: row, col16
    int br = tid >> 2, bc = (tid & 3) * 8;   // B staging: row, col8
    const unsigned short* gAh = Ah + (size_t)(row0 + ar) * Kd + ac;
    const unsigned short* gAl = Al + (size_t)(row0 + ar) * Kd + ac;
    const unsigned short* gBh = Bh + (size_t)(col0 + br) * Kd + bc;
    const unsigned short* gBl = Bl + (size_t)(col0 + br) * Kd + bc;
    int am = lane & 15, qk = (lane >> 4) * 8;

    for (int k0 = 0; k0 < Kd; k0 += 32) {
        __syncthreads();                     // prev frags consumed
        *(float4*)&sAh[ar * 40 + ac]     = *(const float4*)(gAh + k0);
        *(float4*)&sAh[ar * 40 + ac + 8] = *(const float4*)(gAh + k0 + 8);
        *(float4*)&sAl[ar * 40 + ac]     = *(const float4*)(gAl + k0);
        *(float4*)&sAl[ar * 40 + ac + 8] = *(const float4*)(gAl + k0 + 8);
        *(float4*)&sBh[br * 40 + bc]     = *(const float4*)(gBh + k0);
        *(float4*)&sBl[br * 40 + bc]     = *(const float4*)(gBl + k0);
        __syncthreads();

        bf16x8 ah[4], al[4], bh[2], bl[2];
#pragma unroll
        for (int rt = 0; rt < 4; rt++) {
            int r = wr * 64 + rt * 16 + am;
            ah[rt] = *(const bf16x8*)&sAh[r * 40 + qk];
            al[rt] = *(const bf16x8*)&sAl[r * 40 + qk];
        }
#pragma unroll
        for (int ct = 0; ct < 2; ct++) {
            int c = wc * 32 + ct * 16 + am;
            bh[ct] = *(const bf16x8*)&sBh[c * 40 + qk];
            bl[ct] = *(const bf16x8*)&sBl[c * 40 + qk];
        }
#pragma unroll
        for (int rt = 0; rt < 4; rt++)
#pragma unroll
            for (int ct = 0; ct < 2; ct++) {
                acc[rt][ct] = __builtin_amdgcn_mfma_f32_16x16x32_bf16(ah[rt], bh[ct], acc[rt][ct], 0, 0, 0);
                acc[rt][ct] = __builtin_amdgcn_mfma_f32_16x16x32_bf16(ah[rt], bl[ct], acc[rt][ct], 0, 0, 0);
                acc[rt][ct] = __builtin_amdgcn_mfma_f32_16x16x32_bf16(al[rt], bh[ct], acc[rt][ct], 0, 0, 0);
            }
    }

    float scl = scale_ptr ? *scale_ptr : 1.0f;
    int rq = (lane >> 4) * 4;
#pragma unroll
    for (int rt = 0; rt < 4; rt++)
#pragma unroll
        for (int ct = 0; ct < 2; ct++) {
            int col = col0 + wc * 32 + ct * 16 + am;
            float bz = bias ? bias[col] : 0.0f;
#pragma unroll
            for (int rg = 0; rg < 4; rg++) {
                int row = row0 + wr * 64 + rt * 16 + rq + rg;
                float v = (acc[rt][ct][rg] + bz) * scl;
                size_t idx = (size_t)row * N + col;
                if (Cf) Cf[idx] = v;
                if (Chi) {
                    unsigned short hh = f2bf(v);
                    Chi[idx] = hh;
                    Clo[idx] = f2bf(v - bf2f(hh));
                }
            }
        }
}

// ---------------------------------------------------------------------------
// RoPE applied in-place to q and k slices of qkv[S,3072].
// ---------------------------------------------------------------------------
__global__ __launch_bounds__(256) void rope_kernel(
    float* __restrict__ qkv, const float* __restrict__ rope)
{
    int idx = blockIdx.x * blockDim.x + threadIdx.x;  // S*H*32 total
    if (idx >= S_ * H_ * 32) return;
    int d = idx & 31;
    int h = (idx >> 5) & (H_ - 1);
    int s = idx >> 9;
    float r = rope[s * 32 + d];
    float c = cosf(r), sn = sinf(r);
    size_t base = (size_t)s * 3072 + h * 64 + d;
    float q1 = qkv[base], q2 = qkv[base + 32];
    qkv[base]      = q1 * c - q2 * sn;
    qkv[base + 32] = q2 * c + q1 * sn;
    float k1 = qkv[base + 1024], k2 = qkv[base + 1024 + 32];
    qkv[base + 1024]      = k1 * c - k2 * sn;
    qkv[base + 1024 + 32] = k2 * c + k1 * sn;
}

// ---------------------------------------------------------------------------
// Fused index scores + top-K membership (R8-passing version, unchanged).
// ---------------------------------------------------------------------------
__global__ __launch_bounds__(256) void score_topk_kernel(
    const float* __restrict__ qI, const float* __restrict__ kI,
    const int* __restrict__ coords, const float* __restrict__ rpe_table,
    const float* __restrict__ W1g, const float* __restrict__ b1g,
    const float* __restrict__ W2g, const float* __restrict__ b2g,
    unsigned* __restrict__ selmask)
{
    __shared__ float skI[64][132];
    __shared__ float sqI2[4][IDH2_];
    __shared__ unsigned skeys[4][LI_];
    __shared__ int shist[4][256];
    __shared__ float srpe[NBUCK_ * IH_];
    __shared__ float sW1[GH_ * IH_], sb1[GH_], sW2[IH_ * GH_], sb2[IH_];

    int tid  = threadIdx.x;
    int lane = tid & 63;
    int wv   = tid >> 6;
    int row  = blockIdx.x * 4 + wv;
    int n    = (blockIdx.x * 4) >> 9;

    for (int i = tid; i < NBUCK_ * IH_; i += 256) srpe[i] = rpe_table[i];
    if (tid < 32) sW1[tid] = W1g[tid];
    else if (tid < 64) sW2[tid - 32] = W2g[tid - 32];
    else if (tid < 72) sb1[tid - 64] = b1g[tid - 64];
    else if (tid < 76) sb2[tid - 72] = b2g[tid - 72];
    for (int i = tid; i < 4 * IDH2_; i += 256)
        sqI2[i >> 7][i & 127] =
            qI[(size_t)(blockIdx.x * 4 + (i >> 7)) * IDH2_ + (i & 127)];
    int pq = coords[row * 2 + 1];

    for (int kt = 0; kt < 8; kt++) {
        __syncthreads();
        {
            int r  = tid >> 2;
            int d0 = (tid & 3) * 32;
            const float* src = kI + (size_t)(n * LI_ + kt * 64 + r) * IDH2_ + d0;
#pragma unroll
            for (int j = 0; j < 8; j++)
                *(float4*)&skI[r][d0 + j * 4] = *(const float4*)(src + j * 4);
        }
        __syncthreads();

        int kloc = lane;
        int kg   = kt * 64 + kloc;
        const float* sq = &sqI2[wv][0];
        float dh[8];
#pragma unroll
        for (int hh = 0; hh < 8; hh++) {
            float acc = 0.0f;
#pragma unroll
            for (int d = 0; d < 16; d += 4) {
                float4 kv = *(const float4*)&skI[kloc][hh * 16 + d];
                acc += sq[hh * 16 + d + 0] * kv.x + sq[hh * 16 + d + 1] * kv.y +
                       sq[hh * 16 + d + 2] * kv.z + sq[hh * 16 + d + 3] * kv.w;
            }
            dh[hh] = acc;
        }
        int pk = coords[(n * LI_ + kg) * 2 + 1];
        int rel = pq - pk;
        rel = rel < -MAXREL_ ? -MAXREL_ : (rel > MAXREL_ ? MAXREL_ : rel);
        const float* rp = srpe + (rel + MAXREL_) * IH_;
        float t1[GH_];
#pragma unroll
        for (int g = 0; g < GH_; g++) t1[g] = sb1[g];
#pragma unroll
        for (int j = 0; j < IH_; j++) {
            float gate = dh[IH_ + j] + rp[j];
#pragma unroll
            for (int g = 0; g < GH_; g++) t1[g] += gate * sW1[g * IH_ + j];
        }
#pragma unroll
        for (int g = 0; g < GH_; g++) t1[g] = fmaxf(t1[g], 0.0f);
        float score = 0.0f;
#pragma unroll
        for (int j = 0; j < IH_; j++) {
            float t2 = sb2[j];
#pragma unroll
            for (int g = 0; g < GH_; g++) t2 += t1[g] * sW2[j * GH_ + g];
            float sg = 1.0f / (1.0f + expf(-t2));
            float rs = fmaxf(dh[j] + rp[j], 0.0f);
            score += rs * sg;
        }
        unsigned bits = __float_as_uint(score);
        skeys[wv][kg] = (bits & 0x80000000u) ? ~bits : (bits | 0x80000000u);
    }
    __syncthreads();

    unsigned pref = 0u;
    int kcur = K_;
    const unsigned himask[4] = {0u, 0xFF000000u, 0xFFFF0000u, 0xFFFFFF00u};
#pragma unroll
    for (int pass = 0; pass < 4; pass++) {
        int shift = 24 - pass * 8;
        unsigned hm = himask[pass];
        *(int4*)&shist[wv][4 * lane] = make_int4(0, 0, 0, 0);
        __syncthreads();
#pragma unroll
        for (int c = 0; c < 8; c++) {
            unsigned key = skeys[wv][c * 64 + lane];
            if ((key & hm) == pref) atomicAdd(&shist[wv][(key >> shift) & 255], 1);
        }
        __syncthreads();
        int4 b4 = *(const int4*)&shist[wv][4 * lane];
        int b[4] = {b4.x, b4.y, b4.z, b4.w};
        int t = b[0] + b[1] + b[2] + b[3];
        int Ssum = t;
#pragma unroll
        for (int off = 1; off < 64; off <<= 1) {
            int u = __shfl_down(Ssum, off, 64);
            if (lane + off < 64) Ssum += u;
        }
        int E = Ssum - t;
        int cs[5];
        cs[4] = E;
        cs[3] = b[3] + E;
        cs[2] = b[2] + cs[3];
        cs[1] = b[1] + cs[2];
        cs[0] = b[0] + cs[1];
        bool found = false;
        unsigned cpref = 0u; int ck = 0;
#pragma unroll
        for (int j = 0; j < 4; j++) {
            if (!found && cs[j] >= kcur && cs[j + 1] < kcur) {
                found = true;
                cpref = pref | ((unsigned)(4 * lane + j) << shift);
                ck = kcur - cs[j + 1];
            }
        }
        unsigned long long bm = __ballot(found);
        int src = __ffsll((long long)bm) - 1;
        pref = (unsigned)__shfl((int)cpref, src, 64);
        kcur = __shfl(ck, src, 64);
        __syncthreads();
    }
    unsigned Tu = pref;

    unsigned long long bg[8], be[8];
#pragma unroll
    for (int c = 0; c < 8; c++) {
        unsigned key = skeys[wv][c * 64 + lane];
        bg[c] = __ballot(key > Tu);
        be[c] = __ballot(key == Tu);
    }
    if (lane < 16) {
        int total_gt = 0;
#pragma unroll
        for (int c = 0; c < 8; c++) total_gt += __popcll(bg[c]);
        int base = 0;
#pragma unroll
        for (int c = 0; c < 8; c++) {
            if (2 * c < lane)     base += __popc((unsigned)be[c]);
            if (2 * c + 1 < lane) base += __popc((unsigned)(be[c] >> 32));
        }
        unsigned gw = (unsigned)(bg[lane >> 1] >> (32 * (lane & 1)));
        unsigned ew = (unsigned)(be[lane >> 1] >> (32 * (lane & 1)));
        int ne = K_ - total_gt - base;
        int pc = __popc(ew);
        int m = ne < 0 ? 0 : (ne > pc ? pc : ne);
        while (pc > m) { ew ^= (1u << (31 - __clz(ew))); pc--; }
        selmask[(size_t)row * 16 + lane] = gw | ew;
    }
}

// ---------------------------------------------------------------------------
// Dense-masked tiled attention (fp32 compute, unchanged core). Epilogue now
// emits the hi/lo bf16 split of attout directly (consumed by gemm_bf16x3).
// ---------------------------------------------------------------------------
__global__ __launch_bounds__(256) void attn_kernel(
    const float* __restrict__ qkv, const unsigned* __restrict__ selmask,
    unsigned short* __restrict__ outh, unsigned short* __restrict__ outl)
{
    __shared__ float Qs[64][68];
    __shared__ float KPs[64][68];
    __shared__ float Vs[64][68];
    __shared__ unsigned Ms[64][16];

    int b  = blockIdx.x;
    int qt = b & 7;
    int h  = (b >> 3) & 15;
    int n  = b >> 7;
    int tid = threadIdx.x;
    int tx = tid & 15, ty = tid >> 4;
    int q0 = n * LI_ + qt * 64;

    for (int i = tid; i < 64 * 16; i += 256)
        Ms[i >> 4][i & 15] = selmask[(size_t)(q0 + (i >> 4)) * 16 + (i & 15)];

#pragma unroll
    for (int m = 0; m < 4; m++) {
        int r = (tid >> 4) + m * 16;
        int c = tid & 15;
        float4 v = *(const float4*)(qkv + (size_t)(q0 + r) * 3072 + h * 64 + c * 4);
        Qs[c * 4 + 0][r] = v.x * 0.125f;
        Qs[c * 4 + 1][r] = v.y * 0.125f;
        Qs[c * 4 + 2][r] = v.z * 0.125f;
        Qs[c * 4 + 3][r] = v.w * 0.125f;
    }

    float o[4][4] = {};
    float rs[4] = {};

    for (int kt = 0; kt < 8; kt++) {
        __syncthreads();
#pragma unroll
        for (int m = 0; m < 4; m++) {
            int r = (tid >> 4) + m * 16;
            int c = tid & 15;
            size_t krow = (size_t)(n * LI_ + kt * 64 + r) * 3072 + h * 64;
            float4 kv = *(const float4*)(qkv + krow + 1024 + c * 4);
            KPs[c * 4 + 0][r] = kv.x;
            KPs[c * 4 + 1][r] = kv.y;
            KPs[c * 4 + 2][r] = kv.z;
            KPs[c * 4 + 3][r] = kv.w;
            float4 vv = *(const float4*)(qkv + krow + 2048 + c * 4);
            *(float4*)&Vs[r][c * 4] = vv;
        }
        __syncthreads();

        float s[4][4] = {};
#pragma unroll 8
        for (int d = 0; d < 64; d++) {
            float4 a4 = *(const float4*)&Qs[d][ty * 4];
            float4 b4 = *(const float4*)&KPs[d][tx * 4];
            float a[4] = {a4.x, a4.y, a4.z, a4.w};
            float bb[4] = {b4.x, b4.y, b4.z, b4.w};
#pragma unroll
            for (int i = 0; i < 4; i++)
#pragma unroll
                for (int j = 0; j < 4; j++)
                    s[i][j] += a[i] * bb[j];
        }
        __syncthreads();

        int kbase = kt * 64 + tx * 4;
        int wi = kbase >> 5;
        int bit0 = kbase & 31;
#pragma unroll
        for (int i = 0; i < 4; i++) {
            unsigned mw = Ms[ty * 4 + i][wi];
#pragma unroll
            for (int j = 0; j < 4; j++) {
                float p = ((mw >> (bit0 + j)) & 1u) ? __expf(s[i][j]) : 0.0f;
                rs[i] += p;
                KPs[tx * 4 + j][ty * 4 + i] = p;
            }
        }
        __syncthreads();

#pragma unroll 8
        for (int kk = 0; kk < 64; kk++) {
            float4 a4 = *(const float4*)&KPs[kk][ty * 4];
            float4 b4 = *(const float4*)&Vs[kk][tx * 4];
            float a[4] = {a4.x, a4.y, a4.z, a4.w};
            float bb[4] = {b4.x, b4.y, b4.z, b4.w};
#pragma unroll
            for (int i = 0; i < 4; i++)
#pragma unroll
                for (int j = 0; j < 4; j++)
                    o[i][j] += a[i] * bb[j];
        }
    }

#pragma unroll
    for (int i = 0; i < 4; i++) {
#pragma unroll
        for (int off = 1; off < 16; off <<= 1)
            rs[i] += __shfl_xor(rs[i], off, 64);
    }

#pragma unroll
    for (int i = 0; i < 4; i++) {
        float inv = 1.0f / rs[i];
        size_t ob = (size_t)(q0 + ty * 4 + i) * 1024 + h * 64 + tx * 4;
        ushort4 hv, lv;
        float v0 = o[i][0] * inv; hv.x = f2bf(v0); lv.x = f2bf(v0 - bf2f(hv.x));
        float v1 = o[i][1] * inv; hv.y = f2bf(v1); lv.y = f2bf(v1 - bf2f(hv.y));
        float v2 = o[i][2] * inv; hv.z = f2bf(v2); lv.z = f2bf(v2 - bf2f(hv.z));
        float v3 = o[i][3] * inv; hv.w = f2bf(v3); lv.w = f2bf(v3 - bf2f(hv.w));
        *(ushort4*)&outh[ob] = hv;
        *(ushort4*)&outl[ob] = lv;
    }
}

// ---------------------------------------------------------------------------
extern "C" void kernel_launch(void* const* d_in, const int* in_sizes, int n_in,
                              void* d_out, int out_size, void* d_ws, size_t ws_size,
                              hipStream_t stream)
{
    const float* hidden  = (const float*)d_in[0];
    const int*   coords  = (const int*)d_in[1];
    const float* rope    = (const float*)d_in[3];
    const float* Wq_idx  = (const float*)d_in[4];
    const float* Wk_idx  = (const float*)d_in[5];
    const float* W1g     = (const float*)d_in[6];
    const float* b1g     = (const float*)d_in[7];
    const float* W2g     = (const float*)d_in[8];
    const float* b2g     = (const float*)d_in[9];
    const float* rpe     = (const float*)d_in[10];
    const float* Wqkv_d  = (const float*)d_in[11];
    const float* bqkv_d  = (const float*)d_in[12];
    const float* Wqkv_u  = (const float*)d_in[13];
    const float* bqkv_u  = (const float*)d_in[14];
    const float* Wp_d    = (const float*)d_in[15];
    const float* bp_d    = (const float*)d_in[16];
    const float* Wp_u    = (const float*)d_in[17];
    const float* bp_u    = (const float*)d_in[18];
    const float* scaler  = (const float*)d_in[19];
    float* out = (float*)d_out;

    // Workspace layout. Split region: hi[NSPLIT_] then lo[NSPLIT_] (ushort),
    // then mid hi/lo (S*BOT each), then fp32 buffers. attout hi/lo reuse the
    // hidden slots (exactly S*DIM elems; hidden dead after gemm3/4).
    unsigned short* sp_hi  = (unsigned short*)d_ws;
    unsigned short* sp_lo  = sp_hi + NSPLIT_;
    unsigned short* mid_hi = sp_lo + NSPLIT_;
    unsigned short* mid_lo = mid_hi + (size_t)S_ * BOT_;
    float* qkv = (float*)(mid_lo + (size_t)S_ * BOT_);
    float* qIb = qkv + (size_t)S_ * 3 * DIM_;
    float* kIb = qIb + (size_t)S_ * IDH2_;
    unsigned* selmask = (unsigned*)(kIb + (size_t)S_ * IDH2_);

    // 0) split hidden + all weights into hi/lo bf16
    split_all_kernel<<<(NSPLIT_ / 4 + 255) / 256, 256, 0, stream>>>(
        hidden, Wqkv_d, Wqkv_u, Wq_idx, Wk_idx, Wp_d, Wp_u, sp_hi, sp_lo);

    // 1) mid1 = hidden @ Wqkv_d^T + b  (emit hi/lo only)
    gemm_bf16x3<<<dim3(BOT_ / 64, S_ / 128), 256, 0, stream>>>(
        sp_hi, sp_lo, sp_hi + OFF_WQKVD_, sp_lo + OFF_WQKVD_,
        bqkv_d, nullptr, nullptr, mid_hi, mid_lo, S_, BOT_, DIM_);
    //    qkv = mid1 @ Wqkv_u^T + b  (fp32)
    gemm_bf16x3<<<dim3(3 * DIM_ / 64, S_ / 128), 256, 0, stream>>>(
        mid_hi, mid_lo, sp_hi + OFF_WQKVU_, sp_lo + OFF_WQKVU_,
        bqkv_u, nullptr, qkv, nullptr, nullptr, S_, 3 * DIM_, BOT_);

    // 2) RoPE on q,k in place
    rope_kernel<<<(S_ * H_ * 32) / 256, 256, 0, stream>>>(qkv, rope);

    // 3) index projections (fp32 out)
    gemm_bf16x3<<<dim3(IDH2_ / 64, S_ / 128), 256, 0, stream>>>(
        sp_hi, sp_lo, sp_hi + OFF_WQ_, sp_lo + OFF_WQ_,
        nullptr, nullptr, qIb, nullptr, nullptr, S_, IDH2_, DIM_);
    gemm_bf16x3<<<dim3(IDH2_ / 64, S_ / 128), 256, 0, stream>>>(
        sp_hi, sp_lo, sp_hi + OFF_WK_, sp_lo + OFF_WK_,
        nullptr, nullptr, kIb, nullptr, nullptr, S_, IDH2_, DIM_);

    // 4) fused index scores + top-k membership bitmask
    score_topk_kernel<<<S_ / 4, 256, 0, stream>>>(
        qIb, kIb, coords, rpe, W1g, b1g, W2g, b2g, selmask);

    // 5) dense-masked attention (emits attout hi/lo into hidden's slots)
    attn_kernel<<<NIMG_ * H_ * 8, 256, 0, stream>>>(qkv, selmask, sp_hi, sp_lo);

    // 6) mid2 = attout @ Wp_d^T + b (hi/lo); out = mid2 @ Wp_u^T + b, *scaler
    gemm_bf16x3<<<dim3(BOT_ / 64, S_ / 128), 256, 0, stream>>>(
        sp_hi, sp_lo, sp_hi + OFF_WPD_, sp_lo + OFF_WPD_,
        bp_d, nullptr, nullptr, mid_hi, mid_lo, S_, BOT_, DIM_);
    gemm_bf16x3<<<dim3(DIM_ / 64, S_ / 128), 256, 0, stream>>>(
        mid_hi, mid_lo, sp_hi + OFF_WPU_, sp_lo + OFF_WPU_,
        bp_u, scaler, out, nullptr, nullptr, S_, DIM_, BOT_);
}

// Round 10
// 305.703 us; speedup vs baseline: 3.3250x; 1.1998x over previous
//
#include <hip/hip_runtime.h>
#include <hip/hip_bf16.h>

// Problem constants
#define S_    2048
#define DIM_  1024
#define H_    16
#define DH_   64
#define BOT_  256
#define NIMG_ 4
#define LI_   512
#define K_    256
#define IH_   4
#define ID_   16
#define MAXREL_ 64
#define NBUCK_ 129
#define GH_   8
#define IDH2_ 128   // 2*IH*ID

typedef short bf16x8 __attribute__((ext_vector_type(8)));
typedef float f32x4  __attribute__((ext_vector_type(4)));

__device__ __forceinline__ unsigned short f2bf(float x) {   // RNE float->bf16
    unsigned u = __float_as_uint(x);
    return (unsigned short)((u + 0x7fffu + ((u >> 16) & 1u)) >> 16);
}
__device__ __forceinline__ float bf2f(unsigned short h) {
    return __uint_as_float(((unsigned)h) << 16);
}

// Split-region element offsets (ushort units). W1 = [Wqkv_d;Wq;Wk] contiguous
// so gemm1 sees one 512x1024 B matrix.
#define OFF_W1_    2097152                   // hidden 2048x1024 before it
#define OFF_WQ_    2359296                   // = OFF_W1_ + 256*1024
#define OFF_WK_    2490368                   // + 128*1024
#define OFF_WQKVU_ 2621440                   // + 128*1024
#define OFF_WPD_   3407872                   // + 3072*256
#define OFF_WPU_   3670016                   // + 256*1024
#define NSPLIT_    3932160                   // + 1024*256

// ---------------------------------------------------------------------------
// Fused hi/lo bf16 split of hidden + all 6 weight matrices (one launch).
// ---------------------------------------------------------------------------
__global__ __launch_bounds__(256) void split_all_kernel(
    const float* __restrict__ hid, const float* __restrict__ wqd,
    const float* __restrict__ wq,  const float* __restrict__ wk,
    const float* __restrict__ wqu, const float* __restrict__ wpd,
    const float* __restrict__ wpu,
    unsigned short* __restrict__ hi, unsigned short* __restrict__ lo)
{
    long e = ((long)blockIdx.x * 256 + threadIdx.x) * 4;
    if (e >= NSPLIT_) return;
    const float* src; long off;
    if (e < OFF_W1_)         { src = hid; off = 0; }
    else if (e < OFF_WQ_)    { src = wqd; off = OFF_W1_; }
    else if (e < OFF_WK_)    { src = wq;  off = OFF_WQ_; }
    else if (e < OFF_WQKVU_) { src = wk;  off = OFF_WK_; }
    else if (e < OFF_WPD_)   { src = wqu; off = OFF_WQKVU_; }
    else if (e < OFF_WPU_)   { src = wpd; off = OFF_WPD_; }
    else                     { src = wpu; off = OFF_WPU_; }
    float4 v = *(const float4*)(src + (e - off));
    ushort4 h, l;
    h.x = f2bf(v.x); l.x = f2bf(v.x - bf2f(h.x));
    h.y = f2bf(v.y); l.y = f2bf(v.y - bf2f(h.y));
    h.z = f2bf(v.z); l.z = f2bf(v.z - bf2f(h.z));
    h.w = f2bf(v.w); l.w = f2bf(v.w - bf2f(h.w));
    *(ushort4*)&hi[e] = h;
    *(ushort4*)&lo[e] = l;
}

// ---------------------------------------------------------------------------
// bf16x3 MFMA GEMM, 128x64 tile (for large-N call sites: qkv_u, p_u).
// fp32 output + bias + optional scale. 4 waves 2x2, wave 64x32.
// ---------------------------------------------------------------------------
__global__ __launch_bounds__(256) void gemm_bf16x3(
    const unsigned short* __restrict__ Ah, const unsigned short* __restrict__ Al,
    const unsigned short* __restrict__ Bh, const unsigned short* __restrict__ Bl,
    const float* __restrict__ bias, const float* __restrict__ scale_ptr,
    float* __restrict__ Cf, int M, int N, int Kd)
{
    __shared__ unsigned short sAh[128 * 40], sAl[128 * 40];
    __shared__ unsigned short sBh[64 * 40],  sBl[64 * 40];
    int tid = threadIdx.x;
    int lane = tid & 63, wv = tid >> 6;
    int wr = wv >> 1, wc = wv & 1;
    int row0 = blockIdx.y * 128, col0 = blockIdx.x * 64;

    f32x4 acc[4][2];
#pragma unroll
    for (int i = 0; i < 4; i++)
#pragma unroll
        for (int j = 0; j < 2; j++) acc[i][j] = (f32x4){0.f, 0.f, 0.f, 0.f};

    int ar = tid >> 1, ac = (tid & 1) * 16;
    int br = tid >> 2, bc = (tid & 3) * 8;
    const unsigned short* gAh = Ah + (size_t)(row0 + ar) * Kd + ac;
    const unsigned short* gAl = Al + (size_t)(row0 + ar) * Kd + ac;
    const unsigned short* gBh = Bh + (size_t)(col0 + br) * Kd + bc;
    const unsigned short* gBl = Bl + (size_t)(col0 + br) * Kd + bc;
    int am = lane & 15, qk = (lane >> 4) * 8;

    for (int k0 = 0; k0 < Kd; k0 += 32) {
        __syncthreads();
        *(float4*)&sAh[ar * 40 + ac]     = *(const float4*)(gAh + k0);
        *(float4*)&sAh[ar * 40 + ac + 8] = *(const float4*)(gAh + k0 + 8);
        *(float4*)&sAl[ar * 40 + ac]     = *(const float4*)(gAl + k0);
        *(float4*)&sAl[ar * 40 + ac + 8] = *(const float4*)(gAl + k0 + 8);
        *(float4*)&sBh[br * 40 + bc]     = *(const float4*)(gBh + k0);
        *(float4*)&sBl[br * 40 + bc]     = *(const float4*)(gBl + k0);
        __syncthreads();

        bf16x8 ah[4], al[4], bh[2], bl[2];
#pragma unroll
        for (int rt = 0; rt < 4; rt++) {
            int r = wr * 64 + rt * 16 + am;
            ah[rt] = *(const bf16x8*)&sAh[r * 40 + qk];
            al[rt] = *(const bf16x8*)&sAl[r * 40 + qk];
        }
#pragma unroll
        for (int ct = 0; ct < 2; ct++) {
            int c = wc * 32 + ct * 16 + am;
            bh[ct] = *(const bf16x8*)&sBh[c * 40 + qk];
            bl[ct] = *(const bf16x8*)&sBl[c * 40 + qk];
        }
#pragma unroll
        for (int rt = 0; rt < 4; rt++)
#pragma unroll
            for (int ct = 0; ct < 2; ct++) {
                acc[rt][ct] = __builtin_amdgcn_mfma_f32_16x16x32_bf16(ah[rt], bh[ct], acc[rt][ct], 0, 0, 0);
                acc[rt][ct] = __builtin_amdgcn_mfma_f32_16x16x32_bf16(ah[rt], bl[ct], acc[rt][ct], 0, 0, 0);
                acc[rt][ct] = __builtin_amdgcn_mfma_f32_16x16x32_bf16(al[rt], bh[ct], acc[rt][ct], 0, 0, 0);
            }
    }

    float scl = scale_ptr ? *scale_ptr : 1.0f;
    int rq = (lane >> 4) * 4;
#pragma unroll
    for (int rt = 0; rt < 4; rt++)
#pragma unroll
        for (int ct = 0; ct < 2; ct++) {
            int col = col0 + wc * 32 + ct * 16 + am;
            float bz = bias ? bias[col] : 0.0f;
#pragma unroll
            for (int rg = 0; rg < 4; rg++) {
                int row = row0 + wr * 64 + rt * 16 + rq + rg;
                Cf[(size_t)row * N + col] = (acc[rt][ct][rg] + bz) * scl;
            }
        }
}

// ---------------------------------------------------------------------------
// bf16x3 MFMA GEMM, 64x64 tile (small-N call sites: gemm1 N=512, p_d N=256).
// Epilogue splits by column: col < split_col -> hi/lo bf16 pair (width
// split_col, bias_lo); col >= split_col -> fp32 (width N-split_col, bias_hi).
// ---------------------------------------------------------------------------
__global__ __launch_bounds__(256) void gemm64_bf16x3(
    const unsigned short* __restrict__ Ah, const unsigned short* __restrict__ Al,
    const unsigned short* __restrict__ Bh, const unsigned short* __restrict__ Bl,
    const float* __restrict__ bias_lo, const float* __restrict__ bias_hi,
    float* __restrict__ Cf, unsigned short* __restrict__ Chi,
    unsigned short* __restrict__ Clo, int M, int N, int Kd, int split_col)
{
    __shared__ unsigned short sAh[64 * 40], sAl[64 * 40];
    __shared__ unsigned short sBh[64 * 40], sBl[64 * 40];
    int tid = threadIdx.x;
    int lane = tid & 63, wv = tid >> 6;
    int wr = wv >> 1, wc = wv & 1;          // wave 32x32
    int row0 = blockIdx.y * 64, col0 = blockIdx.x * 64;

    f32x4 acc[2][2];
#pragma unroll
    for (int i = 0; i < 2; i++)
#pragma unroll
        for (int j = 0; j < 2; j++) acc[i][j] = (f32x4){0.f, 0.f, 0.f, 0.f};

    int sr = tid >> 2, sc = (tid & 3) * 8;
    const unsigned short* gAh = Ah + (size_t)(row0 + sr) * Kd + sc;
    const unsigned short* gAl = Al + (size_t)(row0 + sr) * Kd + sc;
    const unsigned short* gBh = Bh + (size_t)(col0 + sr) * Kd + sc;
    const unsigned short* gBl = Bl + (size_t)(col0 + sr) * Kd + sc;
    int am = lane & 15, qk = (lane >> 4) * 8;

    for (int k0 = 0; k0 < Kd; k0 += 32) {
        __syncthreads();
        *(float4*)&sAh[sr * 40 + sc] = *(const float4*)(gAh + k0);
        *(float4*)&sAl[sr * 40 + sc] = *(const float4*)(gAl + k0);
        *(float4*)&sBh[sr * 40 + sc] = *(const float4*)(gBh + k0);
        *(float4*)&sBl[sr * 40 + sc] = *(const float4*)(gBl + k0);
        __syncthreads();

        bf16x8 ah[2], al[2], bh[2], bl[2];
#pragma unroll
        for (int rt = 0; rt < 2; rt++) {
            int r = wr * 32 + rt * 16 + am;
            ah[rt] = *(const bf16x8*)&sAh[r * 40 + qk];
            al[rt] = *(const bf16x8*)&sAl[r * 40 + qk];
        }
#pragma unroll
        for (int ct = 0; ct < 2; ct++) {
            int c = wc * 32 + ct * 16 + am;
            bh[ct] = *(const bf16x8*)&sBh[c * 40 + qk];
            bl[ct] = *(const bf16x8*)&sBl[c * 40 + qk];
        }
#pragma unroll
        for (int rt = 0; rt < 2; rt++)
#pragma unroll
            for (int ct = 0; ct < 2; ct++) {
                acc[rt][ct] = __builtin_amdgcn_mfma_f32_16x16x32_bf16(ah[rt], bh[ct], acc[rt][ct], 0, 0, 0);
                acc[rt][ct] = __builtin_amdgcn_mfma_f32_16x16x32_bf16(ah[rt], bl[ct], acc[rt][ct], 0, 0, 0);
                acc[rt][ct] = __builtin_amdgcn_mfma_f32_16x16x32_bf16(al[rt], bh[ct], acc[rt][ct], 0, 0, 0);
            }
    }

    int rq = (lane >> 4) * 4;
#pragma unroll
    for (int rt = 0; rt < 2; rt++)
#pragma unroll
        for (int ct = 0; ct < 2; ct++) {
            int col = col0 + wc * 32 + ct * 16 + am;
#pragma unroll
            for (int rg = 0; rg < 4; rg++) {
                int row = row0 + wr * 32 + rt * 16 + rq + rg;
                float v = acc[rt][ct][rg];
                if (col < split_col) {
                    if (bias_lo) v += bias_lo[col];
                    size_t idx = (size_t)row * split_col + col;
                    unsigned short hh = f2bf(v);
                    Chi[idx] = hh;
                    Clo[idx] = f2bf(v - bf2f(hh));
                } else {
                    if (bias_hi) v += bias_hi[col - split_col];
                    Cf[(size_t)row * (N - split_col) + col - split_col] = v;
                }
            }
        }
}

// ---------------------------------------------------------------------------
// RoPE applied in-place to q and k slices of qkv[S,3072].
// ---------------------------------------------------------------------------
__global__ __launch_bounds__(256) void rope_kernel(
    float* __restrict__ qkv, const float* __restrict__ rope)
{
    int idx = blockIdx.x * blockDim.x + threadIdx.x;  // S*H*32 total
    if (idx >= S_ * H_ * 32) return;
    int d = idx & 31;
    int h = (idx >> 5) & (H_ - 1);
    int s = idx >> 9;
    float r = rope[s * 32 + d];
    float c = cosf(r), sn = sinf(r);
    size_t base = (size_t)s * 3072 + h * 64 + d;
    float q1 = qkv[base], q2 = qkv[base + 32];
    qkv[base]      = q1 * c - q2 * sn;
    qkv[base + 32] = q2 * c + q1 * sn;
    float k1 = qkv[base + 1024], k2 = qkv[base + 1024 + 32];
    qkv[base + 1024]      = k1 * c - k2 * sn;
    qkv[base + 1024 + 32] = k2 * c + k1 * sn;
}

// ---------------------------------------------------------------------------
// Fused index scores + top-K membership. qI/kI now live in one combined
// fp32 buffer qIk[S,256]: qI = cols 0..127, kI = cols 128..255.
// ---------------------------------------------------------------------------
__global__ __launch_bounds__(256) void score_topk_kernel(
    const float* __restrict__ qIk,
    const int* __restrict__ coords, const float* __restrict__ rpe_table,
    const float* __restrict__ W1g, const float* __restrict__ b1g,
    const float* __restrict__ W2g, const float* __restrict__ b2g,
    unsigned* __restrict__ selmask)
{
    __shared__ float skI[64][132];
    __shared__ float sqI2[4][IDH2_];
    __shared__ unsigned skeys[4][LI_];
    __shared__ int shist[4][256];
    __shared__ float srpe[NBUCK_ * IH_];
    __shared__ float sW1[GH_ * IH_], sb1[GH_], sW2[IH_ * GH_], sb2[IH_];

    int tid  = threadIdx.x;
    int lane = tid & 63;
    int wv   = tid >> 6;
    int row  = blockIdx.x * 4 + wv;
    int n    = (blockIdx.x * 4) >> 9;

    for (int i = tid; i < NBUCK_ * IH_; i += 256) srpe[i] = rpe_table[i];
    if (tid < 32) sW1[tid] = W1g[tid];
    else if (tid < 64) sW2[tid - 32] = W2g[tid - 32];
    else if (tid < 72) sb1[tid - 64] = b1g[tid - 64];
    else if (tid < 76) sb2[tid - 72] = b2g[tid - 72];
    for (int i = tid; i < 4 * IDH2_; i += 256)
        sqI2[i >> 7][i & 127] =
            qIk[(size_t)(blockIdx.x * 4 + (i >> 7)) * 256 + (i & 127)];
    int pq = coords[row * 2 + 1];

    for (int kt = 0; kt < 8; kt++) {
        __syncthreads();
        {
            int r  = tid >> 2;
            int d0 = (tid & 3) * 32;
            const float* src = qIk + (size_t)(n * LI_ + kt * 64 + r) * 256 + 128 + d0;
#pragma unroll
            for (int j = 0; j < 8; j++)
                *(float4*)&skI[r][d0 + j * 4] = *(const float4*)(src + j * 4);
        }
        __syncthreads();

        int kloc = lane;
        int kg   = kt * 64 + kloc;
        const float* sq = &sqI2[wv][0];
        float dh[8];
#pragma unroll
        for (int hh = 0; hh < 8; hh++) {
            float acc = 0.0f;
#pragma unroll
            for (int d = 0; d < 16; d += 4) {
                float4 kv = *(const float4*)&skI[kloc][hh * 16 + d];
                acc += sq[hh * 16 + d + 0] * kv.x + sq[hh * 16 + d + 1] * kv.y +
                       sq[hh * 16 + d + 2] * kv.z + sq[hh * 16 + d + 3] * kv.w;
            }
            dh[hh] = acc;
        }
        int pk = coords[(n * LI_ + kg) * 2 + 1];
        int rel = pq - pk;
        rel = rel < -MAXREL_ ? -MAXREL_ : (rel > MAXREL_ ? MAXREL_ : rel);
        const float* rp = srpe + (rel + MAXREL_) * IH_;
        float t1[GH_];
#pragma unroll
        for (int g = 0; g < GH_; g++) t1[g] = sb1[g];
#pragma unroll
        for (int j = 0; j < IH_; j++) {
            float gate = dh[IH_ + j] + rp[j];
#pragma unroll
            for (int g = 0; g < GH_; g++) t1[g] += gate * sW1[g * IH_ + j];
        }
#pragma unroll
        for (int g = 0; g < GH_; g++) t1[g] = fmaxf(t1[g], 0.0f);
        float score = 0.0f;
#pragma unroll
        for (int j = 0; j < IH_; j++) {
            float t2 = sb2[j];
#pragma unroll
            for (int g = 0; g < GH_; g++) t2 += t1[g] * sW2[j * GH_ + g];
            float sg = 1.0f / (1.0f + expf(-t2));
            float rs = fmaxf(dh[j] + rp[j], 0.0f);
            score += rs * sg;
        }
        unsigned bits = __float_as_uint(score);
        skeys[wv][kg] = (bits & 0x80000000u) ? ~bits : (bits | 0x80000000u);
    }
    __syncthreads();

    unsigned pref = 0u;
    int kcur = K_;
    const unsigned himask[4] = {0u, 0xFF000000u, 0xFFFF0000u, 0xFFFFFF00u};
#pragma unroll
    for (int pass = 0; pass < 4; pass++) {
        int shift = 24 - pass * 8;
        unsigned hm = himask[pass];
        *(int4*)&shist[wv][4 * lane] = make_int4(0, 0, 0, 0);
        __syncthreads();
#pragma unroll
        for (int c = 0; c < 8; c++) {
            unsigned key = skeys[wv][c * 64 + lane];
            if ((key & hm) == pref) atomicAdd(&shist[wv][(key >> shift) & 255], 1);
        }
        __syncthreads();
        int4 b4 = *(const int4*)&shist[wv][4 * lane];
        int b[4] = {b4.x, b4.y, b4.z, b4.w};
        int t = b[0] + b[1] + b[2] + b[3];
        int Ssum = t;
#pragma unroll
        for (int off = 1; off < 64; off <<= 1) {
            int u = __shfl_down(Ssum, off, 64);
            if (lane + off < 64) Ssum += u;
        }
        int E = Ssum - t;
        int cs[5];
        cs[4] = E;
        cs[3] = b[3] + E;
        cs[2] = b[2] + cs[3];
        cs[1] = b[1] + cs[2];
        cs[0] = b[0] + cs[1];
        bool found = false;
        unsigned cpref = 0u; int ck = 0;
#pragma unroll
        for (int j = 0; j < 4; j++) {
            if (!found && cs[j] >= kcur && cs[j + 1] < kcur) {
                found = true;
                cpref = pref | ((unsigned)(4 * lane + j) << shift);
                ck = kcur - cs[j + 1];
            }
        }
        unsigned long long bm = __ballot(found);
        int src = __ffsll((long long)bm) - 1;
        pref = (unsigned)__shfl((int)cpref, src, 64);
        kcur = __shfl(ck, src, 64);
        __syncthreads();
    }
    unsigned Tu = pref;

    unsigned long long bg[8], be[8];
#pragma unroll
    for (int c = 0; c < 8; c++) {
        unsigned key = skeys[wv][c * 64 + lane];
        bg[c] = __ballot(key > Tu);
        be[c] = __ballot(key == Tu);
    }
    if (lane < 16) {
        int total_gt = 0;
#pragma unroll
        for (int c = 0; c < 8; c++) total_gt += __popcll(bg[c]);
        int base = 0;
#pragma unroll
        for (int c = 0; c < 8; c++) {
            if (2 * c < lane)     base += __popc((unsigned)be[c]);
            if (2 * c + 1 < lane) base += __popc((unsigned)(be[c] >> 32));
        }
        unsigned gw = (unsigned)(bg[lane >> 1] >> (32 * (lane & 1)));
        unsigned ew = (unsigned)(be[lane >> 1] >> (32 * (lane & 1)));
        int ne = K_ - total_gt - base;
        int pc = __popc(ew);
        int m = ne < 0 ? 0 : (ne > pc ? pc : ne);
        while (pc > m) { ew ^= (1u << (31 - __clz(ew))); pc--; }
        selmask[(size_t)row * 16 + lane] = gw | ew;
    }
}

// ---------------------------------------------------------------------------
// Dense-masked tiled attention. P now stored ROW-major [q][k] in KPs with
// float4 writes (kills the 8-way transposed-scatter conflicts of R9); PV
// reads P as float4 along k. Epilogue emits attout hi/lo bf16.
// ---------------------------------------------------------------------------
__global__ __launch_bounds__(256) void attn_kernel(
    const float* __restrict__ qkv, const unsigned* __restrict__ selmask,
    unsigned short* __restrict__ outh, unsigned short* __restrict__ outl)
{
    __shared__ float Qs[64][68];
    __shared__ float KPs[64][68];    // QK phase: K^T [d][k]; PV phase: P [q][k]
    __shared__ float Vs[64][68];
    __shared__ unsigned Ms[64][16];

    int b  = blockIdx.x;
    int qt = b & 7;
    int h  = (b >> 3) & 15;
    int n  = b >> 7;
    int tid = threadIdx.x;
    int tx = tid & 15, ty = tid >> 4;
    int q0 = n * LI_ + qt * 64;

    for (int i = tid; i < 64 * 16; i += 256)
        Ms[i >> 4][i & 15] = selmask[(size_t)(q0 + (i >> 4)) * 16 + (i & 15)];

#pragma unroll
    for (int m = 0; m < 4; m++) {
        int r = (tid >> 4) + m * 16;
        int c = tid & 15;
        float4 v = *(const float4*)(qkv + (size_t)(q0 + r) * 3072 + h * 64 + c * 4);
        Qs[c * 4 + 0][r] = v.x * 0.125f;
        Qs[c * 4 + 1][r] = v.y * 0.125f;
        Qs[c * 4 + 2][r] = v.z * 0.125f;
        Qs[c * 4 + 3][r] = v.w * 0.125f;
    }

    float o[4][4] = {};
    float rs[4] = {};

    for (int kt = 0; kt < 8; kt++) {
        __syncthreads();
#pragma unroll
        for (int m = 0; m < 4; m++) {
            int r = (tid >> 4) + m * 16;
            int c = tid & 15;
            size_t krow = (size_t)(n * LI_ + kt * 64 + r) * 3072 + h * 64;
            float4 kv = *(const float4*)(qkv + krow + 1024 + c * 4);
            KPs[c * 4 + 0][r] = kv.x;
            KPs[c * 4 + 1][r] = kv.y;
            KPs[c * 4 + 2][r] = kv.z;
            KPs[c * 4 + 3][r] = kv.w;
            float4 vv = *(const float4*)(qkv + krow + 2048 + c * 4);
            *(float4*)&Vs[r][c * 4] = vv;
        }
        __syncthreads();

        float s[4][4] = {};
#pragma unroll 8
        for (int d = 0; d < 64; d++) {
            float4 a4 = *(const float4*)&Qs[d][ty * 4];
            float4 b4 = *(const float4*)&KPs[d][tx * 4];
            float a[4] = {a4.x, a4.y, a4.z, a4.w};
            float bb[4] = {b4.x, b4.y, b4.z, b4.w};
#pragma unroll
            for (int i = 0; i < 4; i++)
#pragma unroll
                for (int j = 0; j < 4; j++)
                    s[i][j] += a[i] * bb[j];
        }
        __syncthreads();   // QK reads of KPs done before P overwrite

        int kbase = kt * 64 + tx * 4;
        int wi = kbase >> 5;
        int bit0 = kbase & 31;
#pragma unroll
        for (int i = 0; i < 4; i++) {
            unsigned mw = Ms[ty * 4 + i][wi];
            float4 p4;
            float p0 = ((mw >> (bit0 + 0)) & 1u) ? __expf(s[i][0]) : 0.0f;
            float p1 = ((mw >> (bit0 + 1)) & 1u) ? __expf(s[i][1]) : 0.0f;
            float p2 = ((mw >> (bit0 + 2)) & 1u) ? __expf(s[i][2]) : 0.0f;
            float p3 = ((mw >> (bit0 + 3)) & 1u) ? __expf(s[i][3]) : 0.0f;
            rs[i] += (p0 + p1) + (p2 + p3);
            p4 = make_float4(p0, p1, p2, p3);
            *(float4*)&KPs[ty * 4 + i][tx * 4] = p4;   // row-major P [q][k]
        }
        __syncthreads();

        // PV: o[i][c] += sum_k P[q_i][k] * V[k][d_c], float4 along k
#pragma unroll 4
        for (int k4 = 0; k4 < 16; k4++) {
            float4 bv0 = *(const float4*)&Vs[k4 * 4 + 0][tx * 4];
            float4 bv1 = *(const float4*)&Vs[k4 * 4 + 1][tx * 4];
            float4 bv2 = *(const float4*)&Vs[k4 * 4 + 2][tx * 4];
            float4 bv3 = *(const float4*)&Vs[k4 * 4 + 3][tx * 4];
#pragma unroll
            for (int i = 0; i < 4; i++) {
                float4 p4 = *(const float4*)&KPs[ty * 4 + i][k4 * 4];
                o[i][0] += p4.x * bv0.x + p4.y * bv1.x + p4.z * bv2.x + p4.w * bv3.x;
                o[i][1] += p4.x * bv0.y + p4.y * bv1.y + p4.z * bv2.y + p4.w * bv3.y;
                o[i][2] += p4.x * bv0.z + p4.y * bv1.z + p4.z * bv2.z + p4.w * bv3.z;
                o[i][3] += p4.x * bv0.w + p4.y * bv1.w + p4.z * bv2.w + p4.w * bv3.w;
            }
        }
    }

#pragma unroll
    for (int i = 0; i < 4; i++) {
#pragma unroll
        for (int off = 1; off < 16; off <<= 1)
            rs[i] += __shfl_xor(rs[i], off, 64);
    }

#pragma unroll
    for (int i = 0; i < 4; i++) {
        float inv = 1.0f / rs[i];
        size_t ob = (size_t)(q0 + ty * 4 + i) * 1024 + h * 64 + tx * 4;
        ushort4 hv, lv;
        float v0 = o[i][0] * inv; hv.x = f2bf(v0); lv.x = f2bf(v0 - bf2f(hv.x));
        float v1 = o[i][1] * inv; hv.y = f2bf(v1); lv.y = f2bf(v1 - bf2f(hv.y));
        float v2 = o[i][2] * inv; hv.z = f2bf(v2); lv.z = f2bf(v2 - bf2f(hv.z));
        float v3 = o[i][3] * inv; hv.w = f2bf(v3); lv.w = f2bf(v3 - bf2f(hv.w));
        *(ushort4*)&outh[ob] = hv;
        *(ushort4*)&outl[ob] = lv;
    }
}

// ---------------------------------------------------------------------------
extern "C" void kernel_launch(void* const* d_in, const int* in_sizes, int n_in,
                              void* d_out, int out_size, void* d_ws, size_t ws_size,
                              hipStream_t stream)
{
    const float* hidden  = (const float*)d_in[0];
    const int*   coords  = (const int*)d_in[1];
    const float* rope    = (const float*)d_in[3];
    const float* Wq_idx  = (const float*)d_in[4];
    const float* Wk_idx  = (const float*)d_in[5];
    const float* W1g     = (const float*)d_in[6];
    const float* b1g     = (const float*)d_in[7];
    const float* W2g     = (const float*)d_in[8];
    const float* b2g     = (const float*)d_in[9];
    const float* rpe     = (const float*)d_in[10];
    const float* Wqkv_d  = (const float*)d_in[11];
    const float* bqkv_d  = (const float*)d_in[12];
    const float* Wqkv_u  = (const float*)d_in[13];
    const float* bqkv_u  = (const float*)d_in[14];
    const float* Wp_d    = (const float*)d_in[15];
    const float* bp_d    = (const float*)d_in[16];
    const float* Wp_u    = (const float*)d_in[17];
    const float* bp_u    = (const float*)d_in[18];
    const float* scaler  = (const float*)d_in[19];
    float* out = (float*)d_out;

    // Workspace: split hi/lo (ushort), mid hi/lo [S,256], qkv fp32, qIk fp32,
    // selmask. attout hi/lo reuse hidden's split slots (dead after gemm1).
    unsigned short* sp_hi  = (unsigned short*)d_ws;
    unsigned short* sp_lo  = sp_hi + NSPLIT_;
    unsigned short* mid_hi = sp_lo + NSPLIT_;
    unsigned short* mid_lo = mid_hi + (size_t)S_ * BOT_;
    float* qkv = (float*)(mid_lo + (size_t)S_ * BOT_);
    float* qIk = qkv + (size_t)S_ * 3 * DIM_;
    unsigned* selmask = (unsigned*)(qIk + (size_t)S_ * 256);

    // 0) split hidden + all weights into hi/lo bf16
    split_all_kernel<<<(NSPLIT_ / 4 + 255) / 256, 256, 0, stream>>>(
        hidden, Wqkv_d, Wq_idx, Wk_idx, Wqkv_u, Wp_d, Wp_u, sp_hi, sp_lo);

    // 1) fused gemm1: hidden @ [Wqkv_d;Wq;Wk]^T -> mid(hi/lo) + qIk(fp32)
    gemm64_bf16x3<<<dim3(512 / 64, S_ / 64), 256, 0, stream>>>(
        sp_hi, sp_lo, sp_hi + OFF_W1_, sp_lo + OFF_W1_,
        bqkv_d, nullptr, qIk, mid_hi, mid_lo, S_, 512, DIM_, 256);

    // 2) qkv = mid @ Wqkv_u^T + b (fp32)
    gemm_bf16x3<<<dim3(3 * DIM_ / 64, S_ / 128), 256, 0, stream>>>(
        mid_hi, mid_lo, sp_hi + OFF_WQKVU_, sp_lo + OFF_WQKVU_,
        bqkv_u, nullptr, qkv, S_, 3 * DIM_, BOT_);

    // 3) RoPE on q,k in place
    rope_kernel<<<(S_ * H_ * 32) / 256, 256, 0, stream>>>(qkv, rope);

    // 4) fused index scores + top-k membership
    score_topk_kernel<<<S_ / 4, 256, 0, stream>>>(
        qIk, coords, rpe, W1g, b1g, W2g, b2g, selmask);

    // 5) dense-masked attention (emits attout hi/lo into hidden's split slots)
    attn_kernel<<<NIMG_ * H_ * 8, 256, 0, stream>>>(qkv, selmask, sp_hi, sp_lo);

    // 6) mid2 = attout @ Wp_d^T + b (hi/lo, all cols)
    gemm64_bf16x3<<<dim3(BOT_ / 64, S_ / 64), 256, 0, stream>>>(
        sp_hi, sp_lo, sp_hi + OFF_WPD_, sp_lo + OFF_WPD_,
        bp_d, nullptr, nullptr, mid_hi, mid_lo, S_, BOT_, DIM_, BOT_);

    // 7) out = mid2 @ Wp_u^T + b, *scaler (fp32)
    gemm_bf16x3<<<dim3(DIM_ / 64, S_ / 128), 256, 0, stream>>>(
        mid_hi, mid_lo, sp_hi + OFF_WPU_, sp_lo + OFF_WPU_,
        bp_u, scaler, out, S_, DIM_, BOT_);
}

// Round 11
// 290.267 us; speedup vs baseline: 3.5019x; 1.0532x over previous
//
#include <hip/hip_runtime.h>
#include <hip/hip_bf16.h>

// Problem constants
#define S_    2048
#define DIM_  1024
#define H_    16
#define DH_   64
#define BOT_  256
#define NIMG_ 4
#define LI_   512
#define K_    256
#define IH_   4
#define ID_   16
#define MAXREL_ 64
#define NBUCK_ 129
#define GH_   8
#define IDH2_ 128   // 2*IH*ID

typedef short bf16x8 __attribute__((ext_vector_type(8)));
typedef float f32x4  __attribute__((ext_vector_type(4)));

__device__ __forceinline__ unsigned short f2bf(float x) {   // RNE float->bf16
    unsigned u = __float_as_uint(x);
    return (unsigned short)((u + 0x7fffu + ((u >> 16) & 1u)) >> 16);
}
__device__ __forceinline__ float bf2f(unsigned short h) {
    return __uint_as_float(((unsigned)h) << 16);
}

// Split-region element offsets (ushort units). W1 = [Wqkv_d;Wq;Wk] contiguous
// so gemm1 sees one 512x1024 B matrix.
#define OFF_W1_    2097152                   // hidden 2048x1024 before it
#define OFF_WQ_    2359296                   // = OFF_W1_ + 256*1024
#define OFF_WK_    2490368                   // + 128*1024
#define OFF_WQKVU_ 2621440                   // + 128*1024
#define OFF_WPD_   3407872                   // + 3072*256
#define OFF_WPU_   3670016                   // + 256*1024
#define NSPLIT_    3932160                   // + 1024*256

// ---------------------------------------------------------------------------
// Fused hi/lo bf16 split of hidden + all 6 weight matrices (one launch).
// ---------------------------------------------------------------------------
__global__ __launch_bounds__(256) void split_all_kernel(
    const float* __restrict__ hid, const float* __restrict__ wqd,
    const float* __restrict__ wq,  const float* __restrict__ wk,
    const float* __restrict__ wqu, const float* __restrict__ wpd,
    const float* __restrict__ wpu,
    unsigned short* __restrict__ hi, unsigned short* __restrict__ lo)
{
    long e = ((long)blockIdx.x * 256 + threadIdx.x) * 4;
    if (e >= NSPLIT_) return;
    const float* src; long off;
    if (e < OFF_W1_)         { src = hid; off = 0; }
    else if (e < OFF_WQ_)    { src = wqd; off = OFF_W1_; }
    else if (e < OFF_WK_)    { src = wq;  off = OFF_WQ_; }
    else if (e < OFF_WQKVU_) { src = wk;  off = OFF_WK_; }
    else if (e < OFF_WPD_)   { src = wqu; off = OFF_WQKVU_; }
    else if (e < OFF_WPU_)   { src = wpd; off = OFF_WPD_; }
    else                     { src = wpu; off = OFF_WPU_; }
    float4 v = *(const float4*)(src + (e - off));
    ushort4 h, l;
    h.x = f2bf(v.x); l.x = f2bf(v.x - bf2f(h.x));
    h.y = f2bf(v.y); l.y = f2bf(v.y - bf2f(h.y));
    h.z = f2bf(v.z); l.z = f2bf(v.z - bf2f(h.z));
    h.w = f2bf(v.w); l.w = f2bf(v.w - bf2f(h.w));
    *(ushort4*)&hi[e] = h;
    *(ushort4*)&lo[e] = l;
}

// ---------------------------------------------------------------------------
// bf16x3 MFMA GEMM, 128x64 tile (for large-N call sites: qkv_u, p_u).
// fp32 output + bias + optional scale. 4 waves 2x2, wave 64x32.
// ---------------------------------------------------------------------------
__global__ __launch_bounds__(256) void gemm_bf16x3(
    const unsigned short* __restrict__ Ah, const unsigned short* __restrict__ Al,
    const unsigned short* __restrict__ Bh, const unsigned short* __restrict__ Bl,
    const float* __restrict__ bias, const float* __restrict__ scale_ptr,
    float* __restrict__ Cf, int M, int N, int Kd)
{
    __shared__ unsigned short sAh[128 * 40], sAl[128 * 40];
    __shared__ unsigned short sBh[64 * 40],  sBl[64 * 40];
    int tid = threadIdx.x;
    int lane = tid & 63, wv = tid >> 6;
    int wr = wv >> 1, wc = wv & 1;
    int row0 = blockIdx.y * 128, col0 = blockIdx.x * 64;

    f32x4 acc[4][2];
#pragma unroll
    for (int i = 0; i < 4; i++)
#pragma unroll
        for (int j = 0; j < 2; j++) acc[i][j] = (f32x4){0.f, 0.f, 0.f, 0.f};

    int ar = tid >> 1, ac = (tid & 1) * 16;
    int br = tid >> 2, bc = (tid & 3) * 8;
    const unsigned short* gAh = Ah + (size_t)(row0 + ar) * Kd + ac;
    const unsigned short* gAl = Al + (size_t)(row0 + ar) * Kd + ac;
    const unsigned short* gBh = Bh + (size_t)(col0 + br) * Kd + bc;
    const unsigned short* gBl = Bl + (size_t)(col0 + br) * Kd + bc;
    int am = lane & 15, qk = (lane >> 4) * 8;

    for (int k0 = 0; k0 < Kd; k0 += 32) {
        __syncthreads();
        *(float4*)&sAh[ar * 40 + ac]     = *(const float4*)(gAh + k0);
        *(float4*)&sAh[ar * 40 + ac + 8] = *(const float4*)(gAh + k0 + 8);
        *(float4*)&sAl[ar * 40 + ac]     = *(const float4*)(gAl + k0);
        *(float4*)&sAl[ar * 40 + ac + 8] = *(const float4*)(gAl + k0 + 8);
        *(float4*)&sBh[br * 40 + bc]     = *(const float4*)(gBh + k0);
        *(float4*)&sBl[br * 40 + bc]     = *(const float4*)(gBl + k0);
        __syncthreads();

        bf16x8 ah[4], al[4], bh[2], bl[2];
#pragma unroll
        for (int rt = 0; rt < 4; rt++) {
            int r = wr * 64 + rt * 16 + am;
            ah[rt] = *(const bf16x8*)&sAh[r * 40 + qk];
            al[rt] = *(const bf16x8*)&sAl[r * 40 + qk];
        }
#pragma unroll
        for (int ct = 0; ct < 2; ct++) {
            int c = wc * 32 + ct * 16 + am;
            bh[ct] = *(const bf16x8*)&sBh[c * 40 + qk];
            bl[ct] = *(const bf16x8*)&sBl[c * 40 + qk];
        }
#pragma unroll
        for (int rt = 0; rt < 4; rt++)
#pragma unroll
            for (int ct = 0; ct < 2; ct++) {
                acc[rt][ct] = __builtin_amdgcn_mfma_f32_16x16x32_bf16(ah[rt], bh[ct], acc[rt][ct], 0, 0, 0);
                acc[rt][ct] = __builtin_amdgcn_mfma_f32_16x16x32_bf16(ah[rt], bl[ct], acc[rt][ct], 0, 0, 0);
                acc[rt][ct] = __builtin_amdgcn_mfma_f32_16x16x32_bf16(al[rt], bh[ct], acc[rt][ct], 0, 0, 0);
            }
    }

    float scl = scale_ptr ? *scale_ptr : 1.0f;
    int rq = (lane >> 4) * 4;
#pragma unroll
    for (int rt = 0; rt < 4; rt++)
#pragma unroll
        for (int ct = 0; ct < 2; ct++) {
            int col = col0 + wc * 32 + ct * 16 + am;
            float bz = bias ? bias[col] : 0.0f;
#pragma unroll
            for (int rg = 0; rg < 4; rg++) {
                int row = row0 + wr * 64 + rt * 16 + rq + rg;
                Cf[(size_t)row * N + col] = (acc[rt][ct][rg] + bz) * scl;
            }
        }
}

// ---------------------------------------------------------------------------
// bf16x3 MFMA GEMM, 64x64 tile (small-N call sites: gemm1 N=512, p_d N=256).
// Epilogue splits by column: col < split_col -> hi/lo bf16 pair (width
// split_col, bias_lo); col >= split_col -> fp32 (width N-split_col, bias_hi).
// ---------------------------------------------------------------------------
__global__ __launch_bounds__(256) void gemm64_bf16x3(
    const unsigned short* __restrict__ Ah, const unsigned short* __restrict__ Al,
    const unsigned short* __restrict__ Bh, const unsigned short* __restrict__ Bl,
    const float* __restrict__ bias_lo, const float* __restrict__ bias_hi,
    float* __restrict__ Cf, unsigned short* __restrict__ Chi,
    unsigned short* __restrict__ Clo, int M, int N, int Kd, int split_col)
{
    __shared__ unsigned short sAh[64 * 40], sAl[64 * 40];
    __shared__ unsigned short sBh[64 * 40], sBl[64 * 40];
    int tid = threadIdx.x;
    int lane = tid & 63, wv = tid >> 6;
    int wr = wv >> 1, wc = wv & 1;          // wave 32x32
    int row0 = blockIdx.y * 64, col0 = blockIdx.x * 64;

    f32x4 acc[2][2];
#pragma unroll
    for (int i = 0; i < 2; i++)
#pragma unroll
        for (int j = 0; j < 2; j++) acc[i][j] = (f32x4){0.f, 0.f, 0.f, 0.f};

    int sr = tid >> 2, sc = (tid & 3) * 8;
    const unsigned short* gAh = Ah + (size_t)(row0 + sr) * Kd + sc;
    const unsigned short* gAl = Al + (size_t)(row0 + sr) * Kd + sc;
    const unsigned short* gBh = Bh + (size_t)(col0 + sr) * Kd + sc;
    const unsigned short* gBl = Bl + (size_t)(col0 + sr) * Kd + sc;
    int am = lane & 15, qk = (lane >> 4) * 8;

    for (int k0 = 0; k0 < Kd; k0 += 32) {
        __syncthreads();
        *(float4*)&sAh[sr * 40 + sc] = *(const float4*)(gAh + k0);
        *(float4*)&sAl[sr * 40 + sc] = *(const float4*)(gAl + k0);
        *(float4*)&sBh[sr * 40 + sc] = *(const float4*)(gBh + k0);
        *(float4*)&sBl[sr * 40 + sc] = *(const float4*)(gBl + k0);
        __syncthreads();

        bf16x8 ah[2], al[2], bh[2], bl[2];
#pragma unroll
        for (int rt = 0; rt < 2; rt++) {
            int r = wr * 32 + rt * 16 + am;
            ah[rt] = *(const bf16x8*)&sAh[r * 40 + qk];
            al[rt] = *(const bf16x8*)&sAl[r * 40 + qk];
        }
#pragma unroll
        for (int ct = 0; ct < 2; ct++) {
            int c = wc * 32 + ct * 16 + am;
            bh[ct] = *(const bf16x8*)&sBh[c * 40 + qk];
            bl[ct] = *(const bf16x8*)&sBl[c * 40 + qk];
        }
#pragma unroll
        for (int rt = 0; rt < 2; rt++)
#pragma unroll
            for (int ct = 0; ct < 2; ct++) {
                acc[rt][ct] = __builtin_amdgcn_mfma_f32_16x16x32_bf16(ah[rt], bh[ct], acc[rt][ct], 0, 0, 0);
                acc[rt][ct] = __builtin_amdgcn_mfma_f32_16x16x32_bf16(ah[rt], bl[ct], acc[rt][ct], 0, 0, 0);
                acc[rt][ct] = __builtin_amdgcn_mfma_f32_16x16x32_bf16(al[rt], bh[ct], acc[rt][ct], 0, 0, 0);
            }
    }

    int rq = (lane >> 4) * 4;
#pragma unroll
    for (int rt = 0; rt < 2; rt++)
#pragma unroll
        for (int ct = 0; ct < 2; ct++) {
            int col = col0 + wc * 32 + ct * 16 + am;
#pragma unroll
            for (int rg = 0; rg < 4; rg++) {
                int row = row0 + wr * 32 + rt * 16 + rq + rg;
                float v = acc[rt][ct][rg];
                if (col < split_col) {
                    if (bias_lo) v += bias_lo[col];
                    size_t idx = (size_t)row * split_col + col;
                    unsigned short hh = f2bf(v);
                    Chi[idx] = hh;
                    Clo[idx] = f2bf(v - bf2f(hh));
                } else {
                    if (bias_hi) v += bias_hi[col - split_col];
                    Cf[(size_t)row * (N - split_col) + col - split_col] = v;
                }
            }
        }
}

// ---------------------------------------------------------------------------
// RoPE applied in-place to q and k slices of qkv[S,3072].
// ---------------------------------------------------------------------------
__global__ __launch_bounds__(256) void rope_kernel(
    float* __restrict__ qkv, const float* __restrict__ rope)
{
    int idx = blockIdx.x * blockDim.x + threadIdx.x;  // S*H*32 total
    if (idx >= S_ * H_ * 32) return;
    int d = idx & 31;
    int h = (idx >> 5) & (H_ - 1);
    int s = idx >> 9;
    float r = rope[s * 32 + d];
    float c = cosf(r), sn = sinf(r);
    size_t base = (size_t)s * 3072 + h * 64 + d;
    float q1 = qkv[base], q2 = qkv[base + 32];
    qkv[base]      = q1 * c - q2 * sn;
    qkv[base + 32] = q2 * c + q1 * sn;
    float k1 = qkv[base + 1024], k2 = qkv[base + 1024 + 32];
    qkv[base + 1024]      = k1 * c - k2 * sn;
    qkv[base + 1024 + 32] = k2 * c + k1 * sn;
}

// ---------------------------------------------------------------------------
// Fused index scores + top-K membership. qI/kI in one combined fp32 buffer
// qIk[S,256]: qI = cols 0..127, kI = cols 128..255. (R10-passing, unchanged.)
// ---------------------------------------------------------------------------
__global__ __launch_bounds__(256) void score_topk_kernel(
    const float* __restrict__ qIk,
    const int* __restrict__ coords, const float* __restrict__ rpe_table,
    const float* __restrict__ W1g, const float* __restrict__ b1g,
    const float* __restrict__ W2g, const float* __restrict__ b2g,
    unsigned* __restrict__ selmask)
{
    __shared__ float skI[64][132];
    __shared__ float sqI2[4][IDH2_];
    __shared__ unsigned skeys[4][LI_];
    __shared__ int shist[4][256];
    __shared__ float srpe[NBUCK_ * IH_];
    __shared__ float sW1[GH_ * IH_], sb1[GH_], sW2[IH_ * GH_], sb2[IH_];

    int tid  = threadIdx.x;
    int lane = tid & 63;
    int wv   = tid >> 6;
    int row  = blockIdx.x * 4 + wv;
    int n    = (blockIdx.x * 4) >> 9;

    for (int i = tid; i < NBUCK_ * IH_; i += 256) srpe[i] = rpe_table[i];
    if (tid < 32) sW1[tid] = W1g[tid];
    else if (tid < 64) sW2[tid - 32] = W2g[tid - 32];
    else if (tid < 72) sb1[tid - 64] = b1g[tid - 64];
    else if (tid < 76) sb2[tid - 72] = b2g[tid - 72];
    for (int i = tid; i < 4 * IDH2_; i += 256)
        sqI2[i >> 7][i & 127] =
            qIk[(size_t)(blockIdx.x * 4 + (i >> 7)) * 256 + (i & 127)];
    int pq = coords[row * 2 + 1];

    for (int kt = 0; kt < 8; kt++) {
        __syncthreads();
        {
            int r  = tid >> 2;
            int d0 = (tid & 3) * 32;
            const float* src = qIk + (size_t)(n * LI_ + kt * 64 + r) * 256 + 128 + d0;
#pragma unroll
            for (int j = 0; j < 8; j++)
                *(float4*)&skI[r][d0 + j * 4] = *(const float4*)(src + j * 4);
        }
        __syncthreads();

        int kloc = lane;
        int kg   = kt * 64 + kloc;
        const float* sq = &sqI2[wv][0];
        float dh[8];
#pragma unroll
        for (int hh = 0; hh < 8; hh++) {
            float acc = 0.0f;
#pragma unroll
            for (int d = 0; d < 16; d += 4) {
                float4 kv = *(const float4*)&skI[kloc][hh * 16 + d];
                acc += sq[hh * 16 + d + 0] * kv.x + sq[hh * 16 + d + 1] * kv.y +
                       sq[hh * 16 + d + 2] * kv.z + sq[hh * 16 + d + 3] * kv.w;
            }
            dh[hh] = acc;
        }
        int pk = coords[(n * LI_ + kg) * 2 + 1];
        int rel = pq - pk;
        rel = rel < -MAXREL_ ? -MAXREL_ : (rel > MAXREL_ ? MAXREL_ : rel);
        const float* rp = srpe + (rel + MAXREL_) * IH_;
        float t1[GH_];
#pragma unroll
        for (int g = 0; g < GH_; g++) t1[g] = sb1[g];
#pragma unroll
        for (int j = 0; j < IH_; j++) {
            float gate = dh[IH_ + j] + rp[j];
#pragma unroll
            for (int g = 0; g < GH_; g++) t1[g] += gate * sW1[g * IH_ + j];
        }
#pragma unroll
        for (int g = 0; g < GH_; g++) t1[g] = fmaxf(t1[g], 0.0f);
        float score = 0.0f;
#pragma unroll
        for (int j = 0; j < IH_; j++) {
            float t2 = sb2[j];
#pragma unroll
            for (int g = 0; g < GH_; g++) t2 += t1[g] * sW2[j * GH_ + g];
            float sg = 1.0f / (1.0f + expf(-t2));
            float rs = fmaxf(dh[j] + rp[j], 0.0f);
            score += rs * sg;
        }
        unsigned bits = __float_as_uint(score);
        skeys[wv][kg] = (bits & 0x80000000u) ? ~bits : (bits | 0x80000000u);
    }
    __syncthreads();

    unsigned pref = 0u;
    int kcur = K_;
    const unsigned himask[4] = {0u, 0xFF000000u, 0xFFFF0000u, 0xFFFFFF00u};
#pragma unroll
    for (int pass = 0; pass < 4; pass++) {
        int shift = 24 - pass * 8;
        unsigned hm = himask[pass];
        *(int4*)&shist[wv][4 * lane] = make_int4(0, 0, 0, 0);
        __syncthreads();
#pragma unroll
        for (int c = 0; c < 8; c++) {
            unsigned key = skeys[wv][c * 64 + lane];
            if ((key & hm) == pref) atomicAdd(&shist[wv][(key >> shift) & 255], 1);
        }
        __syncthreads();
        int4 b4 = *(const int4*)&shist[wv][4 * lane];
        int b[4] = {b4.x, b4.y, b4.z, b4.w};
        int t = b[0] + b[1] + b[2] + b[3];
        int Ssum = t;
#pragma unroll
        for (int off = 1; off < 64; off <<= 1) {
            int u = __shfl_down(Ssum, off, 64);
            if (lane + off < 64) Ssum += u;
        }
        int E = Ssum - t;
        int cs[5];
        cs[4] = E;
        cs[3] = b[3] + E;
        cs[2] = b[2] + cs[3];
        cs[1] = b[1] + cs[2];
        cs[0] = b[0] + cs[1];
        bool found = false;
        unsigned cpref = 0u; int ck = 0;
#pragma unroll
        for (int j = 0; j < 4; j++) {
            if (!found && cs[j] >= kcur && cs[j + 1] < kcur) {
                found = true;
                cpref = pref | ((unsigned)(4 * lane + j) << shift);
                ck = kcur - cs[j + 1];
            }
        }
        unsigned long long bm = __ballot(found);
        int src = __ffsll((long long)bm) - 1;
        pref = (unsigned)__shfl((int)cpref, src, 64);
        kcur = __shfl(ck, src, 64);
        __syncthreads();
    }
    unsigned Tu = pref;

    unsigned long long bg[8], be[8];
#pragma unroll
    for (int c = 0; c < 8; c++) {
        unsigned key = skeys[wv][c * 64 + lane];
        bg[c] = __ballot(key > Tu);
        be[c] = __ballot(key == Tu);
    }
    if (lane < 16) {
        int total_gt = 0;
#pragma unroll
        for (int c = 0; c < 8; c++) total_gt += __popcll(bg[c]);
        int base = 0;
#pragma unroll
        for (int c = 0; c < 8; c++) {
            if (2 * c < lane)     base += __popc((unsigned)be[c]);
            if (2 * c + 1 < lane) base += __popc((unsigned)(be[c] >> 32));
        }
        unsigned gw = (unsigned)(bg[lane >> 1] >> (32 * (lane & 1)));
        unsigned ew = (unsigned)(be[lane >> 1] >> (32 * (lane & 1)));
        int ne = K_ - total_gt - base;
        int pc = __popc(ew);
        int m = ne < 0 ? 0 : (ne > pc ? pc : ne);
        while (pc > m) { ew ^= (1u << (31 - __clz(ew))); pc--; }
        selmask[(size_t)row * 16 + lane] = gw | ew;
    }
}

// ---------------------------------------------------------------------------
// Dense-masked tiled attention v3.
// Block decode swizzled for XCD L2 locality: qt in HIGH bits (b>>6), so all
// 8 q-tiles of one (n,h) share b%64 -> same XCD (blockIdx%8 round-robin),
// K/V head slice fetched once per (n,h) instead of 8x.
// P stored as P^T[k][q] via float4-over-q writes (banks 4*ty: 2-way, free);
// PV is per-k outer product with 2-way-max LDS reads. Kills R10's 8-way
// P-read conflict (stride 68, every-4th-row pattern).
// ---------------------------------------------------------------------------
__global__ __launch_bounds__(256) void attn_kernel(
    const float* __restrict__ qkv, const unsigned* __restrict__ selmask,
    unsigned short* __restrict__ outh, unsigned short* __restrict__ outl)
{
    __shared__ float Qs[64][68];     // [d][q]  (Q scaled by 1/8)
    __shared__ float KPs[64][68];    // QK phase: K^T [d][k]; PV phase: P^T [k][q]
    __shared__ float Vs[64][68];     // [k][d]
    __shared__ unsigned Ms[64][16];

    int b  = blockIdx.x;
    int qt = b >> 6;                 // swizzle: qt in high bits
    int nh = b & 63;
    int h  = nh & 15;
    int n  = nh >> 4;
    int tid = threadIdx.x;
    int tx = tid & 15, ty = tid >> 4;
    int q0 = n * LI_ + qt * 64;

    for (int i = tid; i < 64 * 16; i += 256)
        Ms[i >> 4][i & 15] = selmask[(size_t)(q0 + (i >> 4)) * 16 + (i & 15)];

#pragma unroll
    for (int m = 0; m < 4; m++) {
        int r = (tid >> 4) + m * 16;
        int c = tid & 15;
        float4 v = *(const float4*)(qkv + (size_t)(q0 + r) * 3072 + h * 64 + c * 4);
        Qs[c * 4 + 0][r] = v.x * 0.125f;
        Qs[c * 4 + 1][r] = v.y * 0.125f;
        Qs[c * 4 + 2][r] = v.z * 0.125f;
        Qs[c * 4 + 3][r] = v.w * 0.125f;
    }

    float o[4][4] = {};
    float rs[4] = {};

    for (int kt = 0; kt < 8; kt++) {
        __syncthreads();   // prev PV reads done before restaging
#pragma unroll
        for (int m = 0; m < 4; m++) {
            int r = (tid >> 4) + m * 16;
            int c = tid & 15;
            size_t krow = (size_t)(n * LI_ + kt * 64 + r) * 3072 + h * 64;
            float4 kv = *(const float4*)(qkv + krow + 1024 + c * 4);
            KPs[c * 4 + 0][r] = kv.x;
            KPs[c * 4 + 1][r] = kv.y;
            KPs[c * 4 + 2][r] = kv.z;
            KPs[c * 4 + 3][r] = kv.w;
            float4 vv = *(const float4*)(qkv + krow + 2048 + c * 4);
            *(float4*)&Vs[r][c * 4] = vv;
        }
        __syncthreads();

        // QK: s[i][j], q = ty*4+i, k = tx*4+j
        float s[4][4] = {};
#pragma unroll 8
        for (int d = 0; d < 64; d++) {
            float4 a4 = *(const float4*)&Qs[d][ty * 4];
            float4 b4 = *(const float4*)&KPs[d][tx * 4];
            float a[4] = {a4.x, a4.y, a4.z, a4.w};
            float bb[4] = {b4.x, b4.y, b4.z, b4.w};
#pragma unroll
            for (int i = 0; i < 4; i++)
#pragma unroll
                for (int j = 0; j < 4; j++)
                    s[i][j] += a[i] * bb[j];
        }

        // mask + exp into registers (no LDS touch yet)
        int kbase = kt * 64 + tx * 4;
        int wi = kbase >> 5;
        int bit0 = kbase & 31;
        float pcol[4][4];   // [j][i]
#pragma unroll
        for (int i = 0; i < 4; i++) {
            unsigned mw = Ms[ty * 4 + i][wi];
#pragma unroll
            for (int j = 0; j < 4; j++) {
                float p = ((mw >> (bit0 + j)) & 1u) ? __expf(s[i][j]) : 0.0f;
                rs[i] += p;
                pcol[j][i] = p;
            }
        }
        __syncthreads();   // all QK reads of KPs complete before P^T overwrite

        // write P^T[k][q]: float4 along q (banks 4*ty -> 2-way, free)
#pragma unroll
        for (int j = 0; j < 4; j++)
            *(float4*)&KPs[tx * 4 + j][ty * 4] =
                make_float4(pcol[j][0], pcol[j][1], pcol[j][2], pcol[j][3]);
        __syncthreads();

        // PV: per-k outer product; P4 over q (2-way), V4 over d (2-way)
#pragma unroll 4
        for (int k = 0; k < 64; k++) {
            float4 p4 = *(const float4*)&KPs[k][ty * 4];
            float4 v4 = *(const float4*)&Vs[k][tx * 4];
            o[0][0] += p4.x * v4.x; o[0][1] += p4.x * v4.y;
            o[0][2] += p4.x * v4.z; o[0][3] += p4.x * v4.w;
            o[1][0] += p4.y * v4.x; o[1][1] += p4.y * v4.y;
            o[1][2] += p4.y * v4.z; o[1][3] += p4.y * v4.w;
            o[2][0] += p4.z * v4.x; o[2][1] += p4.z * v4.y;
            o[2][2] += p4.z * v4.z; o[2][3] += p4.z * v4.w;
            o[3][0] += p4.w * v4.x; o[3][1] += p4.w * v4.y;
            o[3][2] += p4.w * v4.z; o[3][3] += p4.w * v4.w;
        }
    }

#pragma unroll
    for (int i = 0; i < 4; i++) {
#pragma unroll
        for (int off = 1; off < 16; off <<= 1)
            rs[i] += __shfl_xor(rs[i], off, 64);
    }

#pragma unroll
    for (int i = 0; i < 4; i++) {
        float inv = 1.0f / rs[i];
        size_t ob = (size_t)(q0 + ty * 4 + i) * 1024 + h * 64 + tx * 4;
        ushort4 hv, lv;
        float v0 = o[i][0] * inv; hv.x = f2bf(v0); lv.x = f2bf(v0 - bf2f(hv.x));
        float v1 = o[i][1] * inv; hv.y = f2bf(v1); lv.y = f2bf(v1 - bf2f(hv.y));
        float v2 = o[i][2] * inv; hv.z = f2bf(v2); lv.z = f2bf(v2 - bf2f(hv.z));
        float v3 = o[i][3] * inv; hv.w = f2bf(v3); lv.w = f2bf(v3 - bf2f(hv.w));
        *(ushort4*)&outh[ob] = hv;
        *(ushort4*)&outl[ob] = lv;
    }
}

// ---------------------------------------------------------------------------
extern "C" void kernel_launch(void* const* d_in, const int* in_sizes, int n_in,
                              void* d_out, int out_size, void* d_ws, size_t ws_size,
                              hipStream_t stream)
{
    const float* hidden  = (const float*)d_in[0];
    const int*   coords  = (const int*)d_in[1];
    const float* rope    = (const float*)d_in[3];
    const float* Wq_idx  = (const float*)d_in[4];
    const float* Wk_idx  = (const float*)d_in[5];
    const float* W1g     = (const float*)d_in[6];
    const float* b1g     = (const float*)d_in[7];
    const float* W2g     = (const float*)d_in[8];
    const float* b2g     = (const float*)d_in[9];
    const float* rpe     = (const float*)d_in[10];
    const float* Wqkv_d  = (const float*)d_in[11];
    const float* bqkv_d  = (const float*)d_in[12];
    const float* Wqkv_u  = (const float*)d_in[13];
    const float* bqkv_u  = (const float*)d_in[14];
    const float* Wp_d    = (const float*)d_in[15];
    const float* bp_d    = (const float*)d_in[16];
    const float* Wp_u    = (const float*)d_in[17];
    const float* bp_u    = (const float*)d_in[18];
    const float* scaler  = (const float*)d_in[19];
    float* out = (float*)d_out;

    // Workspace: split hi/lo (ushort), mid hi/lo [S,256], qkv fp32, qIk fp32,
    // selmask. attout hi/lo reuse hidden's split slots (dead after gemm1).
    unsigned short* sp_hi  = (unsigned short*)d_ws;
    unsigned short* sp_lo  = sp_hi + NSPLIT_;
    unsigned short* mid_hi = sp_lo + NSPLIT_;
    unsigned short* mid_lo = mid_hi + (size_t)S_ * BOT_;
    float* qkv = (float*)(mid_lo + (size_t)S_ * BOT_);
    float* qIk = qkv + (size_t)S_ * 3 * DIM_;
    unsigned* selmask = (unsigned*)(qIk + (size_t)S_ * 256);

    // 0) split hidden + all weights into hi/lo bf16
    split_all_kernel<<<(NSPLIT_ / 4 + 255) / 256, 256, 0, stream>>>(
        hidden, Wqkv_d, Wq_idx, Wk_idx, Wqkv_u, Wp_d, Wp_u, sp_hi, sp_lo);

    // 1) fused gemm1: hidden @ [Wqkv_d;Wq;Wk]^T -> mid(hi/lo) + qIk(fp32)
    gemm64_bf16x3<<<dim3(512 / 64, S_ / 64), 256, 0, stream>>>(
        sp_hi, sp_lo, sp_hi + OFF_W1_, sp_lo + OFF_W1_,
        bqkv_d, nullptr, qIk, mid_hi, mid_lo, S_, 512, DIM_, 256);

    // 2) qkv = mid @ Wqkv_u^T + b (fp32)
    gemm_bf16x3<<<dim3(3 * DIM_ / 64, S_ / 128), 256, 0, stream>>>(
        mid_hi, mid_lo, sp_hi + OFF_WQKVU_, sp_lo + OFF_WQKVU_,
        bqkv_u, nullptr, qkv, S_, 3 * DIM_, BOT_);

    // 3) RoPE on q,k in place
    rope_kernel<<<(S_ * H_ * 32) / 256, 256, 0, stream>>>(qkv, rope);

    // 4) fused index scores + top-k membership
    score_topk_kernel<<<S_ / 4, 256, 0, stream>>>(
        qIk, coords, rpe, W1g, b1g, W2g, b2g, selmask);

    // 5) dense-masked attention (emits attout hi/lo into hidden's split slots)
    attn_kernel<<<NIMG_ * H_ * 8, 256, 0, stream>>>(qkv, selmask, sp_hi, sp_lo);

    // 6) mid2 = attout @ Wp_d^T + b (hi/lo, all cols)
    gemm64_bf16x3<<<dim3(BOT_ / 64, S_ / 64), 256, 0, stream>>>(
        sp_hi, sp_lo, sp_hi + OFF_WPD_, sp_lo + OFF_WPD_,
        bp_d, nullptr, nullptr, mid_hi, mid_lo, S_, BOT_, DIM_, BOT_);

    // 7) out = mid2 @ Wp_u^T + b, *scaler (fp32)
    gemm_bf16x3<<<dim3(DIM_ / 64, S_ / 128), 256, 0, stream>>>(
        mid_hi, mid_lo, sp_hi + OFF_WPU_, sp_lo + OFF_WPU_,
        bp_u, scaler, out, S_, DIM_, BOT_);
}

// Round 12
// 255.282 us; speedup vs baseline: 3.9818x; 1.1370x over previous
//
#include <hip/hip_runtime.h>
#include <hip/hip_bf16.h>

// Problem constants
#define S_    2048
#define DIM_  1024
#define H_    16
#define DH_   64
#define BOT_  256
#define NIMG_ 4
#define LI_   512
#define K_    256
#define IH_   4
#define ID_   16
#define MAXREL_ 64
#define NBUCK_ 129
#define GH_   8
#define IDH2_ 128   // 2*IH*ID

typedef short bf16x8 __attribute__((ext_vector_type(8)));
typedef float f32x4  __attribute__((ext_vector_type(4)));

__device__ __forceinline__ unsigned short f2bf(float x) {   // RNE float->bf16
    unsigned u = __float_as_uint(x);
    return (unsigned short)((u + 0x7fffu + ((u >> 16) & 1u)) >> 16);
}
__device__ __forceinline__ float bf2f(unsigned short h) {
    return __uint_as_float(((unsigned)h) << 16);
}

// Split-region element offsets (ushort units). W1 = [Wqkv_d;Wq;Wk] contiguous.
#define OFF_W1_    2097152
#define OFF_WQ_    2359296
#define OFF_WK_    2490368
#define OFF_WQKVU_ 2621440
#define OFF_WPD_   3407872
#define OFF_WPU_   3670016
#define NSPLIT_    3932160

// ---------------------------------------------------------------------------
// Fused hi/lo bf16 split of hidden + all 6 weight matrices (one launch).
// ---------------------------------------------------------------------------
__global__ __launch_bounds__(256) void split_all_kernel(
    const float* __restrict__ hid, const float* __restrict__ wqd,
    const float* __restrict__ wq,  const float* __restrict__ wk,
    const float* __restrict__ wqu, const float* __restrict__ wpd,
    const float* __restrict__ wpu,
    unsigned short* __restrict__ hi, unsigned short* __restrict__ lo)
{
    long e = ((long)blockIdx.x * 256 + threadIdx.x) * 4;
    if (e >= NSPLIT_) return;
    const float* src; long off;
    if (e < OFF_W1_)         { src = hid; off = 0; }
    else if (e < OFF_WQ_)    { src = wqd; off = OFF_W1_; }
    else if (e < OFF_WK_)    { src = wq;  off = OFF_WQ_; }
    else if (e < OFF_WQKVU_) { src = wk;  off = OFF_WK_; }
    else if (e < OFF_WPD_)   { src = wqu; off = OFF_WQKVU_; }
    else if (e < OFF_WPU_)   { src = wpd; off = OFF_WPD_; }
    else                     { src = wpu; off = OFF_WPU_; }
    float4 v = *(const float4*)(src + (e - off));
    ushort4 h, l;
    h.x = f2bf(v.x); l.x = f2bf(v.x - bf2f(h.x));
    h.y = f2bf(v.y); l.y = f2bf(v.y - bf2f(h.y));
    h.z = f2bf(v.z); l.z = f2bf(v.z - bf2f(h.z));
    h.w = f2bf(v.w); l.w = f2bf(v.w - bf2f(h.w));
    *(ushort4*)&hi[e] = h;
    *(ushort4*)&lo[e] = l;
}

// ---------------------------------------------------------------------------
// bf16x3 MFMA GEMM, 128x64 tile (large-N: qkv_u, p_u). fp32 out.
// ---------------------------------------------------------------------------
__global__ __launch_bounds__(256) void gemm_bf16x3(
    const unsigned short* __restrict__ Ah, const unsigned short* __restrict__ Al,
    const unsigned short* __restrict__ Bh, const unsigned short* __restrict__ Bl,
    const float* __restrict__ bias, const float* __restrict__ scale_ptr,
    float* __restrict__ Cf, int M, int N, int Kd)
{
    __shared__ unsigned short sAh[128 * 40], sAl[128 * 40];
    __shared__ unsigned short sBh[64 * 40],  sBl[64 * 40];
    int tid = threadIdx.x;
    int lane = tid & 63, wv = tid >> 6;
    int wr = wv >> 1, wc = wv & 1;
    int row0 = blockIdx.y * 128, col0 = blockIdx.x * 64;

    f32x4 acc[4][2];
#pragma unroll
    for (int i = 0; i < 4; i++)
#pragma unroll
        for (int j = 0; j < 2; j++) acc[i][j] = (f32x4){0.f, 0.f, 0.f, 0.f};

    int ar = tid >> 1, ac = (tid & 1) * 16;
    int br = tid >> 2, bc = (tid & 3) * 8;
    const unsigned short* gAh = Ah + (size_t)(row0 + ar) * Kd + ac;
    const unsigned short* gAl = Al + (size_t)(row0 + ar) * Kd + ac;
    const unsigned short* gBh = Bh + (size_t)(col0 + br) * Kd + bc;
    const unsigned short* gBl = Bl + (size_t)(col0 + br) * Kd + bc;
    int am = lane & 15, qk = (lane >> 4) * 8;

    for (int k0 = 0; k0 < Kd; k0 += 32) {
        __syncthreads();
        *(float4*)&sAh[ar * 40 + ac]     = *(const float4*)(gAh + k0);
        *(float4*)&sAh[ar * 40 + ac + 8] = *(const float4*)(gAh + k0 + 8);
        *(float4*)&sAl[ar * 40 + ac]     = *(const float4*)(gAl + k0);
        *(float4*)&sAl[ar * 40 + ac + 8] = *(const float4*)(gAl + k0 + 8);
        *(float4*)&sBh[br * 40 + bc]     = *(const float4*)(gBh + k0);
        *(float4*)&sBl[br * 40 + bc]     = *(const float4*)(gBl + k0);
        __syncthreads();

        bf16x8 ah[4], al[4], bh[2], bl[2];
#pragma unroll
        for (int rt = 0; rt < 4; rt++) {
            int r = wr * 64 + rt * 16 + am;
            ah[rt] = *(const bf16x8*)&sAh[r * 40 + qk];
            al[rt] = *(const bf16x8*)&sAl[r * 40 + qk];
        }
#pragma unroll
        for (int ct = 0; ct < 2; ct++) {
            int c = wc * 32 + ct * 16 + am;
            bh[ct] = *(const bf16x8*)&sBh[c * 40 + qk];
            bl[ct] = *(const bf16x8*)&sBl[c * 40 + qk];
        }
#pragma unroll
        for (int rt = 0; rt < 4; rt++)
#pragma unroll
            for (int ct = 0; ct < 2; ct++) {
                acc[rt][ct] = __builtin_amdgcn_mfma_f32_16x16x32_bf16(ah[rt], bh[ct], acc[rt][ct], 0, 0, 0);
                acc[rt][ct] = __builtin_amdgcn_mfma_f32_16x16x32_bf16(ah[rt], bl[ct], acc[rt][ct], 0, 0, 0);
                acc[rt][ct] = __builtin_amdgcn_mfma_f32_16x16x32_bf16(al[rt], bh[ct], acc[rt][ct], 0, 0, 0);
            }
    }

    float scl = scale_ptr ? *scale_ptr : 1.0f;
    int rq = (lane >> 4) * 4;
#pragma unroll
    for (int rt = 0; rt < 4; rt++)
#pragma unroll
        for (int ct = 0; ct < 2; ct++) {
            int col = col0 + wc * 32 + ct * 16 + am;
            float bz = bias ? bias[col] : 0.0f;
#pragma unroll
            for (int rg = 0; rg < 4; rg++) {
                int row = row0 + wr * 64 + rt * 16 + rq + rg;
                Cf[(size_t)row * N + col] = (acc[rt][ct][rg] + bz) * scl;
            }
        }
}

// ---------------------------------------------------------------------------
// bf16x3 MFMA GEMM, 64x64 tile (gemm1 N=512 split epilogue, p_d N=256).
// ---------------------------------------------------------------------------
__global__ __launch_bounds__(256) void gemm64_bf16x3(
    const unsigned short* __restrict__ Ah, const unsigned short* __restrict__ Al,
    const unsigned short* __restrict__ Bh, const unsigned short* __restrict__ Bl,
    const float* __restrict__ bias_lo, const float* __restrict__ bias_hi,
    float* __restrict__ Cf, unsigned short* __restrict__ Chi,
    unsigned short* __restrict__ Clo, int M, int N, int Kd, int split_col)
{
    __shared__ unsigned short sAh[64 * 40], sAl[64 * 40];
    __shared__ unsigned short sBh[64 * 40], sBl[64 * 40];
    int tid = threadIdx.x;
    int lane = tid & 63, wv = tid >> 6;
    int wr = wv >> 1, wc = wv & 1;          // wave 32x32
    int row0 = blockIdx.y * 64, col0 = blockIdx.x * 64;

    f32x4 acc[2][2];
#pragma unroll
    for (int i = 0; i < 2; i++)
#pragma unroll
        for (int j = 0; j < 2; j++) acc[i][j] = (f32x4){0.f, 0.f, 0.f, 0.f};

    int sr = tid >> 2, sc = (tid & 3) * 8;
    const unsigned short* gAh = Ah + (size_t)(row0 + sr) * Kd + sc;
    const unsigned short* gAl = Al + (size_t)(row0 + sr) * Kd + sc;
    const unsigned short* gBh = Bh + (size_t)(col0 + sr) * Kd + sc;
    const unsigned short* gBl = Bl + (size_t)(col0 + sr) * Kd + sc;
    int am = lane & 15, qk = (lane >> 4) * 8;

    for (int k0 = 0; k0 < Kd; k0 += 32) {
        __syncthreads();
        *(float4*)&sAh[sr * 40 + sc] = *(const float4*)(gAh + k0);
        *(float4*)&sAl[sr * 40 + sc] = *(const float4*)(gAl + k0);
        *(float4*)&sBh[sr * 40 + sc] = *(const float4*)(gBh + k0);
        *(float4*)&sBl[sr * 40 + sc] = *(const float4*)(gBl + k0);
        __syncthreads();

        bf16x8 ah[2], al[2], bh[2], bl[2];
#pragma unroll
        for (int rt = 0; rt < 2; rt++) {
            int r = wr * 32 + rt * 16 + am;
            ah[rt] = *(const bf16x8*)&sAh[r * 40 + qk];
            al[rt] = *(const bf16x8*)&sAl[r * 40 + qk];
        }
#pragma unroll
        for (int ct = 0; ct < 2; ct++) {
            int c = wc * 32 + ct * 16 + am;
            bh[ct] = *(const bf16x8*)&sBh[c * 40 + qk];
            bl[ct] = *(const bf16x8*)&sBl[c * 40 + qk];
        }
#pragma unroll
        for (int rt = 0; rt < 2; rt++)
#pragma unroll
            for (int ct = 0; ct < 2; ct++) {
                acc[rt][ct] = __builtin_amdgcn_mfma_f32_16x16x32_bf16(ah[rt], bh[ct], acc[rt][ct], 0, 0, 0);
                acc[rt][ct] = __builtin_amdgcn_mfma_f32_16x16x32_bf16(ah[rt], bl[ct], acc[rt][ct], 0, 0, 0);
                acc[rt][ct] = __builtin_amdgcn_mfma_f32_16x16x32_bf16(al[rt], bh[ct], acc[rt][ct], 0, 0, 0);
            }
    }

    int rq = (lane >> 4) * 4;
#pragma unroll
    for (int rt = 0; rt < 2; rt++)
#pragma unroll
        for (int ct = 0; ct < 2; ct++) {
            int col = col0 + wc * 32 + ct * 16 + am;
#pragma unroll
            for (int rg = 0; rg < 4; rg++) {
                int row = row0 + wr * 32 + rt * 16 + rq + rg;
                float v = acc[rt][ct][rg];
                if (col < split_col) {
                    if (bias_lo) v += bias_lo[col];
                    size_t idx = (size_t)row * split_col + col;
                    unsigned short hh = f2bf(v);
                    Chi[idx] = hh;
                    Clo[idx] = f2bf(v - bf2f(hh));
                } else {
                    if (bias_hi) v += bias_hi[col - split_col];
                    Cf[(size_t)row * (N - split_col) + col - split_col] = v;
                }
            }
        }
}

// ---------------------------------------------------------------------------
// RoPE applied in-place to q and k slices of qkv[S,3072].
// ---------------------------------------------------------------------------
__global__ __launch_bounds__(256) void rope_kernel(
    float* __restrict__ qkv, const float* __restrict__ rope)
{
    int idx = blockIdx.x * blockDim.x + threadIdx.x;  // S*H*32 total
    if (idx >= S_ * H_ * 32) return;
    int d = idx & 31;
    int h = (idx >> 5) & (H_ - 1);
    int s = idx >> 9;
    float r = rope[s * 32 + d];
    float c = cosf(r), sn = sinf(r);
    size_t base = (size_t)s * 3072 + h * 64 + d;
    float q1 = qkv[base], q2 = qkv[base + 32];
    qkv[base]      = q1 * c - q2 * sn;
    qkv[base + 32] = q2 * c + q1 * sn;
    float k1 = qkv[base + 1024], k2 = qkv[base + 1024 + 32];
    qkv[base + 1024]      = k1 * c - k2 * sn;
    qkv[base + 1024 + 32] = k2 * c + k1 * sn;
}

// ---------------------------------------------------------------------------
// Fused index scores + top-K membership (R11-passing, unchanged).
// ---------------------------------------------------------------------------
__global__ __launch_bounds__(256) void score_topk_kernel(
    const float* __restrict__ qIk,
    const int* __restrict__ coords, const float* __restrict__ rpe_table,
    const float* __restrict__ W1g, const float* __restrict__ b1g,
    const float* __restrict__ W2g, const float* __restrict__ b2g,
    unsigned* __restrict__ selmask)
{
    __shared__ float skI[64][132];
    __shared__ float sqI2[4][IDH2_];
    __shared__ unsigned skeys[4][LI_];
    __shared__ int shist[4][256];
    __shared__ float srpe[NBUCK_ * IH_];
    __shared__ float sW1[GH_ * IH_], sb1[GH_], sW2[IH_ * GH_], sb2[IH_];

    int tid  = threadIdx.x;
    int lane = tid & 63;
    int wv   = tid >> 6;
    int row  = blockIdx.x * 4 + wv;
    int n    = (blockIdx.x * 4) >> 9;

    for (int i = tid; i < NBUCK_ * IH_; i += 256) srpe[i] = rpe_table[i];
    if (tid < 32) sW1[tid] = W1g[tid];
    else if (tid < 64) sW2[tid - 32] = W2g[tid - 32];
    else if (tid < 72) sb1[tid - 64] = b1g[tid - 64];
    else if (tid < 76) sb2[tid - 72] = b2g[tid - 72];
    for (int i = tid; i < 4 * IDH2_; i += 256)
        sqI2[i >> 7][i & 127] =
            qIk[(size_t)(blockIdx.x * 4 + (i >> 7)) * 256 + (i & 127)];
    int pq = coords[row * 2 + 1];

    for (int kt = 0; kt < 8; kt++) {
        __syncthreads();
        {
            int r  = tid >> 2;
            int d0 = (tid & 3) * 32;
            const float* src = qIk + (size_t)(n * LI_ + kt * 64 + r) * 256 + 128 + d0;
#pragma unroll
            for (int j = 0; j < 8; j++)
                *(float4*)&skI[r][d0 + j * 4] = *(const float4*)(src + j * 4);
        }
        __syncthreads();

        int kloc = lane;
        int kg   = kt * 64 + kloc;
        const float* sq = &sqI2[wv][0];
        float dh[8];
#pragma unroll
        for (int hh = 0; hh < 8; hh++) {
            float acc = 0.0f;
#pragma unroll
            for (int d = 0; d < 16; d += 4) {
                float4 kv = *(const float4*)&skI[kloc][hh * 16 + d];
                acc += sq[hh * 16 + d + 0] * kv.x + sq[hh * 16 + d + 1] * kv.y +
                       sq[hh * 16 + d + 2] * kv.z + sq[hh * 16 + d + 3] * kv.w;
            }
            dh[hh] = acc;
        }
        int pk = coords[(n * LI_ + kg) * 2 + 1];
        int rel = pq - pk;
        rel = rel < -MAXREL_ ? -MAXREL_ : (rel > MAXREL_ ? MAXREL_ : rel);
        const float* rp = srpe + (rel + MAXREL_) * IH_;
        float t1[GH_];
#pragma unroll
        for (int g = 0; g < GH_; g++) t1[g] = sb1[g];
#pragma unroll
        for (int j = 0; j < IH_; j++) {
            float gate = dh[IH_ + j] + rp[j];
#pragma unroll
            for (int g = 0; g < GH_; g++) t1[g] += gate * sW1[g * IH_ + j];
        }
#pragma unroll
        for (int g = 0; g < GH_; g++) t1[g] = fmaxf(t1[g], 0.0f);
        float score = 0.0f;
#pragma unroll
        for (int j = 0; j < IH_; j++) {
            float t2 = sb2[j];
#pragma unroll
            for (int g = 0; g < GH_; g++) t2 += t1[g] * sW2[j * GH_ + g];
            float sg = 1.0f / (1.0f + expf(-t2));
            float rs = fmaxf(dh[j] + rp[j], 0.0f);
            score += rs * sg;
        }
        unsigned bits = __float_as_uint(score);
        skeys[wv][kg] = (bits & 0x80000000u) ? ~bits : (bits | 0x80000000u);
    }
    __syncthreads();

    unsigned pref = 0u;
    int kcur = K_;
    const unsigned himask[4] = {0u, 0xFF000000u, 0xFFFF0000u, 0xFFFFFF00u};
#pragma unroll
    for (int pass = 0; pass < 4; pass++) {
        int shift = 24 - pass * 8;
        unsigned hm = himask[pass];
        *(int4*)&shist[wv][4 * lane] = make_int4(0, 0, 0, 0);
        __syncthreads();
#pragma unroll
        for (int c = 0; c < 8; c++) {
            unsigned key = skeys[wv][c * 64 + lane];
            if ((key & hm) == pref) atomicAdd(&shist[wv][(key >> shift) & 255], 1);
        }
        __syncthreads();
        int4 b4 = *(const int4*)&shist[wv][4 * lane];
        int b[4] = {b4.x, b4.y, b4.z, b4.w};
        int t = b[0] + b[1] + b[2] + b[3];
        int Ssum = t;
#pragma unroll
        for (int off = 1; off < 64; off <<= 1) {
            int u = __shfl_down(Ssum, off, 64);
            if (lane + off < 64) Ssum += u;
        }
        int E = Ssum - t;
        int cs[5];
        cs[4] = E;
        cs[3] = b[3] + E;
        cs[2] = b[2] + cs[3];
        cs[1] = b[1] + cs[2];
        cs[0] = b[0] + cs[1];
        bool found = false;
        unsigned cpref = 0u; int ck = 0;
#pragma unroll
        for (int j = 0; j < 4; j++) {
            if (!found && cs[j] >= kcur && cs[j + 1] < kcur) {
                found = true;
                cpref = pref | ((unsigned)(4 * lane + j) << shift);
                ck = kcur - cs[j + 1];
            }
        }
        unsigned long long bm = __ballot(found);
        int src = __ffsll((long long)bm) - 1;
        pref = (unsigned)__shfl((int)cpref, src, 64);
        kcur = __shfl(ck, src, 64);
        __syncthreads();
    }
    unsigned Tu = pref;

    unsigned long long bg[8], be[8];
#pragma unroll
    for (int c = 0; c < 8; c++) {
        unsigned key = skeys[wv][c * 64 + lane];
        bg[c] = __ballot(key > Tu);
        be[c] = __ballot(key == Tu);
    }
    if (lane < 16) {
        int total_gt = 0;
#pragma unroll
        for (int c = 0; c < 8; c++) total_gt += __popcll(bg[c]);
        int base = 0;
#pragma unroll
        for (int c = 0; c < 8; c++) {
            if (2 * c < lane)     base += __popc((unsigned)be[c]);
            if (2 * c + 1 < lane) base += __popc((unsigned)(be[c] >> 32));
        }
        unsigned gw = (unsigned)(bg[lane >> 1] >> (32 * (lane & 1)));
        unsigned ew = (unsigned)(be[lane >> 1] >> (32 * (lane & 1)));
        int ne = K_ - total_gt - base;
        int pc = __popc(ew);
        int m = ne < 0 ? 0 : (ne > pc ? pc : ne);
        while (pc > m) { ew ^= (1u << (31 - __clz(ew))); pc--; }
        selmask[(size_t)row * 16 + lane] = gw | ew;
    }
}

// ---------------------------------------------------------------------------
// Dense-masked attention v4: full MFMA bf16x3 for both QK^T and PV.
// Per (n,h,64q) block (XCD-swizzled decode), 4 waves; wave w owns q rows
// [16w,16w+16). Per key-tile: stage K (row-major [key][d]) and V^T
// ([d][key], via coalesced column reads) as hi/lo bf16 split on the fly
// from fp32 qkv; QK = NT-MFMA (A=Q,B=K) x3; fp32 softmax on C-layout regs
// (no max-sub, scores O(1)); P split hi/lo into K's LDS (time-disjoint);
// PV = NT-MFMA (A=P,B=V^T) x3. Row sums per-wave via 16-lane shuffles.
// LDS: 6 x 64x72 ushort tiles + masks = 58 KiB.
// ---------------------------------------------------------------------------
__global__ __launch_bounds__(256) void attn_kernel(
    const float* __restrict__ qkv, const unsigned* __restrict__ selmask,
    unsigned short* __restrict__ outh, unsigned short* __restrict__ outl)
{
    __shared__ unsigned short Qh[64 * 72],  Ql[64 * 72];   // [q][d]
    __shared__ unsigned short KPh[64 * 72], KPl[64 * 72];  // K [key][d] -> P [q][key]
    __shared__ unsigned short VTh[64 * 72], VTl[64 * 72];  // V^T [d][key]
    __shared__ unsigned Ms[64][16];

    int b  = blockIdx.x;
    int qt = b >> 6;                 // XCD swizzle: qt in high bits
    int nh = b & 63;
    int h  = nh & 15;
    int n  = nh >> 4;
    int tid = threadIdx.x;
    int lane = tid & 63, w = tid >> 6;
    int lane15 = lane & 15, quad = lane >> 4;
    int q0 = n * LI_ + qt * 64;

    for (int i = tid; i < 64 * 16; i += 256)
        Ms[i >> 4][i & 15] = selmask[(size_t)(q0 + (i >> 4)) * 16 + (i & 15)];

    // stage Q once: row r, 16 d's; scale 1/8 then split (exact scaling)
    {
        int r = tid >> 2, c0 = (tid & 3) * 16;
        const float* src = qkv + (size_t)(q0 + r) * 3072 + h * 64 + c0;
        unsigned short hb[16], lb[16];
#pragma unroll
        for (int j = 0; j < 16; j += 4) {
            float4 v = *(const float4*)(src + j);
            float f[4] = {v.x * 0.125f, v.y * 0.125f, v.z * 0.125f, v.w * 0.125f};
#pragma unroll
            for (int t = 0; t < 4; t++) {
                unsigned short hh = f2bf(f[t]);
                hb[j + t] = hh;
                lb[j + t] = f2bf(f[t] - bf2f(hh));
            }
        }
        *(uint4*)&Qh[r * 72 + c0]     = *(uint4*)&hb[0];
        *(uint4*)&Qh[r * 72 + c0 + 8] = *(uint4*)&hb[8];
        *(uint4*)&Ql[r * 72 + c0]     = *(uint4*)&lb[0];
        *(uint4*)&Ql[r * 72 + c0 + 8] = *(uint4*)&lb[8];
    }

    f32x4 o_acc[4];
#pragma unroll
    for (int i = 0; i < 4; i++) o_acc[i] = (f32x4){0.f, 0.f, 0.f, 0.f};
    float rsum[4] = {};

    for (int kt = 0; kt < 8; kt++) {
        __syncthreads();   // prev PV reads of KP/VT done
        // stage K [key][d] hi/lo
        {
            int r = tid >> 2, c0 = (tid & 3) * 16;
            const float* src = qkv + (size_t)(n * LI_ + kt * 64 + r) * 3072 + 1024 + h * 64 + c0;
            unsigned short hb[16], lb[16];
#pragma unroll
            for (int j = 0; j < 16; j += 4) {
                float4 v = *(const float4*)(src + j);
                float f[4] = {v.x, v.y, v.z, v.w};
#pragma unroll
                for (int t = 0; t < 4; t++) {
                    unsigned short hh = f2bf(f[t]);
                    hb[j + t] = hh;
                    lb[j + t] = f2bf(f[t] - bf2f(hh));
                }
            }
            *(uint4*)&KPh[r * 72 + c0]     = *(uint4*)&hb[0];
            *(uint4*)&KPh[r * 72 + c0 + 8] = *(uint4*)&hb[8];
            *(uint4*)&KPl[r * 72 + c0]     = *(uint4*)&lb[0];
            *(uint4*)&KPl[r * 72 + c0 + 8] = *(uint4*)&lb[8];
        }
        // stage V^T [d][key]: thread owns column d = lane (per-wave 16 keys),
        // coalesced reads (lanes span d), contiguous row writes
        {
            int d = lane;
            int k0 = w * 16;
            const float* src = qkv + (size_t)(n * LI_ + kt * 64 + k0) * 3072 + 2048 + h * 64 + d;
            unsigned short hb[16], lb[16];
#pragma unroll
            for (int j = 0; j < 16; j++) {
                float f = src[(size_t)j * 3072];
                unsigned short hh = f2bf(f);
                hb[j] = hh;
                lb[j] = f2bf(f - bf2f(hh));
            }
            *(uint4*)&VTh[d * 72 + k0]     = *(uint4*)&hb[0];
            *(uint4*)&VTh[d * 72 + k0 + 8] = *(uint4*)&hb[8];
            *(uint4*)&VTl[d * 72 + k0]     = *(uint4*)&lb[0];
            *(uint4*)&VTl[d * 72 + k0 + 8] = *(uint4*)&lb[8];
        }
        __syncthreads();

        // QK: wave w computes q-tile w vs all 4 key-tiles, bf16x3
        f32x4 s_acc[4];
#pragma unroll
        for (int nt = 0; nt < 4; nt++) s_acc[nt] = (f32x4){0.f, 0.f, 0.f, 0.f};
        {
            bf16x8 qfh[2], qfl[2];
#pragma unroll
            for (int ks = 0; ks < 2; ks++) {
                qfh[ks] = *(const bf16x8*)&Qh[(16 * w + lane15) * 72 + ks * 32 + quad * 8];
                qfl[ks] = *(const bf16x8*)&Ql[(16 * w + lane15) * 72 + ks * 32 + quad * 8];
            }
#pragma unroll
            for (int nt = 0; nt < 4; nt++) {
#pragma unroll
                for (int ks = 0; ks < 2; ks++) {
                    bf16x8 kfh = *(const bf16x8*)&KPh[(16 * nt + lane15) * 72 + ks * 32 + quad * 8];
                    bf16x8 kfl = *(const bf16x8*)&KPl[(16 * nt + lane15) * 72 + ks * 32 + quad * 8];
                    s_acc[nt] = __builtin_amdgcn_mfma_f32_16x16x32_bf16(qfh[ks], kfh, s_acc[nt], 0, 0, 0);
                    s_acc[nt] = __builtin_amdgcn_mfma_f32_16x16x32_bf16(qfh[ks], kfl, s_acc[nt], 0, 0, 0);
                    s_acc[nt] = __builtin_amdgcn_mfma_f32_16x16x32_bf16(qfl[ks], kfh, s_acc[nt], 0, 0, 0);
                }
            }
        }
        __syncthreads();   // all K frag reads done before P overwrite

        // softmax (C-layout: row q = quad*4+reg, col key = lane15) + P split
#pragma unroll
        for (int nt = 0; nt < 4; nt++) {
            int kb = kt * 64 + nt * 16 + lane15;
            int wi = kb >> 5, bit = kb & 31;
#pragma unroll
            for (int reg = 0; reg < 4; reg++) {
                int qloc = 16 * w + quad * 4 + reg;
                unsigned mw = Ms[qloc][wi];
                float p = ((mw >> bit) & 1u) ? __expf(s_acc[nt][reg]) : 0.0f;
                rsum[reg] += p;
                unsigned short ph = f2bf(p);
                KPh[qloc * 72 + nt * 16 + lane15] = ph;
                KPl[qloc * 72 + nt * 16 + lane15] = f2bf(p - bf2f(ph));
            }
        }
        __syncthreads();

        // PV: A = P [q][key], B = V^T [d][key], bf16x3
        {
            bf16x8 pfh[2], pfl[2];
#pragma unroll
            for (int ks = 0; ks < 2; ks++) {
                pfh[ks] = *(const bf16x8*)&KPh[(16 * w + lane15) * 72 + ks * 32 + quad * 8];
                pfl[ks] = *(const bf16x8*)&KPl[(16 * w + lane15) * 72 + ks * 32 + quad * 8];
            }
#pragma unroll
            for (int dt = 0; dt < 4; dt++) {
#pragma unroll
                for (int ks = 0; ks < 2; ks++) {
                    bf16x8 vfh = *(const bf16x8*)&VTh[(16 * dt + lane15) * 72 + ks * 32 + quad * 8];
                    bf16x8 vfl = *(const bf16x8*)&VTl[(16 * dt + lane15) * 72 + ks * 32 + quad * 8];
                    o_acc[dt] = __builtin_amdgcn_mfma_f32_16x16x32_bf16(pfh[ks], vfh, o_acc[dt], 0, 0, 0);
                    o_acc[dt] = __builtin_amdgcn_mfma_f32_16x16x32_bf16(pfh[ks], vfl, o_acc[dt], 0, 0, 0);
                    o_acc[dt] = __builtin_amdgcn_mfma_f32_16x16x32_bf16(pfl[ks], vfh, o_acc[dt], 0, 0, 0);
                }
            }
        }
    }

    // row sums: reduce over the 16 lanes (lane15) sharing each q row
#pragma unroll
    for (int reg = 0; reg < 4; reg++) {
        rsum[reg] += __shfl_xor(rsum[reg], 1, 64);
        rsum[reg] += __shfl_xor(rsum[reg], 2, 64);
        rsum[reg] += __shfl_xor(rsum[reg], 4, 64);
        rsum[reg] += __shfl_xor(rsum[reg], 8, 64);
    }

    // epilogue: normalize, split hi/lo, store (C-layout: row=quad*4+reg, col=lane15)
#pragma unroll
    for (int dt = 0; dt < 4; dt++) {
#pragma unroll
        for (int reg = 0; reg < 4; reg++) {
            float v = o_acc[dt][reg] / rsum[reg];
            size_t ob = (size_t)(q0 + 16 * w + quad * 4 + reg) * 1024 + h * 64 + 16 * dt + lane15;
            unsigned short hh = f2bf(v);
            outh[ob] = hh;
            outl[ob] = f2bf(v - bf2f(hh));
        }
    }
}

// ---------------------------------------------------------------------------
extern "C" void kernel_launch(void* const* d_in, const int* in_sizes, int n_in,
                              void* d_out, int out_size, void* d_ws, size_t ws_size,
                              hipStream_t stream)
{
    const float* hidden  = (const float*)d_in[0];
    const int*   coords  = (const int*)d_in[1];
    const float* rope    = (const float*)d_in[3];
    const float* Wq_idx  = (const float*)d_in[4];
    const float* Wk_idx  = (const float*)d_in[5];
    const float* W1g     = (const float*)d_in[6];
    const float* b1g     = (const float*)d_in[7];
    const float* W2g     = (const float*)d_in[8];
    const float* b2g     = (const float*)d_in[9];
    const float* rpe     = (const float*)d_in[10];
    const float* Wqkv_d  = (const float*)d_in[11];
    const float* bqkv_d  = (const float*)d_in[12];
    const float* Wqkv_u  = (const float*)d_in[13];
    const float* bqkv_u  = (const float*)d_in[14];
    const float* Wp_d    = (const float*)d_in[15];
    const float* bp_d    = (const float*)d_in[16];
    const float* Wp_u    = (const float*)d_in[17];
    const float* bp_u    = (const float*)d_in[18];
    const float* scaler  = (const float*)d_in[19];
    float* out = (float*)d_out;

    unsigned short* sp_hi  = (unsigned short*)d_ws;
    unsigned short* sp_lo  = sp_hi + NSPLIT_;
    unsigned short* mid_hi = sp_lo + NSPLIT_;
    unsigned short* mid_lo = mid_hi + (size_t)S_ * BOT_;
    float* qkv = (float*)(mid_lo + (size_t)S_ * BOT_);
    float* qIk = qkv + (size_t)S_ * 3 * DIM_;
    unsigned* selmask = (unsigned*)(qIk + (size_t)S_ * 256);

    // 0) split hidden + all weights into hi/lo bf16
    split_all_kernel<<<(NSPLIT_ / 4 + 255) / 256, 256, 0, stream>>>(
        hidden, Wqkv_d, Wq_idx, Wk_idx, Wqkv_u, Wp_d, Wp_u, sp_hi, sp_lo);

    // 1) fused gemm1: hidden @ [Wqkv_d;Wq;Wk]^T -> mid(hi/lo) + qIk(fp32)
    gemm64_bf16x3<<<dim3(512 / 64, S_ / 64), 256, 0, stream>>>(
        sp_hi, sp_lo, sp_hi + OFF_W1_, sp_lo + OFF_W1_,
        bqkv_d, nullptr, qIk, mid_hi, mid_lo, S_, 512, DIM_, 256);

    // 2) qkv = mid @ Wqkv_u^T + b (fp32)
    gemm_bf16x3<<<dim3(3 * DIM_ / 64, S_ / 128), 256, 0, stream>>>(
        mid_hi, mid_lo, sp_hi + OFF_WQKVU_, sp_lo + OFF_WQKVU_,
        bqkv_u, nullptr, qkv, S_, 3 * DIM_, BOT_);

    // 3) RoPE on q,k in place
    rope_kernel<<<(S_ * H_ * 32) / 256, 256, 0, stream>>>(qkv, rope);

    // 4) fused index scores + top-k membership
    score_topk_kernel<<<S_ / 4, 256, 0, stream>>>(
        qIk, coords, rpe, W1g, b1g, W2g, b2g, selmask);

    // 5) MFMA attention (emits attout hi/lo into hidden's split slots)
    attn_kernel<<<NIMG_ * H_ * 8, 256, 0, stream>>>(qkv, selmask, sp_hi, sp_lo);

    // 6) mid2 = attout @ Wp_d^T + b (hi/lo)
    gemm64_bf16x3<<<dim3(BOT_ / 64, S_ / 64), 256, 0, stream>>>(
        sp_hi, sp_lo, sp_hi + OFF_WPD_, sp_lo + OFF_WPD_,
        bp_d, nullptr, nullptr, mid_hi, mid_lo, S_, BOT_, DIM_, BOT_);

    // 7) out = mid2 @ Wp_u^T + b, *scaler (fp32)
    gemm_bf16x3<<<dim3(DIM_ / 64, S_ / 128), 256, 0, stream>>>(
        mid_hi, mid_lo, sp_hi + OFF_WPU_, sp_lo + OFF_WPU_,
        bp_u, scaler, out, S_, DIM_, BOT_);
}